// Round 3
// baseline (944.432 us; speedup 1.0000x reference)
//
#include <hip/hip_runtime.h>
#include <hip/hip_bf16.h>

// N=8192, K=16, CIN=64, C=256, S=8, C/S=32 ; all float tensors are float32.
#define INV_N  (1.0f/8192.0f)
#define INV_NK (1.0f/131072.0f)

__device__ __forceinline__ float bn_ap(float v, const float* st, int C, int ch,
                                       float inv, float g, float b) {
  float m = st[ch] * inv;
  float var = st[C + ch] * inv - m * m;
  return (v - m) * rsqrtf(var + 1e-5f) * g + b;
}

// ---------------------------------------------------------------- head: p copy + o
__launch_bounds__(256)
__global__ void head_k(const float* __restrict__ p, const int* __restrict__ o,
                       float* __restrict__ out) {
  int e = blockIdx.x*256 + threadIdx.x;
  if (e < 24576) out[e] = p[e];
  if (e == 0) out[24576 + 2097152] = (float)o[0];
}

// ---------------------------------------------------------------- KNN
__launch_bounds__(64)
__global__ void knn_k(const float* __restrict__ p, int* __restrict__ idxo) {
  int q = blockIdx.x;
  int lane = threadIdx.x;
  float qx = p[q*3+0], qy = p[q*3+1], qz = p[q*3+2];
  float sqi = (qx*qx + qy*qy) + qz*qz;
  float dist[16];
  int ind[16];
#pragma unroll
  for (int s = 0; s < 16; ++s) { dist[s] = 3.0e38f; ind[s] = 0x7fffffff; }
  for (int j = lane; j < 8192; j += 64) {
    float px = p[j*3+0], py = p[j*3+1], pz = p[j*3+2];
    float sqj = (px*px + py*py) + pz*pz;
    float dot = (qx*px + qy*py) + qz*pz;
    float d2 = (sqi + sqj) - 2.0f*dot;
    bool better = (d2 < dist[15]) || (d2 == dist[15] && j < ind[15]);
    if (better) {
#pragma unroll
      for (int s = 15; s >= 0; --s) {
        bool lt_s = (d2 < dist[s]) || (d2 == dist[s] && j < ind[s]);
        bool lt_p = (s == 0) ? false
                   : ((d2 < dist[s-1]) || (d2 == dist[s-1] && j < ind[s-1]));
        float nd = lt_s ? (lt_p ? dist[s-1] : d2) : dist[s];
        int   ni = lt_s ? (lt_p ? ind[s-1]  : j ) : ind[s];
        dist[s] = nd; ind[s] = ni;
      }
    }
  }
  for (int r = 0; r < 16; ++r) {
    float bd = dist[0]; int bi = ind[0];
#pragma unroll
    for (int m = 1; m < 64; m <<= 1) {
      float od = __shfl_xor(bd, m);
      int   oi = __shfl_xor(bi, m);
      if (od < bd || (od == bd && oi < bi)) { bd = od; bi = oi; }
    }
    if (lane == 0) idxo[q*16 + r] = bi;
    if (dist[0] == bd && ind[0] == bi) {
#pragma unroll
      for (int s = 0; s < 15; ++s) { dist[s] = dist[s+1]; ind[s] = ind[s+1]; }
      dist[15] = 3.0e38f; ind[15] = 0x7fffffff;
    }
  }
}

// ---------------------------------------------------------------- GEMM
template<bool BNA, bool BIAS, int BM, int BN, int TM, int TN, int BK>
__launch_bounds__(256)
__global__ void gemm_k(const float* __restrict__ A, const float* __restrict__ st,
                       const float* __restrict__ g, const float* __restrict__ bb,
                       float inv_cnt,
                       const float* __restrict__ W, const float* __restrict__ bias,
                       float* __restrict__ out, int M, int KA, int NOUT) {
  constexpr int THREADS = (BM/TM) * (BN/TN);
  __shared__ float As[BK][BM + 4];
  __shared__ float Bs[BK][BN + 4];
  int t = threadIdx.x;
  int tn = t % (BN/TN), tm = t / (BN/TN);
  int m0 = blockIdx.x * BM, n0 = blockIdx.y * BN;
  float acc[TM][TN] = {};
  for (int k0 = 0; k0 < KA; k0 += BK) {
#pragma unroll
    for (int e = t; e < BM*BK; e += THREADS) {
      int r = e / BK, c = e % BK;
      float v = A[(size_t)(m0 + r)*KA + (k0 + c)];
      if (BNA) {
        int ch = k0 + c;
        v = fmaxf(bn_ap(v, st, KA, ch, inv_cnt, g[ch], bb[ch]), 0.0f);
      }
      As[c][r] = v;
    }
#pragma unroll
    for (int e = t; e < BK*BN; e += THREADS) {
      int r = e / BN, c = e % BN;
      Bs[r][c] = W[(size_t)(k0 + r)*NOUT + (n0 + c)];
    }
    __syncthreads();
#pragma unroll
    for (int kk = 0; kk < BK; ++kk) {
      float a[TM], b[TN];
#pragma unroll
      for (int i = 0; i < TM; ++i) a[i] = As[kk][tm*TM + i];
#pragma unroll
      for (int j = 0; j < TN; ++j) b[j] = Bs[kk][tn*TN + j];
#pragma unroll
      for (int i = 0; i < TM; ++i)
#pragma unroll
        for (int j = 0; j < TN; ++j) acc[i][j] += a[i]*b[j];
    }
    __syncthreads();
  }
#pragma unroll
  for (int i = 0; i < TM; ++i) {
    int r = m0 + tm*TM + i;
#pragma unroll
    for (int j = 0; j < TN; ++j) {
      int c = n0 + tn*TN + j;
      float v = acc[i][j];
      if (BIAS) v += bias[c];
      out[(size_t)r*NOUT + c] = v;
    }
  }
}

// ---------------------------------------------------------------- stats
__launch_bounds__(256)
__global__ void stats256_k(const float* __restrict__ X, float* __restrict__ st) {
  int c = threadIdx.x;
  int r0 = blockIdx.x * 32;
  float s1 = 0.f, s2 = 0.f;
  for (int r = 0; r < 32; ++r) {
    float v = X[(size_t)(r0 + r)*256 + c];
    s1 += v; s2 += v*v;
  }
  atomicAdd(&st[c], s1);
  atomicAdd(&st[256 + c], s2);
}

__launch_bounds__(256)
__global__ void stats32_k(const float* __restrict__ X, float* __restrict__ st) {
  int c = threadIdx.x & 31, rg = threadIdx.x >> 5;
  size_t r0 = (size_t)blockIdx.x * 256;
  float s1 = 0.f, s2 = 0.f;
  for (int r = rg; r < 256; r += 8) {
    float v = X[(r0 + r)*32 + c];
    s1 += v; s2 += v*v;
  }
  __shared__ float red1[256], red2[256];
  red1[threadIdx.x] = s1; red2[threadIdx.x] = s2;
  __syncthreads();
  if (threadIdx.x < 32) {
    float a = 0.f, b = 0.f;
#pragma unroll
    for (int gI = 0; gI < 8; ++gI) { a += red1[gI*32 + threadIdx.x]; b += red2[gI*32 + threadIdx.x]; }
    atomicAdd(&st[threadIdx.x], a);
    atomicAdd(&st[32 + threadIdx.x], b);
  }
}

// ---------------------------------------------------------------- p_r helpers
__device__ __forceinline__ void comp_pr1(const float* p, int i, int j,
                                         const float* Wp1, const float* bp1,
                                         float pr1[3]) {
  float rx = p[j*3+0] - p[i*3+0];
  float ry = p[j*3+1] - p[i*3+1];
  float rz = p[j*3+2] - p[i*3+2];
#pragma unroll
  for (int c = 0; c < 3; ++c)
    pr1[c] = rx*Wp1[c] + ry*Wp1[3+c] + rz*Wp1[6+c] + bp1[c];
}

__device__ __forceinline__ void comp_prv(const float* p, int i, int j,
                                         const float* Wp1, const float* bp1,
                                         const float* gp, const float* bpp,
                                         const float* sp, float o3[3]) {
  float pr1[3];
  comp_pr1(p, i, j, Wp1, bp1, pr1);
#pragma unroll
  for (int c = 0; c < 3; ++c)
    o3[c] = fmaxf(bn_ap(pr1[c], sp, 3, c, INV_NK, gp[c], bpp[c]), 0.0f);
}

__launch_bounds__(256)
__global__ void prstats_k(const float* __restrict__ p, const int* __restrict__ idx,
                          const float* Wp1, const float* bp1, float* __restrict__ sp) {
  float s[3] = {0,0,0}, s2[3] = {0,0,0};
  for (int it = 0; it < 4; ++it) {
    int e = blockIdx.x*1024 + it*256 + threadIdx.x;
    int i = e >> 4;
    int j = idx[e] & 8191;
    float pr1[3];
    comp_pr1(p, i, j, Wp1, bp1, pr1);
#pragma unroll
    for (int c = 0; c < 3; ++c) { s[c] += pr1[c]; s2[c] += pr1[c]*pr1[c]; }
  }
#pragma unroll
  for (int m = 1; m < 64; m <<= 1) {
#pragma unroll
    for (int c = 0; c < 3; ++c) {
      s[c]  += __shfl_xor(s[c],  m);
      s2[c] += __shfl_xor(s2[c], m);
    }
  }
  __shared__ float red[4][6];
  int wv = threadIdx.x >> 6, lane = threadIdx.x & 63;
  if (lane == 0) {
#pragma unroll
    for (int c = 0; c < 3; ++c) { red[wv][c] = s[c]; red[wv][3+c] = s2[c]; }
  }
  __syncthreads();
  if (threadIdx.x < 6) {
    float v = red[0][threadIdx.x] + red[1][threadIdx.x] +
              red[2][threadIdx.x] + red[3][threadIdx.x];
    atomicAdd(&sp[threadIdx.x], v);
  }
}

// ---------------------------------------------------------------- stats of w (no materialization)
__launch_bounds__(256)
__global__ void wstats_k(const float* __restrict__ xk, const float* __restrict__ xq,
                         const float* __restrict__ p, const int* __restrict__ idx,
                         const float* Wp1, const float* bp1, const float* gp, const float* bpp,
                         const float* sp, const float* __restrict__ Wp2, const float* bp2,
                         float* __restrict__ sw) {
  __shared__ float prv[32][16][4];
  __shared__ int   jidx[32][16];
  int base = blockIdx.x * 32;
  int t = threadIdx.x;
  for (int e = t; e < 512; e += 256) {
    int pt = e >> 4, k = e & 15;
    int j = idx[(base + pt)*16 + k] & 8191;
    jidx[pt][k] = j;
    float o3[3];
    comp_prv(p, base + pt, j, Wp1, bp1, gp, bpp, sp, o3);
    prv[pt][k][0] = o3[0]; prv[pt][k][1] = o3[1]; prv[pt][k][2] = o3[2];
  }
  __syncthreads();
  int c = t;
  float wp0 = Wp2[c], wp1v = Wp2[256+c], wp2v = Wp2[512+c];
  float bbv = bp2[c];
  float s1 = 0.f, s2 = 0.f;
  for (int pt = 0; pt < 32; ++pt) {
    int i = base + pt;
    float xqv = xq[(size_t)i*256 + c];
#pragma unroll
    for (int k = 0; k < 16; ++k) {
      int j = jidx[pt][k];
      float pr = prv[pt][k][0]*wp0 + prv[pt][k][1]*wp1v + prv[pt][k][2]*wp2v + bbv;
      float wval = xk[(size_t)j*256 + c] - xqv + pr;
      s1 += wval; s2 += wval*wval;
    }
  }
  atomicAdd(&sw[c], s1);
  atomicAdd(&sw[256 + c], s2);
}

// ---------------------------------------------------------------- fused: w1 = BNReLU(w) @ Ww1 + bww1
__launch_bounds__(256)
__global__ void w1gemm_k(const float* __restrict__ xk, const float* __restrict__ xq,
                         const float* __restrict__ p, const int* __restrict__ idx,
                         const float* Wp1, const float* bp1, const float* gp, const float* bpp,
                         const float* sp, const float* __restrict__ Wp2, const float* bp2,
                         const float* sw, const float* gw1, const float* bw1,
                         const float* __restrict__ Ww1, const float* bww1,
                         float* __restrict__ w1) {
  __shared__ float As[32][65];
  __shared__ float Bs[32][33];
  __shared__ float prv[64][4];
  __shared__ int   jrow[64];
  __shared__ float cc6[6][32];   // scl, sft, wp2r0, wp2r1, wp2r2, bp2
  int t = threadIdx.x;
  int base4 = blockIdx.x * 4;
  if (t < 64) {
    int grow = blockIdx.x*64 + t;
    int i = grow >> 4;
    int j = idx[grow] & 8191;
    jrow[t] = j;
    float o3[3];
    comp_prv(p, i, j, Wp1, bp1, gp, bpp, sp, o3);
    prv[t][0] = o3[0]; prv[t][1] = o3[1]; prv[t][2] = o3[2];
  }
  int tn = t & 7, tm = t >> 3;
  float acc[2][4] = {};
  for (int k0 = 0; k0 < 256; k0 += 32) {
    if (t < 32) {
      int ch = k0 + t;
      float m = sw[ch] * INV_NK;
      float var = sw[256+ch]*INV_NK - m*m;
      float scl = rsqrtf(var + 1e-5f) * gw1[ch];
      cc6[0][t] = scl;
      cc6[1][t] = bw1[ch] - m*scl;
      cc6[2][t] = Wp2[ch];
      cc6[3][t] = Wp2[256+ch];
      cc6[4][t] = Wp2[512+ch];
      cc6[5][t] = bp2[ch];
    }
    {
      int e = t;
#pragma unroll
      for (int it = 0; it < 4; ++it, e += 256) {
        int r = e >> 5, c = e & 31;
        Bs[r][c] = Ww1[(k0 + r)*32 + c];
      }
    }
    __syncthreads();
#pragma unroll
    for (int it = 0; it < 8; ++it) {
      int c = t & 31;
      int r = it*8 + (t >> 5);
      float v = xk[(size_t)jrow[r]*256 + k0 + c]
              - xq[(size_t)(base4 + (r >> 4))*256 + k0 + c]
              + prv[r][0]*cc6[2][c] + prv[r][1]*cc6[3][c] + prv[r][2]*cc6[4][c]
              + cc6[5][c];
      As[c][r] = fmaxf(v*cc6[0][c] + cc6[1][c], 0.0f);
    }
    __syncthreads();
#pragma unroll
    for (int kk = 0; kk < 32; ++kk) {
      float a0 = As[kk][tm*2], a1 = As[kk][tm*2+1];
      float b0 = Bs[kk][tn*4], b1 = Bs[kk][tn*4+1], b2 = Bs[kk][tn*4+2], b3 = Bs[kk][tn*4+3];
      acc[0][0] += a0*b0; acc[0][1] += a0*b1; acc[0][2] += a0*b2; acc[0][3] += a0*b3;
      acc[1][0] += a1*b0; acc[1][1] += a1*b1; acc[1][2] += a1*b2; acc[1][3] += a1*b3;
    }
    __syncthreads();
  }
#pragma unroll
  for (int i = 0; i < 2; ++i) {
    size_t grow = (size_t)blockIdx.x*64 + tm*2 + i;
#pragma unroll
    for (int j = 0; j < 4; ++j) {
      int col = tn*4 + j;
      w1[grow*32 + col] = acc[i][j] + bww1[col];
    }
  }
}

// ---------------------------------------------------------------- second linear_w + softmax + aggregate
__launch_bounds__(256)
__global__ void aggr_k(const float* __restrict__ w1, const float* sw1,
                       const float* gw2, const float* bw2,
                       const float* __restrict__ Ww2, const float* bww2,
                       const float* __restrict__ xv,
                       const float* __restrict__ p, const int* __restrict__ idx,
                       const float* Wp1, const float* bp1, const float* gp, const float* bpp,
                       const float* sp, const float* __restrict__ Wp2, const float* bp2,
                       float* __restrict__ y) {
  __shared__ float lw1[16][32];
  __shared__ float lW2[32][32];
  __shared__ float sw2[16][33];
  __shared__ float prv[16][4];
  __shared__ int   jidx[16];
  int i = blockIdx.x, t = threadIdx.x;
  for (int e = t; e < 1024; e += 256) lW2[e >> 5][e & 31] = Ww2[e];
  for (int e = t; e < 512; e += 256) {
    int c32 = e & 31;
    float v = w1[(size_t)i*512 + e];
    v = fmaxf(bn_ap(v, sw1, 32, c32, INV_NK, gw2[c32], bw2[c32]), 0.0f);
    lw1[e >> 5][c32] = v;
  }
  if (t < 16) jidx[t] = idx[i*16 + t] & 8191;
  __syncthreads();
  if (t < 16) {
    float o3[3];
    comp_prv(p, i, jidx[t], Wp1, bp1, gp, bpp, sp, o3);
    prv[t][0] = o3[0]; prv[t][1] = o3[1]; prv[t][2] = o3[2];
  }
  for (int e = t; e < 512; e += 256) {
    int k = e >> 5, c32 = e & 31;
    float a = bww2[c32];
#pragma unroll
    for (int j = 0; j < 32; ++j) a += lw1[k][j] * lW2[j][c32];
    sw2[k][c32] = a;
  }
  __syncthreads();
  if (t < 32) {
    float mx = -3.0e38f;
#pragma unroll
    for (int k = 0; k < 16; ++k) mx = fmaxf(mx, sw2[k][t]);
    float s = 0.f;
#pragma unroll
    for (int k = 0; k < 16; ++k) { float e2 = expf(sw2[k][t] - mx); sw2[k][t] = e2; s += e2; }
    float r = 1.0f / s;
#pragma unroll
    for (int k = 0; k < 16; ++k) sw2[k][t] *= r;
  }
  __syncthreads();
  int c = t;
  float wp0 = Wp2[c], wp1v = Wp2[256+c], wp2v = Wp2[512+c];
  float bbv = bp2[c];
  int c32 = c & 31;
  float acc = 0.f;
#pragma unroll
  for (int k = 0; k < 16; ++k) {
    int j = jidx[k];
    float pr = prv[k][0]*wp0 + prv[k][1]*wp1v + prv[k][2]*wp2v + bbv;
    float xvv = xv[(size_t)j*256 + c];
    acc += (xvv + pr) * sw2[k][c32];
  }
  y[(size_t)i*256 + c] = acc;
}

// ---------------------------------------------------------------- epilogue (x2 only)
__launch_bounds__(256)
__global__ void final_k(const float* __restrict__ t0, const float* s0,
                        const float* g0, const float* b0,
                        const float* __restrict__ t3, const float* s3,
                        const float* g3, const float* b3,
                        float* __restrict__ out) {
  int i = blockIdx.x, c = threadIdx.x;
  size_t off = (size_t)i*256 + c;
  float h0 = fmaxf(bn_ap(t0[off], s0, 256, c, INV_N, g0[c], b0[c]), 0.0f);
  float v3 = bn_ap(t3[off], s3, 256, c, INV_N, g3[c], b3[c]);
  out[24576 + off] = fmaxf(v3 + h0, 0.0f);
}

// ---------------------------------------------------------------- launch
extern "C" void kernel_launch(void* const* d_in, const int* in_sizes, int n_in,
                              void* d_out, int out_size, void* d_ws, size_t ws_size,
                              hipStream_t stream) {
  (void)in_sizes; (void)n_in; (void)out_size; (void)ws_size;
  const float* p    = (const float*)d_in[0];
  const float* x    = (const float*)d_in[1];
  const int*   o    = (const int*)  d_in[2];
  const float* W_pa = (const float*)d_in[3];
  const float* g_pa = (const float*)d_in[4];
  const float* b_pa = (const float*)d_in[5];
  const float* W1   = (const float*)d_in[6];
  const float* g1   = (const float*)d_in[7];
  const float* b1   = (const float*)d_in[8];
  const float* Wq   = (const float*)d_in[9];
  const float* bq   = (const float*)d_in[10];
  const float* Wk   = (const float*)d_in[11];
  const float* bk   = (const float*)d_in[12];
  const float* Wv   = (const float*)d_in[13];
  const float* bv   = (const float*)d_in[14];
  const float* Wp1  = (const float*)d_in[15];
  const float* bp1  = (const float*)d_in[16];
  const float* gp   = (const float*)d_in[17];
  const float* bpp  = (const float*)d_in[18];
  const float* Wp2  = (const float*)d_in[19];
  const float* bp2  = (const float*)d_in[20];
  const float* gw1  = (const float*)d_in[21];
  const float* bw1  = (const float*)d_in[22];
  const float* Ww1  = (const float*)d_in[23];
  const float* bww1 = (const float*)d_in[24];
  const float* gw2  = (const float*)d_in[25];
  const float* bw2  = (const float*)d_in[26];
  const float* Ww2  = (const float*)d_in[27];
  const float* bww2 = (const float*)d_in[28];
  const float* g2   = (const float*)d_in[29];
  const float* b2   = (const float*)d_in[30];
  const float* W3   = (const float*)d_in[31];
  const float* g3   = (const float*)d_in[32];
  const float* b3   = (const float*)d_in[33];

  // workspace layout (~56.5 MB total)
  char* ws = (char*)d_ws;
  float* t0  = (float*)(ws + 0);          // [8192,256] f32
  float* t1  = (float*)(ws + 8388608);    // [8192,256] f32 (later: y)
  float* xq  = (float*)(ws + 16777216);   // [8192,256] f32 (later: t3)
  float* xk  = (float*)(ws + 25165824);   // [8192,256] f32
  float* xv  = (float*)(ws + 33554432);   // [8192,256] f32
  float* w1  = (float*)(ws + 41943040);   // [131072,32] f32 (16 MB)
  int*   idx = (int*)  (ws + 58720256);   // [8192,16] i32
  float* st  = (float*)(ws + 59244544);   // stats block (16 KB)
  float* y  = t1;
  float* t3 = xq;
  // stats offsets (floats): s0=0, s1=512, sw=1024, sy=1536, s3=2048, sw1=2560, sp=2624

  hipMemsetAsync(st, 0, 16384, stream);

  head_k<<<96, 256, 0, stream>>>(p, o, (float*)d_out);

  knn_k<<<8192, 64, 0, stream>>>(p, idx);

  gemm_k<false, false, 64, 64, 4, 4, 32><<<dim3(128, 4), 256, 0, stream>>>(
      x, nullptr, nullptr, nullptr, 0.f, W_pa, nullptr, t0, 8192, 64, 256);
  stats256_k<<<256, 256, 0, stream>>>(t0, st + 0);

  gemm_k<true, false, 64, 64, 4, 4, 32><<<dim3(128, 4), 256, 0, stream>>>(
      t0, st + 0, g_pa, b_pa, INV_N, W1, nullptr, t1, 8192, 256, 256);
  stats256_k<<<256, 256, 0, stream>>>(t1, st + 512);

  gemm_k<true, true, 64, 64, 4, 4, 32><<<dim3(128, 4), 256, 0, stream>>>(
      t1, st + 512, g1, b1, INV_N, Wq, bq, xq, 8192, 256, 256);
  gemm_k<true, true, 64, 64, 4, 4, 32><<<dim3(128, 4), 256, 0, stream>>>(
      t1, st + 512, g1, b1, INV_N, Wk, bk, xk, 8192, 256, 256);
  gemm_k<true, true, 64, 64, 4, 4, 32><<<dim3(128, 4), 256, 0, stream>>>(
      t1, st + 512, g1, b1, INV_N, Wv, bv, xv, 8192, 256, 256);

  prstats_k<<<128, 256, 0, stream>>>(p, idx, Wp1, bp1, st + 2624);

  wstats_k<<<256, 256, 0, stream>>>(xk, xq, p, idx, Wp1, bp1, gp, bpp,
                                    st + 2624, Wp2, bp2, st + 1024);

  w1gemm_k<<<2048, 256, 0, stream>>>(xk, xq, p, idx, Wp1, bp1, gp, bpp,
                                     st + 2624, Wp2, bp2, st + 1024,
                                     gw1, bw1, Ww1, bww1, w1);
  stats32_k<<<512, 256, 0, stream>>>(w1, st + 2560);

  aggr_k<<<8192, 256, 0, stream>>>(w1, st + 2560, gw2, bw2, Ww2, bww2, xv,
                                   p, idx, Wp1, bp1, gp, bpp, st + 2624,
                                   Wp2, bp2, y);
  stats256_k<<<256, 256, 0, stream>>>(y, st + 1536);

  gemm_k<true, false, 64, 64, 4, 4, 32><<<dim3(128, 4), 256, 0, stream>>>(
      y, st + 1536, g2, b2, INV_N, W3, nullptr, t3, 8192, 256, 256);
  stats256_k<<<256, 256, 0, stream>>>(t3, st + 2048);

  final_k<<<8192, 256, 0, stream>>>(t0, st + 0, g_pa, b_pa,
                                    t3, st + 2048, g3, b3, (float*)d_out);
}

// Round 4
// 613.218 us; speedup vs baseline: 1.5401x; 1.5401x over previous
//
#include <hip/hip_runtime.h>
#include <hip/hip_bf16.h>

// N=8192, K=16, CIN=64, C=256, S=8, C/S=32 ; all float tensors are float32.
#define INV_N  (1.0f/8192.0f)
#define INV_NK (1.0f/131072.0f)

__device__ __forceinline__ float bn_ap(float v, const float* st, int C, int ch,
                                       float inv, float g, float b) {
  float m = st[ch] * inv;
  float var = st[C + ch] * inv - m * m;
  return (v - m) * rsqrtf(var + 1e-5f) * g + b;
}

// ---------------------------------------------------------------- head: p copy + o
__launch_bounds__(256)
__global__ void head_k(const float* __restrict__ p, const int* __restrict__ o,
                       float* __restrict__ out) {
  int e = blockIdx.x*256 + threadIdx.x;
  if (e < 24576) out[e] = p[e];
  if (e == 0) out[24576 + 2097152] = (float)o[0];
}

// ---------------------------------------------------------------- pack (x,y,z,|p|^2)
__launch_bounds__(256)
__global__ void pack4_k(const float* __restrict__ p, float4* __restrict__ pp) {
  int i = blockIdx.x*256 + threadIdx.x;   // 8192
  float x = p[i*3+0], y = p[i*3+1], z = p[i*3+2];
  pp[i] = make_float4(x, y, z, (x*x + y*y) + z*z);
}

// ---------------------------------------------------------------- KNN v2
// one wave per query; 128 candidates/lane; cheap parallel sorted-insert;
// wave-wide 16-round merge.
__launch_bounds__(64)
__global__ void knn_k(const float4* __restrict__ pp, int* __restrict__ idxo) {
  int q = blockIdx.x;
  int lane = threadIdx.x;
  float4 qv = pp[q];                       // wave-uniform -> s_load
  float d[16]; int id[16];
#pragma unroll
  for (int s = 0; s < 16; ++s) { d[s] = 3.0e38f; id[s] = -1; }
#pragma unroll 4
  for (int it = 0; it < 128; ++it) {
    int j = it*64 + lane;                  // coalesced float4 load
    float4 c = pp[j];
    float dot = qv.x*c.x + qv.y*c.y + qv.z*c.z;
    float d2 = __fmaf_rn(-2.0f, dot, qv.w + c.w);
    if (d2 < d[15]) {
      bool lts = true;                     // d2 < d[15]
#pragma unroll
      for (int s = 15; s >= 1; --s) {
        bool ltp = d2 < d[s-1];
        d[s]  = lts ? (ltp ? d[s-1]  : d2) : d[s];
        id[s] = lts ? (ltp ? id[s-1] : j ) : id[s];
        lts = ltp;
      }
      if (lts) { d[0] = d2; id[0] = j; }
    }
  }
  // merge 64 sorted lists -> global top-16
  for (int r = 0; r < 16; ++r) {
    float bd = d[0]; int bi = id[0];
#pragma unroll
    for (int m = 1; m < 64; m <<= 1) {
      float od = __shfl_xor(bd, m);
      int   oi = __shfl_xor(bi, m);
      if (od < bd || (od == bd && oi < bi)) { bd = od; bi = oi; }
    }
    if (lane == 0) idxo[q*16 + r] = bi;
    if (d[0] == bd && id[0] == bi) {
#pragma unroll
      for (int s = 0; s < 15; ++s) { d[s] = d[s+1]; id[s] = id[s+1]; }
      d[15] = 3.0e38f; id[15] = -1;
    }
  }
}

// ---------------------------------------------------------------- GEMM
template<bool BNA, bool BIAS, int BM, int BN, int TM, int TN, int BK>
__launch_bounds__(256)
__global__ void gemm_k(const float* __restrict__ A, const float* __restrict__ st,
                       const float* __restrict__ g, const float* __restrict__ bb,
                       float inv_cnt,
                       const float* __restrict__ W, const float* __restrict__ bias,
                       float* __restrict__ out, int M, int KA, int NOUT) {
  constexpr int THREADS = (BM/TM) * (BN/TN);
  __shared__ float As[BK][BM + 4];
  __shared__ float Bs[BK][BN + 4];
  int t = threadIdx.x;
  int tn = t % (BN/TN), tm = t / (BN/TN);
  int m0 = blockIdx.x * BM, n0 = blockIdx.y * BN;
  float acc[TM][TN] = {};
  for (int k0 = 0; k0 < KA; k0 += BK) {
#pragma unroll
    for (int e = t; e < BM*BK; e += THREADS) {
      int r = e / BK, c = e % BK;
      float v = A[(size_t)(m0 + r)*KA + (k0 + c)];
      if (BNA) {
        int ch = k0 + c;
        v = fmaxf(bn_ap(v, st, KA, ch, inv_cnt, g[ch], bb[ch]), 0.0f);
      }
      As[c][r] = v;
    }
#pragma unroll
    for (int e = t; e < BK*BN; e += THREADS) {
      int r = e / BN, c = e % BN;
      Bs[r][c] = W[(size_t)(k0 + r)*NOUT + (n0 + c)];
    }
    __syncthreads();
#pragma unroll
    for (int kk = 0; kk < BK; ++kk) {
      float a[TM], b[TN];
#pragma unroll
      for (int i = 0; i < TM; ++i) a[i] = As[kk][tm*TM + i];
#pragma unroll
      for (int j = 0; j < TN; ++j) b[j] = Bs[kk][tn*TN + j];
#pragma unroll
      for (int i = 0; i < TM; ++i)
#pragma unroll
        for (int j = 0; j < TN; ++j) acc[i][j] += a[i]*b[j];
    }
    __syncthreads();
  }
#pragma unroll
  for (int i = 0; i < TM; ++i) {
    int r = m0 + tm*TM + i;
#pragma unroll
    for (int j = 0; j < TN; ++j) {
      int c = n0 + tn*TN + j;
      float v = acc[i][j];
      if (BIAS) v += bias[c];
      out[(size_t)r*NOUT + c] = v;
    }
  }
}

// ---------------------------------------------------------------- stats
__launch_bounds__(256)
__global__ void stats256_k(const float* __restrict__ X, float* __restrict__ st) {
  int c = threadIdx.x;
  int r0 = blockIdx.x * 32;
  float s1 = 0.f, s2 = 0.f;
  for (int r = 0; r < 32; ++r) {
    float v = X[(size_t)(r0 + r)*256 + c];
    s1 += v; s2 += v*v;
  }
  atomicAdd(&st[c], s1);
  atomicAdd(&st[256 + c], s2);
}

__launch_bounds__(256)
__global__ void stats32_k(const float* __restrict__ X, float* __restrict__ st) {
  int c = threadIdx.x & 31, rg = threadIdx.x >> 5;
  size_t r0 = (size_t)blockIdx.x * 256;
  float s1 = 0.f, s2 = 0.f;
  for (int r = rg; r < 256; r += 8) {
    float v = X[(r0 + r)*32 + c];
    s1 += v; s2 += v*v;
  }
  __shared__ float red1[256], red2[256];
  red1[threadIdx.x] = s1; red2[threadIdx.x] = s2;
  __syncthreads();
  if (threadIdx.x < 32) {
    float a = 0.f, b = 0.f;
#pragma unroll
    for (int gI = 0; gI < 8; ++gI) { a += red1[gI*32 + threadIdx.x]; b += red2[gI*32 + threadIdx.x]; }
    atomicAdd(&st[threadIdx.x], a);
    atomicAdd(&st[32 + threadIdx.x], b);
  }
}

// ---------------------------------------------------------------- p_r helpers
__device__ __forceinline__ void comp_pr1(const float* p, int i, int j,
                                         const float* Wp1, const float* bp1,
                                         float pr1[3]) {
  float rx = p[j*3+0] - p[i*3+0];
  float ry = p[j*3+1] - p[i*3+1];
  float rz = p[j*3+2] - p[i*3+2];
#pragma unroll
  for (int c = 0; c < 3; ++c)
    pr1[c] = rx*Wp1[c] + ry*Wp1[3+c] + rz*Wp1[6+c] + bp1[c];
}

__device__ __forceinline__ void comp_prv(const float* p, int i, int j,
                                         const float* Wp1, const float* bp1,
                                         const float* gp, const float* bpp,
                                         const float* sp, float o3[3]) {
  float pr1[3];
  comp_pr1(p, i, j, Wp1, bp1, pr1);
#pragma unroll
  for (int c = 0; c < 3; ++c)
    o3[c] = fmaxf(bn_ap(pr1[c], sp, 3, c, INV_NK, gp[c], bpp[c]), 0.0f);
}

__launch_bounds__(256)
__global__ void prstats_k(const float* __restrict__ p, const int* __restrict__ idx,
                          const float* Wp1, const float* bp1, float* __restrict__ sp) {
  float s[3] = {0,0,0}, s2[3] = {0,0,0};
  for (int it = 0; it < 4; ++it) {
    int e = blockIdx.x*1024 + it*256 + threadIdx.x;
    int i = e >> 4;
    int j = idx[e] & 8191;
    float pr1[3];
    comp_pr1(p, i, j, Wp1, bp1, pr1);
#pragma unroll
    for (int c = 0; c < 3; ++c) { s[c] += pr1[c]; s2[c] += pr1[c]*pr1[c]; }
  }
#pragma unroll
  for (int m = 1; m < 64; m <<= 1) {
#pragma unroll
    for (int c = 0; c < 3; ++c) {
      s[c]  += __shfl_xor(s[c],  m);
      s2[c] += __shfl_xor(s2[c], m);
    }
  }
  __shared__ float red[4][6];
  int wv = threadIdx.x >> 6, lane = threadIdx.x & 63;
  if (lane == 0) {
#pragma unroll
    for (int c = 0; c < 3; ++c) { red[wv][c] = s[c]; red[wv][3+c] = s2[c]; }
  }
  __syncthreads();
  if (threadIdx.x < 6) {
    float v = red[0][threadIdx.x] + red[1][threadIdx.x] +
              red[2][threadIdx.x] + red[3][threadIdx.x];
    atomicAdd(&sp[threadIdx.x], v);
  }
}

// ---------------------------------------------------------------- stats of w (no materialization)
__launch_bounds__(256)
__global__ void wstats_k(const float* __restrict__ xk, const float* __restrict__ xq,
                         const float* __restrict__ p, const int* __restrict__ idx,
                         const float* Wp1, const float* bp1, const float* gp, const float* bpp,
                         const float* sp, const float* __restrict__ Wp2, const float* bp2,
                         float* __restrict__ sw) {
  __shared__ float prv[32][16][4];
  __shared__ int   jidx[32][16];
  int base = blockIdx.x * 32;
  int t = threadIdx.x;
  for (int e = t; e < 512; e += 256) {
    int pt = e >> 4, k = e & 15;
    int j = idx[(base + pt)*16 + k] & 8191;
    jidx[pt][k] = j;
    float o3[3];
    comp_prv(p, base + pt, j, Wp1, bp1, gp, bpp, sp, o3);
    prv[pt][k][0] = o3[0]; prv[pt][k][1] = o3[1]; prv[pt][k][2] = o3[2];
  }
  __syncthreads();
  int c = t;
  float wp0 = Wp2[c], wp1v = Wp2[256+c], wp2v = Wp2[512+c];
  float bbv = bp2[c];
  float s1 = 0.f, s2 = 0.f;
  for (int pt = 0; pt < 32; ++pt) {
    int i = base + pt;
    float xqv = xq[(size_t)i*256 + c];
#pragma unroll
    for (int k = 0; k < 16; ++k) {
      int j = jidx[pt][k];
      float pr = prv[pt][k][0]*wp0 + prv[pt][k][1]*wp1v + prv[pt][k][2]*wp2v + bbv;
      float wval = xk[(size_t)j*256 + c] - xqv + pr;
      s1 += wval; s2 += wval*wval;
    }
  }
  atomicAdd(&sw[c], s1);
  atomicAdd(&sw[256 + c], s2);
}

// ---------------------------------------------------------------- fused: w1 = BNReLU(w) @ Ww1 + bww1
__launch_bounds__(256)
__global__ void w1gemm_k(const float* __restrict__ xk, const float* __restrict__ xq,
                         const float* __restrict__ p, const int* __restrict__ idx,
                         const float* Wp1, const float* bp1, const float* gp, const float* bpp,
                         const float* sp, const float* __restrict__ Wp2, const float* bp2,
                         const float* sw, const float* gw1, const float* bw1,
                         const float* __restrict__ Ww1, const float* bww1,
                         float* __restrict__ w1) {
  __shared__ float As[32][65];
  __shared__ float Bs[32][33];
  __shared__ float prv[64][4];
  __shared__ int   jrow[64];
  __shared__ float cc6[6][32];   // scl, sft, wp2r0, wp2r1, wp2r2, bp2
  int t = threadIdx.x;
  int base4 = blockIdx.x * 4;
  if (t < 64) {
    int grow = blockIdx.x*64 + t;
    int i = grow >> 4;
    int j = idx[grow] & 8191;
    jrow[t] = j;
    float o3[3];
    comp_prv(p, i, j, Wp1, bp1, gp, bpp, sp, o3);
    prv[t][0] = o3[0]; prv[t][1] = o3[1]; prv[t][2] = o3[2];
  }
  int tn = t & 7, tm = t >> 3;
  float acc[2][4] = {};
  for (int k0 = 0; k0 < 256; k0 += 32) {
    if (t < 32) {
      int ch = k0 + t;
      float m = sw[ch] * INV_NK;
      float var = sw[256+ch]*INV_NK - m*m;
      float scl = rsqrtf(var + 1e-5f) * gw1[ch];
      cc6[0][t] = scl;
      cc6[1][t] = bw1[ch] - m*scl;
      cc6[2][t] = Wp2[ch];
      cc6[3][t] = Wp2[256+ch];
      cc6[4][t] = Wp2[512+ch];
      cc6[5][t] = bp2[ch];
    }
    {
      int e = t;
#pragma unroll
      for (int it = 0; it < 4; ++it, e += 256) {
        int r = e >> 5, c = e & 31;
        Bs[r][c] = Ww1[(k0 + r)*32 + c];
      }
    }
    __syncthreads();
#pragma unroll
    for (int it = 0; it < 8; ++it) {
      int c = t & 31;
      int r = it*8 + (t >> 5);
      float v = xk[(size_t)jrow[r]*256 + k0 + c]
              - xq[(size_t)(base4 + (r >> 4))*256 + k0 + c]
              + prv[r][0]*cc6[2][c] + prv[r][1]*cc6[3][c] + prv[r][2]*cc6[4][c]
              + cc6[5][c];
      As[c][r] = fmaxf(v*cc6[0][c] + cc6[1][c], 0.0f);
    }
    __syncthreads();
#pragma unroll
    for (int kk = 0; kk < 32; ++kk) {
      float a0 = As[kk][tm*2], a1 = As[kk][tm*2+1];
      float b0 = Bs[kk][tn*4], b1 = Bs[kk][tn*4+1], b2 = Bs[kk][tn*4+2], b3 = Bs[kk][tn*4+3];
      acc[0][0] += a0*b0; acc[0][1] += a0*b1; acc[0][2] += a0*b2; acc[0][3] += a0*b3;
      acc[1][0] += a1*b0; acc[1][1] += a1*b1; acc[1][2] += a1*b2; acc[1][3] += a1*b3;
    }
    __syncthreads();
  }
#pragma unroll
  for (int i = 0; i < 2; ++i) {
    size_t grow = (size_t)blockIdx.x*64 + tm*2 + i;
#pragma unroll
    for (int j = 0; j < 4; ++j) {
      int col = tn*4 + j;
      w1[grow*32 + col] = acc[i][j] + bww1[col];
    }
  }
}

// ---------------------------------------------------------------- second linear_w + softmax + aggregate
__launch_bounds__(256)
__global__ void aggr_k(const float* __restrict__ w1, const float* sw1,
                       const float* gw2, const float* bw2,
                       const float* __restrict__ Ww2, const float* bww2,
                       const float* __restrict__ xv,
                       const float* __restrict__ p, const int* __restrict__ idx,
                       const float* Wp1, const float* bp1, const float* gp, const float* bpp,
                       const float* sp, const float* __restrict__ Wp2, const float* bp2,
                       float* __restrict__ y) {
  __shared__ float lw1[16][32];
  __shared__ float lW2[32][32];
  __shared__ float sw2[16][33];
  __shared__ float prv[16][4];
  __shared__ int   jidx[16];
  int i = blockIdx.x, t = threadIdx.x;
  for (int e = t; e < 1024; e += 256) lW2[e >> 5][e & 31] = Ww2[e];
  for (int e = t; e < 512; e += 256) {
    int c32 = e & 31;
    float v = w1[(size_t)i*512 + e];
    v = fmaxf(bn_ap(v, sw1, 32, c32, INV_NK, gw2[c32], bw2[c32]), 0.0f);
    lw1[e >> 5][c32] = v;
  }
  if (t < 16) jidx[t] = idx[i*16 + t] & 8191;
  __syncthreads();
  if (t < 16) {
    float o3[3];
    comp_prv(p, i, jidx[t], Wp1, bp1, gp, bpp, sp, o3);
    prv[t][0] = o3[0]; prv[t][1] = o3[1]; prv[t][2] = o3[2];
  }
  for (int e = t; e < 512; e += 256) {
    int k = e >> 5, c32 = e & 31;
    float a = bww2[c32];
#pragma unroll
    for (int j = 0; j < 32; ++j) a += lw1[k][j] * lW2[j][c32];
    sw2[k][c32] = a;
  }
  __syncthreads();
  if (t < 32) {
    float mx = -3.0e38f;
#pragma unroll
    for (int k = 0; k < 16; ++k) mx = fmaxf(mx, sw2[k][t]);
    float s = 0.f;
#pragma unroll
    for (int k = 0; k < 16; ++k) { float e2 = expf(sw2[k][t] - mx); sw2[k][t] = e2; s += e2; }
    float r = 1.0f / s;
#pragma unroll
    for (int k = 0; k < 16; ++k) sw2[k][t] *= r;
  }
  __syncthreads();
  int c = t;
  float wp0 = Wp2[c], wp1v = Wp2[256+c], wp2v = Wp2[512+c];
  float bbv = bp2[c];
  int c32 = c & 31;
  float acc = 0.f;
#pragma unroll
  for (int k = 0; k < 16; ++k) {
    int j = jidx[k];
    float pr = prv[k][0]*wp0 + prv[k][1]*wp1v + prv[k][2]*wp2v + bbv;
    float xvv = xv[(size_t)j*256 + c];
    acc += (xvv + pr) * sw2[k][c32];
  }
  y[(size_t)i*256 + c] = acc;
}

// ---------------------------------------------------------------- epilogue (x2 only)
__launch_bounds__(256)
__global__ void final_k(const float* __restrict__ t0, const float* s0,
                        const float* g0, const float* b0,
                        const float* __restrict__ t3, const float* s3,
                        const float* g3, const float* b3,
                        float* __restrict__ out) {
  int i = blockIdx.x, c = threadIdx.x;
  size_t off = (size_t)i*256 + c;
  float h0 = fmaxf(bn_ap(t0[off], s0, 256, c, INV_N, g0[c], b0[c]), 0.0f);
  float v3 = bn_ap(t3[off], s3, 256, c, INV_N, g3[c], b3[c]);
  out[24576 + off] = fmaxf(v3 + h0, 0.0f);
}

// ---------------------------------------------------------------- launch
extern "C" void kernel_launch(void* const* d_in, const int* in_sizes, int n_in,
                              void* d_out, int out_size, void* d_ws, size_t ws_size,
                              hipStream_t stream) {
  (void)in_sizes; (void)n_in; (void)out_size; (void)ws_size;
  const float* p    = (const float*)d_in[0];
  const float* x    = (const float*)d_in[1];
  const int*   o    = (const int*)  d_in[2];
  const float* W_pa = (const float*)d_in[3];
  const float* g_pa = (const float*)d_in[4];
  const float* b_pa = (const float*)d_in[5];
  const float* W1   = (const float*)d_in[6];
  const float* g1   = (const float*)d_in[7];
  const float* b1   = (const float*)d_in[8];
  const float* Wq   = (const float*)d_in[9];
  const float* bq   = (const float*)d_in[10];
  const float* Wk   = (const float*)d_in[11];
  const float* bk   = (const float*)d_in[12];
  const float* Wv   = (const float*)d_in[13];
  const float* bv   = (const float*)d_in[14];
  const float* Wp1  = (const float*)d_in[15];
  const float* bp1  = (const float*)d_in[16];
  const float* gp   = (const float*)d_in[17];
  const float* bpp  = (const float*)d_in[18];
  const float* Wp2  = (const float*)d_in[19];
  const float* bp2  = (const float*)d_in[20];
  const float* gw1  = (const float*)d_in[21];
  const float* bw1  = (const float*)d_in[22];
  const float* Ww1  = (const float*)d_in[23];
  const float* bww1 = (const float*)d_in[24];
  const float* gw2  = (const float*)d_in[25];
  const float* bw2  = (const float*)d_in[26];
  const float* Ww2  = (const float*)d_in[27];
  const float* bww2 = (const float*)d_in[28];
  const float* g2   = (const float*)d_in[29];
  const float* b2   = (const float*)d_in[30];
  const float* W3   = (const float*)d_in[31];
  const float* g3   = (const float*)d_in[32];
  const float* b3   = (const float*)d_in[33];

  // workspace layout (~56.5 MB total)
  char* ws = (char*)d_ws;
  float* t0  = (float*)(ws + 0);          // [8192,256] f32
  float* t1  = (float*)(ws + 8388608);    // [8192,256] f32 (later: y)
  float* xq  = (float*)(ws + 16777216);   // [8192,256] f32 (later: t3)
  float* xk  = (float*)(ws + 25165824);   // [8192,256] f32
  float* xv  = (float*)(ws + 33554432);   // [8192,256] f32
  float* w1  = (float*)(ws + 41943040);   // [131072,32] f32 (16 MB)
  int*   idx = (int*)  (ws + 58720256);   // [8192,16] i32
  float* st  = (float*)(ws + 59244544);   // stats block (16 KB)
  float* y  = t1;
  float* t3 = xq;
  // pp (float4 packed points, 128 KB) aliases w1's region: knn reads it before
  // w1gemm_k (much later in the same stream) writes w1. Safe by stream order.
  float4* pp = (float4*)(ws + 41943040);
  // stats offsets (floats): s0=0, s1=512, sw=1024, sy=1536, s3=2048, sw1=2560, sp=2624

  hipMemsetAsync(st, 0, 16384, stream);

  head_k<<<96, 256, 0, stream>>>(p, o, (float*)d_out);

  pack4_k<<<32, 256, 0, stream>>>(p, pp);
  knn_k<<<8192, 64, 0, stream>>>(pp, idx);

  gemm_k<false, false, 64, 64, 4, 4, 32><<<dim3(128, 4), 256, 0, stream>>>(
      x, nullptr, nullptr, nullptr, 0.f, W_pa, nullptr, t0, 8192, 64, 256);
  stats256_k<<<256, 256, 0, stream>>>(t0, st + 0);

  gemm_k<true, false, 64, 64, 4, 4, 32><<<dim3(128, 4), 256, 0, stream>>>(
      t0, st + 0, g_pa, b_pa, INV_N, W1, nullptr, t1, 8192, 256, 256);
  stats256_k<<<256, 256, 0, stream>>>(t1, st + 512);

  gemm_k<true, true, 64, 64, 4, 4, 32><<<dim3(128, 4), 256, 0, stream>>>(
      t1, st + 512, g1, b1, INV_N, Wq, bq, xq, 8192, 256, 256);
  gemm_k<true, true, 64, 64, 4, 4, 32><<<dim3(128, 4), 256, 0, stream>>>(
      t1, st + 512, g1, b1, INV_N, Wk, bk, xk, 8192, 256, 256);
  gemm_k<true, true, 64, 64, 4, 4, 32><<<dim3(128, 4), 256, 0, stream>>>(
      t1, st + 512, g1, b1, INV_N, Wv, bv, xv, 8192, 256, 256);

  prstats_k<<<128, 256, 0, stream>>>(p, idx, Wp1, bp1, st + 2624);

  wstats_k<<<256, 256, 0, stream>>>(xk, xq, p, idx, Wp1, bp1, gp, bpp,
                                    st + 2624, Wp2, bp2, st + 1024);

  w1gemm_k<<<2048, 256, 0, stream>>>(xk, xq, p, idx, Wp1, bp1, gp, bpp,
                                     st + 2624, Wp2, bp2, st + 1024,
                                     gw1, bw1, Ww1, bww1, w1);
  stats32_k<<<512, 256, 0, stream>>>(w1, st + 2560);

  aggr_k<<<8192, 256, 0, stream>>>(w1, st + 2560, gw2, bw2, Ww2, bww2, xv,
                                   p, idx, Wp1, bp1, gp, bpp, st + 2624,
                                   Wp2, bp2, y);
  stats256_k<<<256, 256, 0, stream>>>(y, st + 1536);

  gemm_k<true, false, 64, 64, 4, 4, 32><<<dim3(128, 4), 256, 0, stream>>>(
      y, st + 1536, g2, b2, INV_N, W3, nullptr, t3, 8192, 256, 256);
  stats256_k<<<256, 256, 0, stream>>>(t3, st + 2048);

  final_k<<<8192, 256, 0, stream>>>(t0, st + 0, g_pa, b_pa,
                                    t3, st + 2048, g3, b3, (float*)d_out);
}

// Round 5
// 474.189 us; speedup vs baseline: 1.9917x; 1.2932x over previous
//
#include <hip/hip_runtime.h>
#include <hip/hip_bf16.h>

// N=8192, K=16, CIN=64, C=256, S=8, C/S=32 ; all float tensors are float32.
#define INV_N  (1.0f/8192.0f)
#define INV_NK (1.0f/131072.0f)

__device__ __forceinline__ float bn_ap(float v, const float* st, int C, int ch,
                                       float inv, float g, float b) {
  float m = st[ch] * inv;
  float var = st[C + ch] * inv - m * m;
  return (v - m) * rsqrtf(var + 1e-5f) * g + b;
}

// ---------------------------------------------------------------- head: p copy + o
__launch_bounds__(256)
__global__ void head_k(const float* __restrict__ p, const int* __restrict__ o,
                       float* __restrict__ out) {
  int e = blockIdx.x*256 + threadIdx.x;
  if (e < 24576) out[e] = p[e];
  if (e == 0) out[24576 + 2097152] = (float)o[0];
}

// ---------------------------------------------------------------- pack (x,y,z,|p|^2)
__launch_bounds__(256)
__global__ void pack4_k(const float* __restrict__ p, float4* __restrict__ pp) {
  int i = blockIdx.x*256 + threadIdx.x;   // 8192
  float x = p[i*3+0], y = p[i*3+1], z = p[i*3+2];
  pp[i] = make_float4(x, y, z, (x*x + y*y) + z*z);
}

// ---------------------------------------------------------------- KNN v3
// 4 waves/block, one query per wave. Branchless med3 sorted-insert on
// index-packed distances (low 13 bits = candidate index).
__launch_bounds__(256)
__global__ void knn_k(const float4* __restrict__ pp, int* __restrict__ idxo) {
  int wave = threadIdx.x >> 6;
  int lane = threadIdx.x & 63;
  int q = blockIdx.x*4 + wave;
  float4 qv = pp[q];
  const float BIG = __uint_as_float(0x7F7FFFFFu);
  float d[16];
#pragma unroll
  for (int s = 0; s < 16; ++s) d[s] = BIG;
#pragma unroll 4
  for (int it = 0; it < 128; ++it) {
    int j = it*64 + lane;                  // coalesced float4 load
    float4 c = pp[j];
    float dot = qv.x*c.x + (qv.y*c.y + qv.z*c.z);
    float d2 = __fmaf_rn(-2.0f, dot, qv.w + c.w);
    float pk = __uint_as_float((__float_as_uint(d2) & 0xFFFFE000u) | (unsigned)j);
    // branchless sorted insert: d[s] = med3(d[s-1], pk, d[s]) (list ascending)
#pragma unroll
    for (int s = 15; s >= 1; --s)
      d[s] = fminf(fmaxf(d[s-1], pk), d[s]);
    d[0] = fminf(d[0], pk);
  }
  // wave merge: 16 rounds of min-reduce; packed values are globally unique.
  for (int r = 0; r < 16; ++r) {
    float bd = d[0];
#pragma unroll
    for (int m = 1; m < 64; m <<= 1)
      bd = fminf(bd, __shfl_xor(bd, m));
    if (lane == 0) idxo[q*16 + r] = (int)(__float_as_uint(bd) & 0x1FFFu);
    if (d[0] == bd) {                      // unique -> exactly one lane shifts
#pragma unroll
      for (int s = 0; s < 15; ++s) d[s] = d[s+1];
      d[15] = BIG;
    }
  }
}

// ---------------------------------------------------------------- GEMM
template<bool BNA, bool BIAS, int BM, int BN, int TM, int TN, int BK>
__launch_bounds__(256)
__global__ void gemm_k(const float* __restrict__ A, const float* __restrict__ st,
                       const float* __restrict__ g, const float* __restrict__ bb,
                       float inv_cnt,
                       const float* __restrict__ W, const float* __restrict__ bias,
                       float* __restrict__ out, int M, int KA, int NOUT) {
  constexpr int THREADS = (BM/TM) * (BN/TN);
  __shared__ float As[BK][BM + 4];
  __shared__ float Bs[BK][BN + 4];
  int t = threadIdx.x;
  int tn = t % (BN/TN), tm = t / (BN/TN);
  int m0 = blockIdx.x * BM, n0 = blockIdx.y * BN;
  float acc[TM][TN] = {};
  for (int k0 = 0; k0 < KA; k0 += BK) {
#pragma unroll
    for (int e = t; e < BM*BK; e += THREADS) {
      int r = e / BK, c = e % BK;
      float v = A[(size_t)(m0 + r)*KA + (k0 + c)];
      if (BNA) {
        int ch = k0 + c;
        v = fmaxf(bn_ap(v, st, KA, ch, inv_cnt, g[ch], bb[ch]), 0.0f);
      }
      As[c][r] = v;
    }
#pragma unroll
    for (int e = t; e < BK*BN; e += THREADS) {
      int r = e / BN, c = e % BN;
      Bs[r][c] = W[(size_t)(k0 + r)*NOUT + (n0 + c)];
    }
    __syncthreads();
#pragma unroll
    for (int kk = 0; kk < BK; ++kk) {
      float a[TM], b[TN];
#pragma unroll
      for (int i = 0; i < TM; ++i) a[i] = As[kk][tm*TM + i];
#pragma unroll
      for (int j = 0; j < TN; ++j) b[j] = Bs[kk][tn*TN + j];
#pragma unroll
      for (int i = 0; i < TM; ++i)
#pragma unroll
        for (int j = 0; j < TN; ++j) acc[i][j] += a[i]*b[j];
    }
    __syncthreads();
  }
#pragma unroll
  for (int i = 0; i < TM; ++i) {
    int r = m0 + tm*TM + i;
#pragma unroll
    for (int j = 0; j < TN; ++j) {
      int c = n0 + tn*TN + j;
      float v = acc[i][j];
      if (BIAS) v += bias[c];
      out[(size_t)r*NOUT + c] = v;
    }
  }
}

// ---------------------------------------------------------------- stats
__launch_bounds__(256)
__global__ void stats256_k(const float* __restrict__ X, float* __restrict__ st) {
  int c = threadIdx.x;
  int r0 = blockIdx.x * 32;
  float s1 = 0.f, s2 = 0.f;
  for (int r = 0; r < 32; ++r) {
    float v = X[(size_t)(r0 + r)*256 + c];
    s1 += v; s2 += v*v;
  }
  atomicAdd(&st[c], s1);
  atomicAdd(&st[256 + c], s2);
}

__launch_bounds__(256)
__global__ void stats32_k(const float* __restrict__ X, float* __restrict__ st) {
  int c = threadIdx.x & 31, rg = threadIdx.x >> 5;
  size_t r0 = (size_t)blockIdx.x * 256;
  float s1 = 0.f, s2 = 0.f;
  for (int r = rg; r < 256; r += 8) {
    float v = X[(r0 + r)*32 + c];
    s1 += v; s2 += v*v;
  }
  __shared__ float red1[256], red2[256];
  red1[threadIdx.x] = s1; red2[threadIdx.x] = s2;
  __syncthreads();
  if (threadIdx.x < 32) {
    float a = 0.f, b = 0.f;
#pragma unroll
    for (int gI = 0; gI < 8; ++gI) { a += red1[gI*32 + threadIdx.x]; b += red2[gI*32 + threadIdx.x]; }
    atomicAdd(&st[threadIdx.x], a);
    atomicAdd(&st[32 + threadIdx.x], b);
  }
}

// ---------------------------------------------------------------- p_r helpers
__device__ __forceinline__ void comp_pr1(const float* p, int i, int j,
                                         const float* Wp1, const float* bp1,
                                         float pr1[3]) {
  float rx = p[j*3+0] - p[i*3+0];
  float ry = p[j*3+1] - p[i*3+1];
  float rz = p[j*3+2] - p[i*3+2];
#pragma unroll
  for (int c = 0; c < 3; ++c)
    pr1[c] = rx*Wp1[c] + ry*Wp1[3+c] + rz*Wp1[6+c] + bp1[c];
}

__device__ __forceinline__ void comp_prv(const float* p, int i, int j,
                                         const float* Wp1, const float* bp1,
                                         const float* gp, const float* bpp,
                                         const float* sp, float o3[3]) {
  float pr1[3];
  comp_pr1(p, i, j, Wp1, bp1, pr1);
#pragma unroll
  for (int c = 0; c < 3; ++c)
    o3[c] = fmaxf(bn_ap(pr1[c], sp, 3, c, INV_NK, gp[c], bpp[c]), 0.0f);
}

__launch_bounds__(256)
__global__ void prstats_k(const float* __restrict__ p, const int* __restrict__ idx,
                          const float* Wp1, const float* bp1, float* __restrict__ sp) {
  float s[3] = {0,0,0}, s2[3] = {0,0,0};
  for (int it = 0; it < 4; ++it) {
    int e = blockIdx.x*1024 + it*256 + threadIdx.x;
    int i = e >> 4;
    int j = idx[e] & 8191;
    float pr1[3];
    comp_pr1(p, i, j, Wp1, bp1, pr1);
#pragma unroll
    for (int c = 0; c < 3; ++c) { s[c] += pr1[c]; s2[c] += pr1[c]*pr1[c]; }
  }
#pragma unroll
  for (int m = 1; m < 64; m <<= 1) {
#pragma unroll
    for (int c = 0; c < 3; ++c) {
      s[c]  += __shfl_xor(s[c],  m);
      s2[c] += __shfl_xor(s2[c], m);
    }
  }
  __shared__ float red[4][6];
  int wv = threadIdx.x >> 6, lane = threadIdx.x & 63;
  if (lane == 0) {
#pragma unroll
    for (int c = 0; c < 3; ++c) { red[wv][c] = s[c]; red[wv][3+c] = s2[c]; }
  }
  __syncthreads();
  if (threadIdx.x < 6) {
    float v = red[0][threadIdx.x] + red[1][threadIdx.x] +
              red[2][threadIdx.x] + red[3][threadIdx.x];
    atomicAdd(&sp[threadIdx.x], v);
  }
}

// ---------------------------------------------------------------- stats of w (no materialization)
__launch_bounds__(256)
__global__ void wstats_k(const float* __restrict__ xk, const float* __restrict__ xq,
                         const float* __restrict__ p, const int* __restrict__ idx,
                         const float* Wp1, const float* bp1, const float* gp, const float* bpp,
                         const float* sp, const float* __restrict__ Wp2, const float* bp2,
                         float* __restrict__ sw) {
  __shared__ float prv[32][16][4];
  __shared__ int   jidx[32][16];
  int base = blockIdx.x * 32;
  int t = threadIdx.x;
  for (int e = t; e < 512; e += 256) {
    int pt = e >> 4, k = e & 15;
    int j = idx[(base + pt)*16 + k] & 8191;
    jidx[pt][k] = j;
    float o3[3];
    comp_prv(p, base + pt, j, Wp1, bp1, gp, bpp, sp, o3);
    prv[pt][k][0] = o3[0]; prv[pt][k][1] = o3[1]; prv[pt][k][2] = o3[2];
  }
  __syncthreads();
  int c = t;
  float wp0 = Wp2[c], wp1v = Wp2[256+c], wp2v = Wp2[512+c];
  float bbv = bp2[c];
  float s1 = 0.f, s2 = 0.f;
  for (int pt = 0; pt < 32; ++pt) {
    int i = base + pt;
    float xqv = xq[(size_t)i*256 + c];
#pragma unroll
    for (int k = 0; k < 16; ++k) {
      int j = jidx[pt][k];
      float pr = prv[pt][k][0]*wp0 + prv[pt][k][1]*wp1v + prv[pt][k][2]*wp2v + bbv;
      float wval = xk[(size_t)j*256 + c] - xqv + pr;
      s1 += wval; s2 += wval*wval;
    }
  }
  atomicAdd(&sw[c], s1);
  atomicAdd(&sw[256 + c], s2);
}

// ---------------------------------------------------------------- fused: w1 = BNReLU(w) @ Ww1 + bww1
__launch_bounds__(256)
__global__ void w1gemm_k(const float* __restrict__ xk, const float* __restrict__ xq,
                         const float* __restrict__ p, const int* __restrict__ idx,
                         const float* Wp1, const float* bp1, const float* gp, const float* bpp,
                         const float* sp, const float* __restrict__ Wp2, const float* bp2,
                         const float* sw, const float* gw1, const float* bw1,
                         const float* __restrict__ Ww1, const float* bww1,
                         float* __restrict__ w1) {
  __shared__ float As[32][65];
  __shared__ float Bs[32][33];
  __shared__ float prv[64][4];
  __shared__ int   jrow[64];
  __shared__ float cc6[6][32];   // scl, sft, wp2r0, wp2r1, wp2r2, bp2
  int t = threadIdx.x;
  int base4 = blockIdx.x * 4;
  if (t < 64) {
    int grow = blockIdx.x*64 + t;
    int i = grow >> 4;
    int j = idx[grow] & 8191;
    jrow[t] = j;
    float o3[3];
    comp_prv(p, i, j, Wp1, bp1, gp, bpp, sp, o3);
    prv[t][0] = o3[0]; prv[t][1] = o3[1]; prv[t][2] = o3[2];
  }
  int tn = t & 7, tm = t >> 3;
  float acc[2][4] = {};
  for (int k0 = 0; k0 < 256; k0 += 32) {
    if (t < 32) {
      int ch = k0 + t;
      float m = sw[ch] * INV_NK;
      float var = sw[256+ch]*INV_NK - m*m;
      float scl = rsqrtf(var + 1e-5f) * gw1[ch];
      cc6[0][t] = scl;
      cc6[1][t] = bw1[ch] - m*scl;
      cc6[2][t] = Wp2[ch];
      cc6[3][t] = Wp2[256+ch];
      cc6[4][t] = Wp2[512+ch];
      cc6[5][t] = bp2[ch];
    }
    {
      int e = t;
#pragma unroll
      for (int it = 0; it < 4; ++it, e += 256) {
        int r = e >> 5, c = e & 31;
        Bs[r][c] = Ww1[(k0 + r)*32 + c];
      }
    }
    __syncthreads();
#pragma unroll
    for (int it = 0; it < 8; ++it) {
      int c = t & 31;
      int r = it*8 + (t >> 5);
      float v = xk[(size_t)jrow[r]*256 + k0 + c]
              - xq[(size_t)(base4 + (r >> 4))*256 + k0 + c]
              + prv[r][0]*cc6[2][c] + prv[r][1]*cc6[3][c] + prv[r][2]*cc6[4][c]
              + cc6[5][c];
      As[c][r] = fmaxf(v*cc6[0][c] + cc6[1][c], 0.0f);
    }
    __syncthreads();
#pragma unroll
    for (int kk = 0; kk < 32; ++kk) {
      float a0 = As[kk][tm*2], a1 = As[kk][tm*2+1];
      float b0 = Bs[kk][tn*4], b1 = Bs[kk][tn*4+1], b2 = Bs[kk][tn*4+2], b3 = Bs[kk][tn*4+3];
      acc[0][0] += a0*b0; acc[0][1] += a0*b1; acc[0][2] += a0*b2; acc[0][3] += a0*b3;
      acc[1][0] += a1*b0; acc[1][1] += a1*b1; acc[1][2] += a1*b2; acc[1][3] += a1*b3;
    }
    __syncthreads();
  }
#pragma unroll
  for (int i = 0; i < 2; ++i) {
    size_t grow = (size_t)blockIdx.x*64 + tm*2 + i;
#pragma unroll
    for (int j = 0; j < 4; ++j) {
      int col = tn*4 + j;
      w1[grow*32 + col] = acc[i][j] + bww1[col];
    }
  }
}

// ---------------------------------------------------------------- second linear_w + softmax + aggregate
__launch_bounds__(256)
__global__ void aggr_k(const float* __restrict__ w1, const float* sw1,
                       const float* gw2, const float* bw2,
                       const float* __restrict__ Ww2, const float* bww2,
                       const float* __restrict__ xv,
                       const float* __restrict__ p, const int* __restrict__ idx,
                       const float* Wp1, const float* bp1, const float* gp, const float* bpp,
                       const float* sp, const float* __restrict__ Wp2, const float* bp2,
                       float* __restrict__ y) {
  __shared__ float lw1[16][32];
  __shared__ float lW2[32][32];
  __shared__ float sw2[16][33];
  __shared__ float prv[16][4];
  __shared__ int   jidx[16];
  int i = blockIdx.x, t = threadIdx.x;
  for (int e = t; e < 1024; e += 256) lW2[e >> 5][e & 31] = Ww2[e];
  for (int e = t; e < 512; e += 256) {
    int c32 = e & 31;
    float v = w1[(size_t)i*512 + e];
    v = fmaxf(bn_ap(v, sw1, 32, c32, INV_NK, gw2[c32], bw2[c32]), 0.0f);
    lw1[e >> 5][c32] = v;
  }
  if (t < 16) jidx[t] = idx[i*16 + t] & 8191;
  __syncthreads();
  if (t < 16) {
    float o3[3];
    comp_prv(p, i, jidx[t], Wp1, bp1, gp, bpp, sp, o3);
    prv[t][0] = o3[0]; prv[t][1] = o3[1]; prv[t][2] = o3[2];
  }
  for (int e = t; e < 512; e += 256) {
    int k = e >> 5, c32 = e & 31;
    float a = bww2[c32];
#pragma unroll
    for (int j = 0; j < 32; ++j) a += lw1[k][j] * lW2[j][c32];
    sw2[k][c32] = a;
  }
  __syncthreads();
  if (t < 32) {
    float mx = -3.0e38f;
#pragma unroll
    for (int k = 0; k < 16; ++k) mx = fmaxf(mx, sw2[k][t]);
    float s = 0.f;
#pragma unroll
    for (int k = 0; k < 16; ++k) { float e2 = expf(sw2[k][t] - mx); sw2[k][t] = e2; s += e2; }
    float r = 1.0f / s;
#pragma unroll
    for (int k = 0; k < 16; ++k) sw2[k][t] *= r;
  }
  __syncthreads();
  int c = t;
  float wp0 = Wp2[c], wp1v = Wp2[256+c], wp2v = Wp2[512+c];
  float bbv = bp2[c];
  int c32 = c & 31;
  float acc = 0.f;
#pragma unroll
  for (int k = 0; k < 16; ++k) {
    int j = jidx[k];
    float pr = prv[k][0]*wp0 + prv[k][1]*wp1v + prv[k][2]*wp2v + bbv;
    float xvv = xv[(size_t)j*256 + c];
    acc += (xvv + pr) * sw2[k][c32];
  }
  y[(size_t)i*256 + c] = acc;
}

// ---------------------------------------------------------------- epilogue (x2 only)
__launch_bounds__(256)
__global__ void final_k(const float* __restrict__ t0, const float* s0,
                        const float* g0, const float* b0,
                        const float* __restrict__ t3, const float* s3,
                        const float* g3, const float* b3,
                        float* __restrict__ out) {
  int i = blockIdx.x, c = threadIdx.x;
  size_t off = (size_t)i*256 + c;
  float h0 = fmaxf(bn_ap(t0[off], s0, 256, c, INV_N, g0[c], b0[c]), 0.0f);
  float v3 = bn_ap(t3[off], s3, 256, c, INV_N, g3[c], b3[c]);
  out[24576 + off] = fmaxf(v3 + h0, 0.0f);
}

// ---------------------------------------------------------------- launch
extern "C" void kernel_launch(void* const* d_in, const int* in_sizes, int n_in,
                              void* d_out, int out_size, void* d_ws, size_t ws_size,
                              hipStream_t stream) {
  (void)in_sizes; (void)n_in; (void)out_size; (void)ws_size;
  const float* p    = (const float*)d_in[0];
  const float* x    = (const float*)d_in[1];
  const int*   o    = (const int*)  d_in[2];
  const float* W_pa = (const float*)d_in[3];
  const float* g_pa = (const float*)d_in[4];
  const float* b_pa = (const float*)d_in[5];
  const float* W1   = (const float*)d_in[6];
  const float* g1   = (const float*)d_in[7];
  const float* b1   = (const float*)d_in[8];
  const float* Wq   = (const float*)d_in[9];
  const float* bq   = (const float*)d_in[10];
  const float* Wk   = (const float*)d_in[11];
  const float* bk   = (const float*)d_in[12];
  const float* Wv   = (const float*)d_in[13];
  const float* bv   = (const float*)d_in[14];
  const float* Wp1  = (const float*)d_in[15];
  const float* bp1  = (const float*)d_in[16];
  const float* gp   = (const float*)d_in[17];
  const float* bpp  = (const float*)d_in[18];
  const float* Wp2  = (const float*)d_in[19];
  const float* bp2  = (const float*)d_in[20];
  const float* gw1  = (const float*)d_in[21];
  const float* bw1  = (const float*)d_in[22];
  const float* Ww1  = (const float*)d_in[23];
  const float* bww1 = (const float*)d_in[24];
  const float* gw2  = (const float*)d_in[25];
  const float* bw2  = (const float*)d_in[26];
  const float* Ww2  = (const float*)d_in[27];
  const float* bww2 = (const float*)d_in[28];
  const float* g2   = (const float*)d_in[29];
  const float* b2   = (const float*)d_in[30];
  const float* W3   = (const float*)d_in[31];
  const float* g3   = (const float*)d_in[32];
  const float* b3   = (const float*)d_in[33];

  // workspace layout (~56.5 MB total)
  char* ws = (char*)d_ws;
  float* t0  = (float*)(ws + 0);          // [8192,256] f32
  float* t1  = (float*)(ws + 8388608);    // [8192,256] f32 (later: y)
  float* xq  = (float*)(ws + 16777216);   // [8192,256] f32 (later: t3)
  float* xk  = (float*)(ws + 25165824);   // [8192,256] f32
  float* xv  = (float*)(ws + 33554432);   // [8192,256] f32
  float* w1  = (float*)(ws + 41943040);   // [131072,32] f32 (16 MB)
  int*   idx = (int*)  (ws + 58720256);   // [8192,16] i32
  float* st  = (float*)(ws + 59244544);   // stats block (16 KB)
  float* y  = t1;
  float* t3 = xq;
  // pp (float4 packed points, 128 KB) aliases w1's region: knn reads it before
  // w1gemm_k (much later in the same stream) writes w1. Safe by stream order.
  float4* pp = (float4*)(ws + 41943040);
  // stats offsets (floats): s0=0, s1=512, sw=1024, sy=1536, s3=2048, sw1=2560, sp=2624

  hipMemsetAsync(st, 0, 16384, stream);

  head_k<<<96, 256, 0, stream>>>(p, o, (float*)d_out);

  pack4_k<<<32, 256, 0, stream>>>(p, pp);
  knn_k<<<2048, 256, 0, stream>>>(pp, idx);

  gemm_k<false, false, 64, 64, 4, 4, 32><<<dim3(128, 4), 256, 0, stream>>>(
      x, nullptr, nullptr, nullptr, 0.f, W_pa, nullptr, t0, 8192, 64, 256);
  stats256_k<<<256, 256, 0, stream>>>(t0, st + 0);

  gemm_k<true, false, 64, 64, 4, 4, 32><<<dim3(128, 4), 256, 0, stream>>>(
      t0, st + 0, g_pa, b_pa, INV_N, W1, nullptr, t1, 8192, 256, 256);
  stats256_k<<<256, 256, 0, stream>>>(t1, st + 512);

  gemm_k<true, true, 64, 64, 4, 4, 32><<<dim3(128, 4), 256, 0, stream>>>(
      t1, st + 512, g1, b1, INV_N, Wq, bq, xq, 8192, 256, 256);
  gemm_k<true, true, 64, 64, 4, 4, 32><<<dim3(128, 4), 256, 0, stream>>>(
      t1, st + 512, g1, b1, INV_N, Wk, bk, xk, 8192, 256, 256);
  gemm_k<true, true, 64, 64, 4, 4, 32><<<dim3(128, 4), 256, 0, stream>>>(
      t1, st + 512, g1, b1, INV_N, Wv, bv, xv, 8192, 256, 256);

  prstats_k<<<128, 256, 0, stream>>>(p, idx, Wp1, bp1, st + 2624);

  wstats_k<<<256, 256, 0, stream>>>(xk, xq, p, idx, Wp1, bp1, gp, bpp,
                                    st + 2624, Wp2, bp2, st + 1024);

  w1gemm_k<<<2048, 256, 0, stream>>>(xk, xq, p, idx, Wp1, bp1, gp, bpp,
                                     st + 2624, Wp2, bp2, st + 1024,
                                     gw1, bw1, Ww1, bww1, w1);
  stats32_k<<<512, 256, 0, stream>>>(w1, st + 2560);

  aggr_k<<<8192, 256, 0, stream>>>(w1, st + 2560, gw2, bw2, Ww2, bww2, xv,
                                   p, idx, Wp1, bp1, gp, bpp, st + 2624,
                                   Wp2, bp2, y);
  stats256_k<<<256, 256, 0, stream>>>(y, st + 1536);

  gemm_k<true, false, 64, 64, 4, 4, 32><<<dim3(128, 4), 256, 0, stream>>>(
      y, st + 1536, g2, b2, INV_N, W3, nullptr, t3, 8192, 256, 256);
  stats256_k<<<256, 256, 0, stream>>>(t3, st + 2048);

  final_k<<<8192, 256, 0, stream>>>(t0, st + 0, g_pa, b_pa,
                                    t3, st + 2048, g3, b3, (float*)d_out);
}

// Round 6
// 348.366 us; speedup vs baseline: 2.7110x; 1.3612x over previous
//
#include <hip/hip_runtime.h>
#include <hip/hip_bf16.h>

// N=8192, K=16, CIN=64, C=256, S=8, C/S=32 ; all float tensors are float32.
#define INV_N  (1.0f/8192.0f)
#define INV_NK (1.0f/131072.0f)

typedef __attribute__((ext_vector_type(8))) short bf16x8;
typedef __attribute__((ext_vector_type(4))) float f32x4;

__device__ __forceinline__ unsigned short f2b(float f) {   // f32 -> bf16 RNE
  unsigned u = __float_as_uint(f);
  return (unsigned short)((u + 0x7FFFu + ((u >> 16) & 1u)) >> 16);
}

__device__ __forceinline__ float bn_ap(float v, const float* st, int C, int ch,
                                       float inv, float g, float b) {
  float m = st[ch] * inv;
  float var = st[C + ch] * inv - m * m;
  return (v - m) * rsqrtf(var + 1e-5f) * g + b;
}

// ---------------------------------------------------------------- head: p copy + o
__launch_bounds__(256)
__global__ void head_k(const float* __restrict__ p, const int* __restrict__ o,
                       float* __restrict__ out) {
  int e = blockIdx.x*256 + threadIdx.x;
  if (e < 24576) out[e] = p[e];
  if (e == 0) out[24576 + 2097152] = (float)o[0];
}

// ---------------------------------------------------------------- pack (x,y,z,|p|^2)
__launch_bounds__(256)
__global__ void pack4_k(const float* __restrict__ p, float4* __restrict__ pp) {
  int i = blockIdx.x*256 + threadIdx.x;   // 8192
  float x = p[i*3+0], y = p[i*3+1], z = p[i*3+2];
  pp[i] = make_float4(x, y, z, (x*x + y*y) + z*z);
}

// ---------------------------------------------------------------- KNN
// 4 waves/block, one query per wave; branchless med3 sorted-insert on
// index-packed distances (low 13 bits = candidate index).
__launch_bounds__(256)
__global__ void knn_k(const float4* __restrict__ pp, int* __restrict__ idxo) {
  int wave = threadIdx.x >> 6;
  int lane = threadIdx.x & 63;
  int q = blockIdx.x*4 + wave;
  float4 qv = pp[q];
  const float BIG = __uint_as_float(0x7F7FFFFFu);
  float d[16];
#pragma unroll
  for (int s = 0; s < 16; ++s) d[s] = BIG;
#pragma unroll 4
  for (int it = 0; it < 128; ++it) {
    int j = it*64 + lane;
    float4 c = pp[j];
    float dot = qv.x*c.x + (qv.y*c.y + qv.z*c.z);
    float d2 = __fmaf_rn(-2.0f, dot, qv.w + c.w);
    float pk = __uint_as_float((__float_as_uint(d2) & 0xFFFFE000u) | (unsigned)j);
#pragma unroll
    for (int s = 15; s >= 1; --s)
      d[s] = fminf(fmaxf(d[s-1], pk), d[s]);
    d[0] = fminf(d[0], pk);
  }
  for (int r = 0; r < 16; ++r) {
    float bd = d[0];
#pragma unroll
    for (int m = 1; m < 64; m <<= 1)
      bd = fminf(bd, __shfl_xor(bd, m));
    if (lane == 0) idxo[q*16 + r] = (int)(__float_as_uint(bd) & 0x1FFFu);
    if (d[0] == bd) {
#pragma unroll
      for (int s = 0; s < 15; ++s) d[s] = d[s+1];
      d[15] = BIG;
    }
  }
}

// ---------------------------------------------------------------- MFMA GEMM
// out[M,NOUT] = act(A) @ W (+bias); act = optional BN+ReLU via stats.
// 64x64 tile, BK=64, 4 waves (2x2), each wave 32x32 = 2x2 frags of 16x16x32.
template<bool BNA, bool BIAS>
__launch_bounds__(256)
__global__ void mfgemm_k(const float* __restrict__ A, const float* __restrict__ st,
                         const float* __restrict__ g, const float* __restrict__ bb,
                         float inv_cnt,
                         const float* __restrict__ W, const float* __restrict__ bias,
                         float* __restrict__ out, int KA, int NOUT) {
  __shared__ short As[64][72];    // +8 pad -> 2-way bank aliasing (free)
  __shared__ short Bt[64][72];    // B transposed: [n][k]
  __shared__ float lscl[256], lsft[256];
  int t = threadIdx.x;
  int m0 = blockIdx.x * 64, n0 = blockIdx.y * 64;
  if (BNA) {
    for (int e = t; e < KA; e += 256) {
      float m = st[e] * inv_cnt;
      float var = st[KA + e] * inv_cnt - m*m;
      float sc = rsqrtf(var + 1e-5f) * g[e];
      lscl[e] = sc; lsft[e] = bb[e] - m*sc;
    }
    __syncthreads();
  }
  const f32x4 zero = {0.f, 0.f, 0.f, 0.f};
  f32x4 acc[2][2] = {{zero, zero}, {zero, zero}};
  int wv = t >> 6, l = t & 63;
  int wm = wv & 1, wn = wv >> 1;
  int lr = l & 15, lk = (l >> 4) * 8;
  int ra = t >> 4, qa = t & 15;
  for (int k0 = 0; k0 < KA; k0 += 64) {
    // stage A (f32 -> BN/ReLU -> bf16)
#pragma unroll
    for (int rp = 0; rp < 4; ++rp) {
      int r = rp*16 + ra;
      float4 av = *(const float4*)(A + (size_t)(m0 + r)*KA + k0 + qa*4);
      float vv[4] = {av.x, av.y, av.z, av.w};
      short4 s;
#pragma unroll
      for (int jj = 0; jj < 4; ++jj) {
        float v = vv[jj];
        if (BNA) { int ch = k0 + qa*4 + jj; v = fmaxf(fmaf(v, lscl[ch], lsft[ch]), 0.f); }
        ((unsigned short*)&s)[jj] = f2b(v);
      }
      *(short4*)&As[r][qa*4] = s;
    }
    // stage B transposed
#pragma unroll
    for (int kp = 0; kp < 4; ++kp) {
      int kr = kp*16 + ra;
      float4 w4 = *(const float4*)(W + (size_t)(k0 + kr)*NOUT + n0 + qa*4);
      Bt[qa*4+0][kr] = (short)f2b(w4.x);
      Bt[qa*4+1][kr] = (short)f2b(w4.y);
      Bt[qa*4+2][kr] = (short)f2b(w4.z);
      Bt[qa*4+3][kr] = (short)f2b(w4.w);
    }
    __syncthreads();
#pragma unroll
    for (int fk = 0; fk < 2; ++fk) {
      bf16x8 a0 = *(const bf16x8*)&As[wm*32 +      lr][fk*32 + lk];
      bf16x8 a1 = *(const bf16x8*)&As[wm*32 + 16 + lr][fk*32 + lk];
      bf16x8 b0 = *(const bf16x8*)&Bt[wn*32 +      lr][fk*32 + lk];
      bf16x8 b1 = *(const bf16x8*)&Bt[wn*32 + 16 + lr][fk*32 + lk];
      acc[0][0] = __builtin_amdgcn_mfma_f32_16x16x32_bf16(a0, b0, acc[0][0], 0, 0, 0);
      acc[0][1] = __builtin_amdgcn_mfma_f32_16x16x32_bf16(a0, b1, acc[0][1], 0, 0, 0);
      acc[1][0] = __builtin_amdgcn_mfma_f32_16x16x32_bf16(a1, b0, acc[1][0], 0, 0, 0);
      acc[1][1] = __builtin_amdgcn_mfma_f32_16x16x32_bf16(a1, b1, acc[1][1], 0, 0, 0);
    }
    __syncthreads();
  }
  // epilogue: D col = lane&15, row = (lane>>4)*4 + reg   [verified m89]
#pragma unroll
  for (int fm = 0; fm < 2; ++fm) {
#pragma unroll
    for (int fn = 0; fn < 2; ++fn) {
      int col = n0 + wn*32 + fn*16 + lr;
      float bv = BIAS ? bias[col] : 0.f;
#pragma unroll
      for (int r = 0; r < 4; ++r) {
        int row = m0 + wm*32 + fm*16 + (l >> 4)*4 + r;
        out[(size_t)row*NOUT + col] = acc[fm][fn][r] + bv;
      }
    }
  }
}

// ---------------------------------------------------------------- stats
__launch_bounds__(256)
__global__ void stats256_k(const float* __restrict__ X, float* __restrict__ st) {
  int c = threadIdx.x;
  int r0 = blockIdx.x * 32;
  float s1 = 0.f, s2 = 0.f;
  for (int r = 0; r < 32; ++r) {
    float v = X[(size_t)(r0 + r)*256 + c];
    s1 += v; s2 += v*v;
  }
  atomicAdd(&st[c], s1);
  atomicAdd(&st[256 + c], s2);
}

__launch_bounds__(256)
__global__ void stats32_k(const float* __restrict__ X, float* __restrict__ st) {
  int c = threadIdx.x & 31, rg = threadIdx.x >> 5;
  size_t r0 = (size_t)blockIdx.x * 256;
  float s1 = 0.f, s2 = 0.f;
  for (int r = rg; r < 256; r += 8) {
    float v = X[(r0 + r)*32 + c];
    s1 += v; s2 += v*v;
  }
  __shared__ float red1[256], red2[256];
  red1[threadIdx.x] = s1; red2[threadIdx.x] = s2;
  __syncthreads();
  if (threadIdx.x < 32) {
    float a = 0.f, b = 0.f;
#pragma unroll
    for (int gI = 0; gI < 8; ++gI) { a += red1[gI*32 + threadIdx.x]; b += red2[gI*32 + threadIdx.x]; }
    atomicAdd(&st[threadIdx.x], a);
    atomicAdd(&st[32 + threadIdx.x], b);
  }
}

// ---------------------------------------------------------------- p_r helpers
__device__ __forceinline__ void comp_pr1(const float* p, int i, int j,
                                         const float* Wp1, const float* bp1,
                                         float pr1[3]) {
  float rx = p[j*3+0] - p[i*3+0];
  float ry = p[j*3+1] - p[i*3+1];
  float rz = p[j*3+2] - p[i*3+2];
#pragma unroll
  for (int c = 0; c < 3; ++c)
    pr1[c] = rx*Wp1[c] + ry*Wp1[3+c] + rz*Wp1[6+c] + bp1[c];
}

__device__ __forceinline__ void comp_prv(const float* p, int i, int j,
                                         const float* Wp1, const float* bp1,
                                         const float* gp, const float* bpp,
                                         const float* sp, float o3[3]) {
  float pr1[3];
  comp_pr1(p, i, j, Wp1, bp1, pr1);
#pragma unroll
  for (int c = 0; c < 3; ++c)
    o3[c] = fmaxf(bn_ap(pr1[c], sp, 3, c, INV_NK, gp[c], bpp[c]), 0.0f);
}

__launch_bounds__(256)
__global__ void prstats_k(const float* __restrict__ p, const int* __restrict__ idx,
                          const float* Wp1, const float* bp1, float* __restrict__ sp) {
  float s[3] = {0,0,0}, s2[3] = {0,0,0};
  for (int it = 0; it < 4; ++it) {
    int e = blockIdx.x*1024 + it*256 + threadIdx.x;
    int i = e >> 4;
    int j = idx[e] & 8191;
    float pr1[3];
    comp_pr1(p, i, j, Wp1, bp1, pr1);
#pragma unroll
    for (int c = 0; c < 3; ++c) { s[c] += pr1[c]; s2[c] += pr1[c]*pr1[c]; }
  }
#pragma unroll
  for (int m = 1; m < 64; m <<= 1) {
#pragma unroll
    for (int c = 0; c < 3; ++c) {
      s[c]  += __shfl_xor(s[c],  m);
      s2[c] += __shfl_xor(s2[c], m);
    }
  }
  __shared__ float red[4][6];
  int wv = threadIdx.x >> 6, lane = threadIdx.x & 63;
  if (lane == 0) {
#pragma unroll
    for (int c = 0; c < 3; ++c) { red[wv][c] = s[c]; red[wv][3+c] = s2[c]; }
  }
  __syncthreads();
  if (threadIdx.x < 6) {
    float v = red[0][threadIdx.x] + red[1][threadIdx.x] +
              red[2][threadIdx.x] + red[3][threadIdx.x];
    atomicAdd(&sp[threadIdx.x], v);
  }
}

// ---------------------------------------------------------------- stats of w (no materialization)
__launch_bounds__(256)
__global__ void wstats_k(const float* __restrict__ xk, const float* __restrict__ xq,
                         const float* __restrict__ p, const int* __restrict__ idx,
                         const float* Wp1, const float* bp1, const float* gp, const float* bpp,
                         const float* sp, const float* __restrict__ Wp2, const float* bp2,
                         float* __restrict__ sw) {
  __shared__ float prv[32][16][4];
  __shared__ int   jidx[32][16];
  int base = blockIdx.x * 32;
  int t = threadIdx.x;
  for (int e = t; e < 512; e += 256) {
    int pt = e >> 4, k = e & 15;
    int j = idx[(base + pt)*16 + k] & 8191;
    jidx[pt][k] = j;
    float o3[3];
    comp_prv(p, base + pt, j, Wp1, bp1, gp, bpp, sp, o3);
    prv[pt][k][0] = o3[0]; prv[pt][k][1] = o3[1]; prv[pt][k][2] = o3[2];
  }
  __syncthreads();
  int c = t;
  float wp0 = Wp2[c], wp1v = Wp2[256+c], wp2v = Wp2[512+c];
  float bbv = bp2[c];
  float s1 = 0.f, s2 = 0.f;
  for (int pt = 0; pt < 32; ++pt) {
    int i = base + pt;
    float xqv = xq[(size_t)i*256 + c];
#pragma unroll
    for (int k = 0; k < 16; ++k) {
      int j = jidx[pt][k];
      float pr = prv[pt][k][0]*wp0 + prv[pt][k][1]*wp1v + prv[pt][k][2]*wp2v + bbv;
      float wval = xk[(size_t)j*256 + c] - xqv + pr;
      s1 += wval; s2 += wval*wval;
    }
  }
  atomicAdd(&sw[c], s1);
  atomicAdd(&sw[256 + c], s2);
}

// ---------------------------------------------------------------- fused MFMA: w1 = BNReLU(w) @ Ww1 + bww1
// 64 rows (4 queries) x 32 cols, BK=64; 4 waves, each 16 rows x 32 cols.
__launch_bounds__(256)
__global__ void w1gemm_k(const float* __restrict__ xk, const float* __restrict__ xq,
                         const float* __restrict__ p, const int* __restrict__ idx,
                         const float* Wp1, const float* bp1, const float* gp, const float* bpp,
                         const float* sp, const float* __restrict__ Wp2, const float* bp2,
                         const float* sw, const float* gw1, const float* bw1,
                         const float* __restrict__ Ww1, const float* bww1,
                         float* __restrict__ w1) {
  __shared__ short sA[64][72];
  __shared__ short sB[32][72];
  __shared__ float prv[64][3];
  __shared__ int   jrow[64];
  __shared__ float cscl[256], csft[256], cw0[256], cw1[256], cw2[256], cb2[256];
  int t = threadIdx.x;
  int base4 = blockIdx.x * 4;
  {
    int e = t;   // exactly one pass: 256 channels
    float m = sw[e]*INV_NK;
    float var = sw[256+e]*INV_NK - m*m;
    float sc = rsqrtf(var + 1e-5f)*gw1[e];
    cscl[e] = sc; csft[e] = bw1[e] - m*sc;
    cw0[e] = Wp2[e]; cw1[e] = Wp2[256+e]; cw2[e] = Wp2[512+e]; cb2[e] = bp2[e];
  }
  if (t < 64) {
    int grow = blockIdx.x*64 + t;
    int j = idx[grow] & 8191;
    jrow[t] = j;
    float o3[3];
    comp_prv(p, grow >> 4, j, Wp1, bp1, gp, bpp, sp, o3);
    prv[t][0] = o3[0]; prv[t][1] = o3[1]; prv[t][2] = o3[2];
  }
  __syncthreads();
  const f32x4 zero = {0.f, 0.f, 0.f, 0.f};
  f32x4 acc[2] = {zero, zero};
  int wv = t >> 6, l = t & 63;
  int lr = l & 15, lk = (l >> 4) * 8;
  int ra = t >> 4, qa = t & 15;
  for (int k0 = 0; k0 < 256; k0 += 64) {
    // stage fused A
#pragma unroll
    for (int rp = 0; rp < 4; ++rp) {
      int r = rp*16 + ra;
      int j = jrow[r];
      int i = base4 + (r >> 4);
      float4 xkv = *(const float4*)(xk + (size_t)j*256 + k0 + qa*4);
      float4 xqv = *(const float4*)(xq + (size_t)i*256 + k0 + qa*4);
      float dv[4] = {xkv.x - xqv.x, xkv.y - xqv.y, xkv.z - xqv.z, xkv.w - xqv.w};
      float p0 = prv[r][0], p1 = prv[r][1], p2 = prv[r][2];
      short4 s;
#pragma unroll
      for (int jj = 0; jj < 4; ++jj) {
        int ch = k0 + qa*4 + jj;
        float v = dv[jj] + p0*cw0[ch] + p1*cw1[ch] + p2*cw2[ch] + cb2[ch];
        v = fmaxf(fmaf(v, cscl[ch], csft[ch]), 0.f);
        ((unsigned short*)&s)[jj] = f2b(v);
      }
      *(short4*)&sA[r][qa*4] = s;
    }
    // stage B transposed
#pragma unroll
    for (int kp = 0; kp < 2; ++kp) {
      int kr = kp*32 + (t >> 3);
      int nq = t & 7;
      float4 w4 = *(const float4*)(Ww1 + (size_t)(k0 + kr)*32 + nq*4);
      sB[nq*4+0][kr] = (short)f2b(w4.x);
      sB[nq*4+1][kr] = (short)f2b(w4.y);
      sB[nq*4+2][kr] = (short)f2b(w4.z);
      sB[nq*4+3][kr] = (short)f2b(w4.w);
    }
    __syncthreads();
#pragma unroll
    for (int fk = 0; fk < 2; ++fk) {
      bf16x8 a  = *(const bf16x8*)&sA[wv*16 + lr][fk*32 + lk];
      bf16x8 b0 = *(const bf16x8*)&sB[     lr][fk*32 + lk];
      bf16x8 b1 = *(const bf16x8*)&sB[16 + lr][fk*32 + lk];
      acc[0] = __builtin_amdgcn_mfma_f32_16x16x32_bf16(a, b0, acc[0], 0, 0, 0);
      acc[1] = __builtin_amdgcn_mfma_f32_16x16x32_bf16(a, b1, acc[1], 0, 0, 0);
    }
    __syncthreads();
  }
#pragma unroll
  for (int fn = 0; fn < 2; ++fn) {
    int col = fn*16 + lr;
    float bv = bww1[col];
#pragma unroll
    for (int r = 0; r < 4; ++r) {
      int grow = blockIdx.x*64 + wv*16 + (l >> 4)*4 + r;
      w1[(size_t)grow*32 + col] = acc[fn][r] + bv;
    }
  }
}

// ---------------------------------------------------------------- second linear_w + softmax + aggregate
__launch_bounds__(256)
__global__ void aggr_k(const float* __restrict__ w1, const float* sw1,
                       const float* gw2, const float* bw2,
                       const float* __restrict__ Ww2, const float* bww2,
                       const float* __restrict__ xv,
                       const float* __restrict__ p, const int* __restrict__ idx,
                       const float* Wp1, const float* bp1, const float* gp, const float* bpp,
                       const float* sp, const float* __restrict__ Wp2, const float* bp2,
                       float* __restrict__ y) {
  __shared__ float lw1[16][32];
  __shared__ float lW2[32][32];
  __shared__ float sw2[16][33];
  __shared__ float prv[16][4];
  __shared__ int   jidx[16];
  int i = blockIdx.x, t = threadIdx.x;
  for (int e = t; e < 1024; e += 256) lW2[e >> 5][e & 31] = Ww2[e];
  for (int e = t; e < 512; e += 256) {
    int c32 = e & 31;
    float v = w1[(size_t)i*512 + e];
    v = fmaxf(bn_ap(v, sw1, 32, c32, INV_NK, gw2[c32], bw2[c32]), 0.0f);
    lw1[e >> 5][c32] = v;
  }
  if (t < 16) jidx[t] = idx[i*16 + t] & 8191;
  __syncthreads();
  if (t < 16) {
    float o3[3];
    comp_prv(p, i, jidx[t], Wp1, bp1, gp, bpp, sp, o3);
    prv[t][0] = o3[0]; prv[t][1] = o3[1]; prv[t][2] = o3[2];
  }
  for (int e = t; e < 512; e += 256) {
    int k = e >> 5, c32 = e & 31;
    float a = bww2[c32];
#pragma unroll
    for (int j = 0; j < 32; ++j) a += lw1[k][j] * lW2[j][c32];
    sw2[k][c32] = a;
  }
  __syncthreads();
  if (t < 32) {
    float mx = -3.0e38f;
#pragma unroll
    for (int k = 0; k < 16; ++k) mx = fmaxf(mx, sw2[k][t]);
    float s = 0.f;
#pragma unroll
    for (int k = 0; k < 16; ++k) { float e2 = expf(sw2[k][t] - mx); sw2[k][t] = e2; s += e2; }
    float r = 1.0f / s;
#pragma unroll
    for (int k = 0; k < 16; ++k) sw2[k][t] *= r;
  }
  __syncthreads();
  int c = t;
  float wp0 = Wp2[c], wp1v = Wp2[256+c], wp2v = Wp2[512+c];
  float bbv = bp2[c];
  int c32 = c & 31;
  float acc = 0.f;
#pragma unroll
  for (int k = 0; k < 16; ++k) {
    int j = jidx[k];
    float pr = prv[k][0]*wp0 + prv[k][1]*wp1v + prv[k][2]*wp2v + bbv;
    float xvv = xv[(size_t)j*256 + c];
    acc += (xvv + pr) * sw2[k][c32];
  }
  y[(size_t)i*256 + c] = acc;
}

// ---------------------------------------------------------------- epilogue (x2 only)
__launch_bounds__(256)
__global__ void final_k(const float* __restrict__ t0, const float* s0,
                        const float* g0, const float* b0,
                        const float* __restrict__ t3, const float* s3,
                        const float* g3, const float* b3,
                        float* __restrict__ out) {
  int i = blockIdx.x, c = threadIdx.x;
  size_t off = (size_t)i*256 + c;
  float h0 = fmaxf(bn_ap(t0[off], s0, 256, c, INV_N, g0[c], b0[c]), 0.0f);
  float v3 = bn_ap(t3[off], s3, 256, c, INV_N, g3[c], b3[c]);
  out[24576 + off] = fmaxf(v3 + h0, 0.0f);
}

// ---------------------------------------------------------------- launch
extern "C" void kernel_launch(void* const* d_in, const int* in_sizes, int n_in,
                              void* d_out, int out_size, void* d_ws, size_t ws_size,
                              hipStream_t stream) {
  (void)in_sizes; (void)n_in; (void)out_size; (void)ws_size;
  const float* p    = (const float*)d_in[0];
  const float* x    = (const float*)d_in[1];
  const int*   o    = (const int*)  d_in[2];
  const float* W_pa = (const float*)d_in[3];
  const float* g_pa = (const float*)d_in[4];
  const float* b_pa = (const float*)d_in[5];
  const float* W1   = (const float*)d_in[6];
  const float* g1   = (const float*)d_in[7];
  const float* b1   = (const float*)d_in[8];
  const float* Wq   = (const float*)d_in[9];
  const float* bq   = (const float*)d_in[10];
  const float* Wk   = (const float*)d_in[11];
  const float* bk   = (const float*)d_in[12];
  const float* Wv   = (const float*)d_in[13];
  const float* bv   = (const float*)d_in[14];
  const float* Wp1  = (const float*)d_in[15];
  const float* bp1  = (const float*)d_in[16];
  const float* gp   = (const float*)d_in[17];
  const float* bpp  = (const float*)d_in[18];
  const float* Wp2  = (const float*)d_in[19];
  const float* bp2  = (const float*)d_in[20];
  const float* gw1  = (const float*)d_in[21];
  const float* bw1  = (const float*)d_in[22];
  const float* Ww1  = (const float*)d_in[23];
  const float* bww1 = (const float*)d_in[24];
  const float* gw2  = (const float*)d_in[25];
  const float* bw2  = (const float*)d_in[26];
  const float* Ww2  = (const float*)d_in[27];
  const float* bww2 = (const float*)d_in[28];
  const float* g2   = (const float*)d_in[29];
  const float* b2   = (const float*)d_in[30];
  const float* W3   = (const float*)d_in[31];
  const float* g3   = (const float*)d_in[32];
  const float* b3   = (const float*)d_in[33];

  // workspace layout (~56.5 MB total)
  char* ws = (char*)d_ws;
  float* t0  = (float*)(ws + 0);          // [8192,256] f32
  float* t1  = (float*)(ws + 8388608);    // [8192,256] f32 (later: y)
  float* xq  = (float*)(ws + 16777216);   // [8192,256] f32 (later: t3)
  float* xk  = (float*)(ws + 25165824);   // [8192,256] f32
  float* xv  = (float*)(ws + 33554432);   // [8192,256] f32
  float* w1  = (float*)(ws + 41943040);   // [131072,32] f32 (16 MB)
  int*   idx = (int*)  (ws + 58720256);   // [8192,16] i32
  float* st  = (float*)(ws + 59244544);   // stats block (16 KB)
  float* y  = t1;
  float* t3 = xq;
  // pp (float4 packed points, 128 KB) aliases w1's region: knn reads it before
  // w1gemm_k (much later in the same stream) writes w1. Safe by stream order.
  float4* pp = (float4*)(ws + 41943040);
  // stats offsets (floats): s0=0, s1=512, sw=1024, sy=1536, s3=2048, sw1=2560, sp=2624

  hipMemsetAsync(st, 0, 16384, stream);

  head_k<<<96, 256, 0, stream>>>(p, o, (float*)d_out);

  pack4_k<<<32, 256, 0, stream>>>(p, pp);
  knn_k<<<2048, 256, 0, stream>>>(pp, idx);

  mfgemm_k<false, false><<<dim3(128, 4), 256, 0, stream>>>(
      x, nullptr, nullptr, nullptr, 0.f, W_pa, nullptr, t0, 64, 256);
  stats256_k<<<256, 256, 0, stream>>>(t0, st + 0);

  mfgemm_k<true, false><<<dim3(128, 4), 256, 0, stream>>>(
      t0, st + 0, g_pa, b_pa, INV_N, W1, nullptr, t1, 256, 256);
  stats256_k<<<256, 256, 0, stream>>>(t1, st + 512);

  mfgemm_k<true, true><<<dim3(128, 4), 256, 0, stream>>>(
      t1, st + 512, g1, b1, INV_N, Wq, bq, xq, 256, 256);
  mfgemm_k<true, true><<<dim3(128, 4), 256, 0, stream>>>(
      t1, st + 512, g1, b1, INV_N, Wk, bk, xk, 256, 256);
  mfgemm_k<true, true><<<dim3(128, 4), 256, 0, stream>>>(
      t1, st + 512, g1, b1, INV_N, Wv, bv, xv, 256, 256);

  prstats_k<<<128, 256, 0, stream>>>(p, idx, Wp1, bp1, st + 2624);

  wstats_k<<<256, 256, 0, stream>>>(xk, xq, p, idx, Wp1, bp1, gp, bpp,
                                    st + 2624, Wp2, bp2, st + 1024);

  w1gemm_k<<<2048, 256, 0, stream>>>(xk, xq, p, idx, Wp1, bp1, gp, bpp,
                                     st + 2624, Wp2, bp2, st + 1024,
                                     gw1, bw1, Ww1, bww1, w1);
  stats32_k<<<512, 256, 0, stream>>>(w1, st + 2560);

  aggr_k<<<8192, 256, 0, stream>>>(w1, st + 2560, gw2, bw2, Ww2, bww2, xv,
                                   p, idx, Wp1, bp1, gp, bpp, st + 2624,
                                   Wp2, bp2, y);
  stats256_k<<<256, 256, 0, stream>>>(y, st + 1536);

  mfgemm_k<true, false><<<dim3(128, 4), 256, 0, stream>>>(
      y, st + 1536, g2, b2, INV_N, W3, nullptr, t3, 256, 256);
  stats256_k<<<256, 256, 0, stream>>>(t3, st + 2048);

  final_k<<<8192, 256, 0, stream>>>(t0, st + 0, g_pa, b_pa,
                                    t3, st + 2048, g3, b3, (float*)d_out);
}

// Round 7
// 289.171 us; speedup vs baseline: 3.2660x; 1.2047x over previous
//
#include <hip/hip_runtime.h>
#include <hip/hip_bf16.h>

// N=8192, K=16, CIN=64, C=256, S=8, C/S=32 ; float tensors are float32.
#define INV_N  (1.0f/8192.0f)
#define INV_NK (1.0f/131072.0f)

typedef __attribute__((ext_vector_type(8))) short bf16x8;
typedef __attribute__((ext_vector_type(4))) float f32x4;
typedef unsigned short u16;

__device__ __forceinline__ u16 f2b(float f) {   // f32 -> bf16 RNE
  unsigned u = __float_as_uint(f);
  return (u16)((u + 0x7FFFu + ((u >> 16) & 1u)) >> 16);
}
__device__ __forceinline__ float b2f(u16 u) {
  return __uint_as_float(((unsigned)u) << 16);
}

__device__ __forceinline__ float bn_ap(float v, const float* st, int C, int ch,
                                       float inv, float g, float b) {
  float m = st[ch] * inv;
  float var = st[C + ch] * inv - m * m;
  return (v - m) * rsqrtf(var + 1e-5f) * g + b;
}

// ---------------------------------------------------------------- head: p copy + o
__launch_bounds__(256)
__global__ void head_k(const float* __restrict__ p, const int* __restrict__ o,
                       float* __restrict__ out) {
  int e = blockIdx.x*256 + threadIdx.x;
  if (e < 24576) out[e] = p[e];
  if (e == 0) out[24576 + 2097152] = (float)o[0];
}

// ---------------------------------------------------------------- pack (x,y,z,|p|^2)
__launch_bounds__(256)
__global__ void pack4_k(const float* __restrict__ p, float4* __restrict__ pp) {
  int i = blockIdx.x*256 + threadIdx.x;   // 8192
  float x = p[i*3+0], y = p[i*3+1], z = p[i*3+2];
  pp[i] = make_float4(x, y, z, (x*x + y*y) + z*z);
}

// ---------------------------------------------------------------- KNN
// 4 waves/block, one query/wave; branchless med3 sorted-insert on
// index-packed distances (low 13 bits = candidate index); 8-deep/lane.
__launch_bounds__(256)
__global__ void knn_k(const float4* __restrict__ pp, int* __restrict__ idxo) {
  int wave = threadIdx.x >> 6;
  int lane = threadIdx.x & 63;
  int q = blockIdx.x*4 + wave;
  float4 qv = pp[q];
  const float BIG = __uint_as_float(0x7F7FFFFFu);
  float d[8];
#pragma unroll
  for (int s = 0; s < 8; ++s) d[s] = BIG;
#pragma unroll 4
  for (int it = 0; it < 128; ++it) {
    int j = it*64 + lane;
    float4 c = pp[j];
    float dot = qv.x*c.x + (qv.y*c.y + qv.z*c.z);
    float d2 = __fmaf_rn(-2.0f, dot, qv.w + c.w);
    float pk = __uint_as_float((__float_as_uint(d2) & 0xFFFFE000u) | (unsigned)j);
#pragma unroll
    for (int s = 7; s >= 1; --s)
      d[s] = fminf(fmaxf(d[s-1], pk), d[s]);
    d[0] = fminf(d[0], pk);
  }
  for (int r = 0; r < 16; ++r) {
    float bd = d[0];
#pragma unroll
    for (int m = 1; m < 64; m <<= 1)
      bd = fminf(bd, __shfl_xor(bd, m));
    if (lane == 0) idxo[q*16 + r] = (int)(__float_as_uint(bd) & 0x1FFFu);
    if (d[0] == bd) {                       // unique -> exactly one lane shifts
#pragma unroll
      for (int s = 0; s < 7; ++s) d[s] = d[s+1];
      d[7] = BIG;
    }
  }
}

// ---------------------------------------------------------------- MFMA GEMM (f32 out, fused col-stats)
// out[M,256] = act(A) @ W ; act = optional BN+ReLU via stats. 64x64 tile, BK=64.
template<bool BNA, bool STATS>
__launch_bounds__(256)
__global__ void mfgemm_k(const float* __restrict__ A, const float* __restrict__ st,
                         const float* __restrict__ g, const float* __restrict__ bb,
                         float inv_cnt,
                         const float* __restrict__ W, float* __restrict__ out,
                         float* __restrict__ stout, int KA, int NOUT) {
  __shared__ short As[64][72];
  __shared__ short Bt[64][72];
  __shared__ float lscl[256], lsft[256];
  int t = threadIdx.x;
  int m0 = blockIdx.x * 64, n0 = blockIdx.y * 64;
  if (BNA) {
    for (int e = t; e < KA; e += 256) {
      float m = st[e] * inv_cnt;
      float var = st[KA + e] * inv_cnt - m*m;
      float sc = rsqrtf(var + 1e-5f) * g[e];
      lscl[e] = sc; lsft[e] = bb[e] - m*sc;
    }
    __syncthreads();
  }
  const f32x4 zero = {0.f, 0.f, 0.f, 0.f};
  f32x4 acc[2][2] = {{zero, zero}, {zero, zero}};
  int wv = t >> 6, l = t & 63;
  int wm = wv & 1, wn = wv >> 1;
  int lr = l & 15, lk = (l >> 4) * 8;
  int ra = t >> 4, qa = t & 15;
  for (int k0 = 0; k0 < KA; k0 += 64) {
#pragma unroll
    for (int rp = 0; rp < 4; ++rp) {
      int r = rp*16 + ra;
      float4 av = *(const float4*)(A + (size_t)(m0 + r)*KA + k0 + qa*4);
      float vv[4] = {av.x, av.y, av.z, av.w};
      short4 s;
#pragma unroll
      for (int jj = 0; jj < 4; ++jj) {
        float v = vv[jj];
        if (BNA) { int ch = k0 + qa*4 + jj; v = fmaxf(fmaf(v, lscl[ch], lsft[ch]), 0.f); }
        ((u16*)&s)[jj] = f2b(v);
      }
      *(short4*)&As[r][qa*4] = s;
    }
#pragma unroll
    for (int kp = 0; kp < 4; ++kp) {
      int kr = kp*16 + ra;
      float4 w4 = *(const float4*)(W + (size_t)(k0 + kr)*NOUT + n0 + qa*4);
      Bt[qa*4+0][kr] = (short)f2b(w4.x);
      Bt[qa*4+1][kr] = (short)f2b(w4.y);
      Bt[qa*4+2][kr] = (short)f2b(w4.z);
      Bt[qa*4+3][kr] = (short)f2b(w4.w);
    }
    __syncthreads();
#pragma unroll
    for (int fk = 0; fk < 2; ++fk) {
      bf16x8 a0 = *(const bf16x8*)&As[wm*32 +      lr][fk*32 + lk];
      bf16x8 a1 = *(const bf16x8*)&As[wm*32 + 16 + lr][fk*32 + lk];
      bf16x8 b0 = *(const bf16x8*)&Bt[wn*32 +      lr][fk*32 + lk];
      bf16x8 b1 = *(const bf16x8*)&Bt[wn*32 + 16 + lr][fk*32 + lk];
      acc[0][0] = __builtin_amdgcn_mfma_f32_16x16x32_bf16(a0, b0, acc[0][0], 0, 0, 0);
      acc[0][1] = __builtin_amdgcn_mfma_f32_16x16x32_bf16(a0, b1, acc[0][1], 0, 0, 0);
      acc[1][0] = __builtin_amdgcn_mfma_f32_16x16x32_bf16(a1, b0, acc[1][0], 0, 0, 0);
      acc[1][1] = __builtin_amdgcn_mfma_f32_16x16x32_bf16(a1, b1, acc[1][1], 0, 0, 0);
    }
    __syncthreads();
  }
  // D: col = lane&15, row = (lane>>4)*4 + reg  [verified m89]
#pragma unroll
  for (int fn = 0; fn < 2; ++fn) {
    int col = n0 + wn*32 + fn*16 + lr;
    float s1 = 0.f, s2 = 0.f;
#pragma unroll
    for (int fm = 0; fm < 2; ++fm) {
#pragma unroll
      for (int r = 0; r < 4; ++r) {
        int row = m0 + wm*32 + fm*16 + (l >> 4)*4 + r;
        float v = acc[fm][fn][r];
        out[(size_t)row*NOUT + col] = v;
        if (STATS) { s1 += v; s2 += v*v; }
      }
    }
    if (STATS) {
      s1 += __shfl_xor(s1, 16); s1 += __shfl_xor(s1, 32);
      s2 += __shfl_xor(s2, 16); s2 += __shfl_xor(s2, 32);
      if (l < 16) {
        atomicAdd(&stout[col], s1);
        atomicAdd(&stout[NOUT + col], s2);
      }
    }
  }
}

// ---------------------------------------------------------------- fused Q/K/V MFMA (bf16 out)
__launch_bounds__(256)
__global__ void qkv_k(const float* __restrict__ t1, const float* __restrict__ st,
                      const float* __restrict__ g1, const float* __restrict__ b1,
                      const float* __restrict__ Wq, const float* __restrict__ bq,
                      const float* __restrict__ Wk, const float* __restrict__ bk,
                      const float* __restrict__ Wv, const float* __restrict__ bv,
                      u16* __restrict__ xq, u16* __restrict__ xk, u16* __restrict__ xv) {
  __shared__ short As[64][72];
  __shared__ short Bt[3][64][72];
  __shared__ float lscl[256], lsft[256];
  int t = threadIdx.x;
  int m0 = blockIdx.x * 64, n0 = blockIdx.y * 64;
  {
    int e = t;
    float m = st[e] * INV_N;
    float var = st[256 + e] * INV_N - m*m;
    float sc = rsqrtf(var + 1e-5f) * g1[e];
    lscl[e] = sc; lsft[e] = b1[e] - m*sc;
  }
  __syncthreads();
  const f32x4 zero = {0.f, 0.f, 0.f, 0.f};
  f32x4 acc[3][2][2];
#pragma unroll
  for (int w = 0; w < 3; ++w)
#pragma unroll
    for (int i = 0; i < 2; ++i)
#pragma unroll
      for (int j = 0; j < 2; ++j) acc[w][i][j] = zero;
  int wv = t >> 6, l = t & 63;
  int wm = wv & 1, wn = wv >> 1;
  int lr = l & 15, lk = (l >> 4) * 8;
  int ra = t >> 4, qa = t & 15;
  const float* Ws[3] = {Wq, Wk, Wv};
  for (int k0 = 0; k0 < 256; k0 += 64) {
#pragma unroll
    for (int rp = 0; rp < 4; ++rp) {
      int r = rp*16 + ra;
      float4 av = *(const float4*)(t1 + (size_t)(m0 + r)*256 + k0 + qa*4);
      float vv[4] = {av.x, av.y, av.z, av.w};
      short4 s;
#pragma unroll
      for (int jj = 0; jj < 4; ++jj) {
        int ch = k0 + qa*4 + jj;
        float v = fmaxf(fmaf(vv[jj], lscl[ch], lsft[ch]), 0.f);
        ((u16*)&s)[jj] = f2b(v);
      }
      *(short4*)&As[r][qa*4] = s;
    }
#pragma unroll
    for (int w = 0; w < 3; ++w) {
#pragma unroll
      for (int kp = 0; kp < 4; ++kp) {
        int kr = kp*16 + ra;
        float4 w4 = *(const float4*)(Ws[w] + (size_t)(k0 + kr)*256 + n0 + qa*4);
        Bt[w][qa*4+0][kr] = (short)f2b(w4.x);
        Bt[w][qa*4+1][kr] = (short)f2b(w4.y);
        Bt[w][qa*4+2][kr] = (short)f2b(w4.z);
        Bt[w][qa*4+3][kr] = (short)f2b(w4.w);
      }
    }
    __syncthreads();
#pragma unroll
    for (int fk = 0; fk < 2; ++fk) {
      bf16x8 a0 = *(const bf16x8*)&As[wm*32 +      lr][fk*32 + lk];
      bf16x8 a1 = *(const bf16x8*)&As[wm*32 + 16 + lr][fk*32 + lk];
#pragma unroll
      for (int w = 0; w < 3; ++w) {
        bf16x8 b0 = *(const bf16x8*)&Bt[w][wn*32 +      lr][fk*32 + lk];
        bf16x8 b1 = *(const bf16x8*)&Bt[w][wn*32 + 16 + lr][fk*32 + lk];
        acc[w][0][0] = __builtin_amdgcn_mfma_f32_16x16x32_bf16(a0, b0, acc[w][0][0], 0, 0, 0);
        acc[w][0][1] = __builtin_amdgcn_mfma_f32_16x16x32_bf16(a0, b1, acc[w][0][1], 0, 0, 0);
        acc[w][1][0] = __builtin_amdgcn_mfma_f32_16x16x32_bf16(a1, b0, acc[w][1][0], 0, 0, 0);
        acc[w][1][1] = __builtin_amdgcn_mfma_f32_16x16x32_bf16(a1, b1, acc[w][1][1], 0, 0, 0);
      }
    }
    __syncthreads();
  }
  u16* outs[3] = {xq, xk, xv};
  const float* bs[3] = {bq, bk, bv};
#pragma unroll
  for (int w = 0; w < 3; ++w) {
#pragma unroll
    for (int fn = 0; fn < 2; ++fn) {
      int col = n0 + wn*32 + fn*16 + lr;
      float bvv = bs[w][col];
#pragma unroll
      for (int fm = 0; fm < 2; ++fm) {
#pragma unroll
        for (int r = 0; r < 4; ++r) {
          int row = m0 + wm*32 + fm*16 + (l >> 4)*4 + r;
          outs[w][(size_t)row*256 + col] = f2b(acc[w][fm][fn][r] + bvv);
        }
      }
    }
  }
}

// ---------------------------------------------------------------- stats (y only)
__launch_bounds__(256)
__global__ void stats256_k(const float* __restrict__ X, float* __restrict__ st) {
  int c = threadIdx.x;
  int r0 = blockIdx.x * 32;
  float s1 = 0.f, s2 = 0.f;
  for (int r = 0; r < 32; ++r) {
    float v = X[(size_t)(r0 + r)*256 + c];
    s1 += v; s2 += v*v;
  }
  atomicAdd(&st[c], s1);
  atomicAdd(&st[256 + c], s2);
}

// ---------------------------------------------------------------- p_r helpers
__device__ __forceinline__ void comp_pr1(const float* p, int i, int j,
                                         const float* Wp1, const float* bp1,
                                         float pr1[3]) {
  float rx = p[j*3+0] - p[i*3+0];
  float ry = p[j*3+1] - p[i*3+1];
  float rz = p[j*3+2] - p[i*3+2];
#pragma unroll
  for (int c = 0; c < 3; ++c)
    pr1[c] = rx*Wp1[c] + ry*Wp1[3+c] + rz*Wp1[6+c] + bp1[c];
}

__device__ __forceinline__ void comp_prv(const float* p, int i, int j,
                                         const float* Wp1, const float* bp1,
                                         const float* gp, const float* bpp,
                                         const float* sp, float o3[3]) {
  float pr1[3];
  comp_pr1(p, i, j, Wp1, bp1, pr1);
#pragma unroll
  for (int c = 0; c < 3; ++c)
    o3[c] = fmaxf(bn_ap(pr1[c], sp, 3, c, INV_NK, gp[c], bpp[c]), 0.0f);
}

__launch_bounds__(256)
__global__ void prstats_k(const float* __restrict__ p, const int* __restrict__ idx,
                          const float* Wp1, const float* bp1, float* __restrict__ sp) {
  float s[3] = {0,0,0}, s2[3] = {0,0,0};
  for (int it = 0; it < 4; ++it) {
    int e = blockIdx.x*1024 + it*256 + threadIdx.x;
    int i = e >> 4;
    int j = idx[e] & 8191;
    float pr1[3];
    comp_pr1(p, i, j, Wp1, bp1, pr1);
#pragma unroll
    for (int c = 0; c < 3; ++c) { s[c] += pr1[c]; s2[c] += pr1[c]*pr1[c]; }
  }
#pragma unroll
  for (int m = 1; m < 64; m <<= 1) {
#pragma unroll
    for (int c = 0; c < 3; ++c) {
      s[c]  += __shfl_xor(s[c],  m);
      s2[c] += __shfl_xor(s2[c], m);
    }
  }
  __shared__ float red[4][6];
  int wv = threadIdx.x >> 6, lane = threadIdx.x & 63;
  if (lane == 0) {
#pragma unroll
    for (int c = 0; c < 3; ++c) { red[wv][c] = s[c]; red[wv][3+c] = s2[c]; }
  }
  __syncthreads();
  if (threadIdx.x < 6) {
    float v = red[0][threadIdx.x] + red[1][threadIdx.x] +
              red[2][threadIdx.x] + red[3][threadIdx.x];
    atomicAdd(&sp[threadIdx.x], v);
  }
}

// ---------------------------------------------------------------- stats of w (no materialization)
__launch_bounds__(256)
__global__ void wstats_k(const u16* __restrict__ xk, const u16* __restrict__ xq,
                         const float* __restrict__ p, const int* __restrict__ idx,
                         const float* Wp1, const float* bp1, const float* gp, const float* bpp,
                         const float* sp, const float* __restrict__ Wp2, const float* bp2,
                         float* __restrict__ sw) {
  __shared__ float prv[32][16][4];
  __shared__ int   jidx[32][16];
  int base = blockIdx.x * 32;
  int t = threadIdx.x;
  for (int e = t; e < 512; e += 256) {
    int pt = e >> 4, k = e & 15;
    int j = idx[(base + pt)*16 + k] & 8191;
    jidx[pt][k] = j;
    float o3[3];
    comp_prv(p, base + pt, j, Wp1, bp1, gp, bpp, sp, o3);
    prv[pt][k][0] = o3[0]; prv[pt][k][1] = o3[1]; prv[pt][k][2] = o3[2];
  }
  __syncthreads();
  int c = t;
  float wp0 = Wp2[c], wp1v = Wp2[256+c], wp2v = Wp2[512+c];
  float bbv = bp2[c];
  float s1 = 0.f, s2 = 0.f;
  for (int pt = 0; pt < 32; ++pt) {
    int i = base + pt;
    float xqv = b2f(xq[(size_t)i*256 + c]);
#pragma unroll
    for (int k = 0; k < 16; ++k) {
      int j = jidx[pt][k];
      float pr = prv[pt][k][0]*wp0 + prv[pt][k][1]*wp1v + prv[pt][k][2]*wp2v + bbv;
      float wval = b2f(xk[(size_t)j*256 + c]) - xqv + pr;
      s1 += wval; s2 += wval*wval;
    }
  }
  atomicAdd(&sw[c], s1);
  atomicAdd(&sw[256 + c], s2);
}

// ---------------------------------------------------------------- fused MFMA: w1 = BNReLU(w) @ Ww1 + bww1 (bf16 out + fused stats)
__launch_bounds__(256)
__global__ void w1gemm_k(const u16* __restrict__ xk, const u16* __restrict__ xq,
                         const float* __restrict__ p, const int* __restrict__ idx,
                         const float* Wp1, const float* bp1, const float* gp, const float* bpp,
                         const float* sp, const float* __restrict__ Wp2, const float* bp2,
                         const float* sw, const float* gw1, const float* bw1,
                         const float* __restrict__ Ww1, const float* bww1,
                         u16* __restrict__ w1, float* __restrict__ sw1out) {
  __shared__ short sA[64][72];
  __shared__ short sB[32][72];
  __shared__ float prv[64][3];
  __shared__ int   jrow[64];
  __shared__ float cscl[256], csft[256], cw0[256], cw1[256], cw2[256], cb2[256];
  int t = threadIdx.x;
  int base4 = blockIdx.x * 4;
  {
    int e = t;
    float m = sw[e]*INV_NK;
    float var = sw[256+e]*INV_NK - m*m;
    float sc = rsqrtf(var + 1e-5f)*gw1[e];
    cscl[e] = sc; csft[e] = bw1[e] - m*sc;
    cw0[e] = Wp2[e]; cw1[e] = Wp2[256+e]; cw2[e] = Wp2[512+e]; cb2[e] = bp2[e];
  }
  if (t < 64) {
    int grow = blockIdx.x*64 + t;
    int j = idx[grow] & 8191;
    jrow[t] = j;
    float o3[3];
    comp_prv(p, grow >> 4, j, Wp1, bp1, gp, bpp, sp, o3);
    prv[t][0] = o3[0]; prv[t][1] = o3[1]; prv[t][2] = o3[2];
  }
  __syncthreads();
  const f32x4 zero = {0.f, 0.f, 0.f, 0.f};
  f32x4 acc[2] = {zero, zero};
  int wv = t >> 6, l = t & 63;
  int lr = l & 15, lk = (l >> 4) * 8;
  int ra = t >> 4, qa = t & 15;
  for (int k0 = 0; k0 < 256; k0 += 64) {
#pragma unroll
    for (int rp = 0; rp < 4; ++rp) {
      int r = rp*16 + ra;
      int j = jrow[r];
      int i = base4 + (r >> 4);
      short4 kv = *(const short4*)(xk + (size_t)j*256 + k0 + qa*4);
      short4 qv = *(const short4*)(xq + (size_t)i*256 + k0 + qa*4);
      float p0 = prv[r][0], p1 = prv[r][1], p2 = prv[r][2];
      short4 s;
#pragma unroll
      for (int jj = 0; jj < 4; ++jj) {
        int ch = k0 + qa*4 + jj;
        float v = b2f(((u16*)&kv)[jj]) - b2f(((u16*)&qv)[jj])
                + p0*cw0[ch] + p1*cw1[ch] + p2*cw2[ch] + cb2[ch];
        v = fmaxf(fmaf(v, cscl[ch], csft[ch]), 0.f);
        ((u16*)&s)[jj] = f2b(v);
      }
      *(short4*)&sA[r][qa*4] = s;
    }
#pragma unroll
    for (int kp = 0; kp < 2; ++kp) {
      int kr = kp*32 + (t >> 3);
      int nq = t & 7;
      float4 w4 = *(const float4*)(Ww1 + (size_t)(k0 + kr)*32 + nq*4);
      sB[nq*4+0][kr] = (short)f2b(w4.x);
      sB[nq*4+1][kr] = (short)f2b(w4.y);
      sB[nq*4+2][kr] = (short)f2b(w4.z);
      sB[nq*4+3][kr] = (short)f2b(w4.w);
    }
    __syncthreads();
#pragma unroll
    for (int fk = 0; fk < 2; ++fk) {
      bf16x8 a  = *(const bf16x8*)&sA[wv*16 + lr][fk*32 + lk];
      bf16x8 b0 = *(const bf16x8*)&sB[     lr][fk*32 + lk];
      bf16x8 b1 = *(const bf16x8*)&sB[16 + lr][fk*32 + lk];
      acc[0] = __builtin_amdgcn_mfma_f32_16x16x32_bf16(a, b0, acc[0], 0, 0, 0);
      acc[1] = __builtin_amdgcn_mfma_f32_16x16x32_bf16(a, b1, acc[1], 0, 0, 0);
    }
    __syncthreads();
  }
  float* sred = (float*)&sA[0][0];   // 256 floats, sA dead after last barrier
#pragma unroll
  for (int fn = 0; fn < 2; ++fn) {
    int col = fn*16 + lr;
    float bv = bww1[col];
    float s1 = 0.f, s2 = 0.f;
#pragma unroll
    for (int r = 0; r < 4; ++r) {
      int grow = blockIdx.x*64 + wv*16 + (l >> 4)*4 + r;
      float v = acc[fn][r] + bv;
      w1[(size_t)grow*32 + col] = f2b(v);
      s1 += v; s2 += v*v;
    }
    s1 += __shfl_xor(s1, 16); s1 += __shfl_xor(s1, 32);
    s2 += __shfl_xor(s2, 16); s2 += __shfl_xor(s2, 32);
    if (l < 16) { sred[(wv*2+fn)*16 + lr] = s1; sred[128 + (wv*2+fn)*16 + lr] = s2; }
  }
  __syncthreads();
  if (t < 32) {
    int fn = t >> 4, lrr = t & 15;
    float a = 0.f, b = 0.f;
#pragma unroll
    for (int w2 = 0; w2 < 4; ++w2) {
      a += sred[(w2*2+fn)*16 + lrr];
      b += sred[128 + (w2*2+fn)*16 + lrr];
    }
    atomicAdd(&sw1out[fn*16 + lrr], a);
    atomicAdd(&sw1out[32 + fn*16 + lrr], b);
  }
}

// ---------------------------------------------------------------- second linear_w + softmax + aggregate
__launch_bounds__(256)
__global__ void aggr_k(const u16* __restrict__ w1, const float* sw1,
                       const float* gw2, const float* bw2,
                       const float* __restrict__ Ww2, const float* bww2,
                       const u16* __restrict__ xv,
                       const float* __restrict__ p, const int* __restrict__ idx,
                       const float* Wp1, const float* bp1, const float* gp, const float* bpp,
                       const float* sp, const float* __restrict__ Wp2, const float* bp2,
                       float* __restrict__ y) {
  __shared__ float lw1[16][32];
  __shared__ float lW2[32][32];
  __shared__ float sw2[16][33];
  __shared__ float prv[16][4];
  __shared__ int   jidx[16];
  int i = blockIdx.x, t = threadIdx.x;
  for (int e = t; e < 1024; e += 256) lW2[e >> 5][e & 31] = Ww2[e];
  for (int e = t; e < 512; e += 256) {
    int c32 = e & 31;
    float v = b2f(w1[(size_t)i*512 + e]);
    v = fmaxf(bn_ap(v, sw1, 32, c32, INV_NK, gw2[c32], bw2[c32]), 0.0f);
    lw1[e >> 5][c32] = v;
  }
  if (t < 16) jidx[t] = idx[i*16 + t] & 8191;
  __syncthreads();
  if (t < 16) {
    float o3[3];
    comp_prv(p, i, jidx[t], Wp1, bp1, gp, bpp, sp, o3);
    prv[t][0] = o3[0]; prv[t][1] = o3[1]; prv[t][2] = o3[2];
  }
  for (int e = t; e < 512; e += 256) {
    int k = e >> 5, c32 = e & 31;
    float a = bww2[c32];
#pragma unroll
    for (int j = 0; j < 32; ++j) a += lw1[k][j] * lW2[j][c32];
    sw2[k][c32] = a;
  }
  __syncthreads();
  if (t < 32) {
    float mx = -3.0e38f;
#pragma unroll
    for (int k = 0; k < 16; ++k) mx = fmaxf(mx, sw2[k][t]);
    float s = 0.f;
#pragma unroll
    for (int k = 0; k < 16; ++k) { float e2 = expf(sw2[k][t] - mx); sw2[k][t] = e2; s += e2; }
    float r = 1.0f / s;
#pragma unroll
    for (int k = 0; k < 16; ++k) sw2[k][t] *= r;
  }
  __syncthreads();
  int c = t;
  float wp0 = Wp2[c], wp1v = Wp2[256+c], wp2v = Wp2[512+c];
  float bbv = bp2[c];
  int c32 = c & 31;
  float acc = 0.f;
#pragma unroll
  for (int k = 0; k < 16; ++k) {
    int j = jidx[k];
    float pr = prv[k][0]*wp0 + prv[k][1]*wp1v + prv[k][2]*wp2v + bbv;
    float xvv = b2f(xv[(size_t)j*256 + c]);
    acc += (xvv + pr) * sw2[k][c32];
  }
  y[(size_t)i*256 + c] = acc;
}

// ---------------------------------------------------------------- epilogue (x2 only)
__launch_bounds__(256)
__global__ void final_k(const float* __restrict__ t0, const float* s0,
                        const float* g0, const float* b0,
                        const float* __restrict__ t3, const float* s3,
                        const float* g3, const float* b3,
                        float* __restrict__ out) {
  int i = blockIdx.x, c = threadIdx.x;
  size_t off = (size_t)i*256 + c;
  float h0 = fmaxf(bn_ap(t0[off], s0, 256, c, INV_N, g0[c], b0[c]), 0.0f);
  float v3 = bn_ap(t3[off], s3, 256, c, INV_N, g3[c], b3[c]);
  out[24576 + off] = fmaxf(v3 + h0, 0.0f);
}

// ---------------------------------------------------------------- launch
extern "C" void kernel_launch(void* const* d_in, const int* in_sizes, int n_in,
                              void* d_out, int out_size, void* d_ws, size_t ws_size,
                              hipStream_t stream) {
  (void)in_sizes; (void)n_in; (void)out_size; (void)ws_size;
  const float* p    = (const float*)d_in[0];
  const float* x    = (const float*)d_in[1];
  const int*   o    = (const int*)  d_in[2];
  const float* W_pa = (const float*)d_in[3];
  const float* g_pa = (const float*)d_in[4];
  const float* b_pa = (const float*)d_in[5];
  const float* W1   = (const float*)d_in[6];
  const float* g1   = (const float*)d_in[7];
  const float* b1   = (const float*)d_in[8];
  const float* Wq   = (const float*)d_in[9];
  const float* bq   = (const float*)d_in[10];
  const float* Wk   = (const float*)d_in[11];
  const float* bk   = (const float*)d_in[12];
  const float* Wv   = (const float*)d_in[13];
  const float* bv   = (const float*)d_in[14];
  const float* Wp1  = (const float*)d_in[15];
  const float* bp1  = (const float*)d_in[16];
  const float* gp   = (const float*)d_in[17];
  const float* bpp  = (const float*)d_in[18];
  const float* Wp2  = (const float*)d_in[19];
  const float* bp2  = (const float*)d_in[20];
  const float* gw1  = (const float*)d_in[21];
  const float* bw1  = (const float*)d_in[22];
  const float* Ww1  = (const float*)d_in[23];
  const float* bww1 = (const float*)d_in[24];
  const float* gw2  = (const float*)d_in[25];
  const float* bw2  = (const float*)d_in[26];
  const float* Ww2  = (const float*)d_in[27];
  const float* bww2 = (const float*)d_in[28];
  const float* g2   = (const float*)d_in[29];
  const float* b2   = (const float*)d_in[30];
  const float* W3   = (const float*)d_in[31];
  const float* g3   = (const float*)d_in[32];
  const float* b3   = (const float*)d_in[33];

  // workspace layout (~34.1 MB)
  char* ws = (char*)d_ws;
  float* t0  = (float*)(ws + 0);          // [8192,256] f32 (live til final_k)
  float* t1  = (float*)(ws + 8388608);    // [8192,256] f32 (later: y)
  u16*   xq  = (u16*)  (ws + 16777216);   // [8192,256] bf16
  u16*   xk  = (u16*)  (ws + 20971520);   // [8192,256] bf16
  u16*   xv  = (u16*)  (ws + 25165824);   // [8192,256] bf16
  u16*   w1  = (u16*)  (ws + 29360128);   // [131072,32] bf16 (8 MB)
  int*   idx = (int*)  (ws + 37748736);   // [8192,16] i32
  float* st  = (float*)(ws + 38273024);   // stats block (16 KB)
  float* y   = t1;                        // aggr output (t1 dead after qkv)
  float* t3  = (float*)(ws + 16777216);   // aliases xq+xk (dead after w1gemm)
  float4* pp = (float4*)(ws + 29360128);  // aliases w1 (knn finishes first)
  // st offsets: s0=0, s1=512, sw=1024, sy=1536, s3=2048, sw1=2560, sp=2624

  hipMemsetAsync(st, 0, 16384, stream);

  head_k<<<96, 256, 0, stream>>>(p, o, (float*)d_out);

  pack4_k<<<32, 256, 0, stream>>>(p, pp);
  knn_k<<<2048, 256, 0, stream>>>(pp, idx);

  mfgemm_k<false, true><<<dim3(128, 4), 256, 0, stream>>>(
      x, nullptr, nullptr, nullptr, 0.f, W_pa, t0, st + 0, 64, 256);

  mfgemm_k<true, true><<<dim3(128, 4), 256, 0, stream>>>(
      t0, st + 0, g_pa, b_pa, INV_N, W1, t1, st + 512, 256, 256);

  qkv_k<<<dim3(128, 4), 256, 0, stream>>>(
      t1, st + 512, g1, b1, Wq, bq, Wk, bk, Wv, bv, xq, xk, xv);

  prstats_k<<<128, 256, 0, stream>>>(p, idx, Wp1, bp1, st + 2624);

  wstats_k<<<256, 256, 0, stream>>>(xk, xq, p, idx, Wp1, bp1, gp, bpp,
                                    st + 2624, Wp2, bp2, st + 1024);

  w1gemm_k<<<2048, 256, 0, stream>>>(xk, xq, p, idx, Wp1, bp1, gp, bpp,
                                     st + 2624, Wp2, bp2, st + 1024,
                                     gw1, bw1, Ww1, bww1, w1, st + 2560);

  aggr_k<<<8192, 256, 0, stream>>>(w1, st + 2560, gw2, bw2, Ww2, bww2, xv,
                                   p, idx, Wp1, bp1, gp, bpp, st + 2624,
                                   Wp2, bp2, y);
  stats256_k<<<256, 256, 0, stream>>>(y, st + 1536);

  mfgemm_k<true, true><<<dim3(128, 4), 256, 0, stream>>>(
      y, st + 1536, g2, b2, INV_N, W3, t3, st + 2048, 256, 256);

  final_k<<<8192, 256, 0, stream>>>(t0, st + 0, g_pa, b_pa,
                                    t3, st + 2048, g3, b3, (float*)d_out);
}

// Round 8
// 267.203 us; speedup vs baseline: 3.5345x; 1.0822x over previous
//
#include <hip/hip_runtime.h>
#include <hip/hip_bf16.h>

// N=8192, K=16, CIN=64, C=256, S=8, C/S=32 ; float tensors are float32.
#define INV_N  (1.0f/8192.0f)
#define INV_NK (1.0f/131072.0f)

typedef __attribute__((ext_vector_type(8))) short bf16x8;
typedef __attribute__((ext_vector_type(4))) float f32x4;
typedef unsigned short u16;

__device__ __forceinline__ u16 f2b(float f) {   // f32 -> bf16 RNE
  unsigned u = __float_as_uint(f);
  return (u16)((u + 0x7FFFu + ((u >> 16) & 1u)) >> 16);
}
__device__ __forceinline__ float b2f(u16 u) {
  return __uint_as_float(((unsigned)u) << 16);
}

__device__ __forceinline__ float bn_ap(float v, const float* st, int C, int ch,
                                       float inv, float g, float b) {
  float m = st[ch] * inv;
  float var = st[C + ch] * inv - m * m;
  return (v - m) * rsqrtf(var + 1e-5f) * g + b;
}

// ---------------------------------------------------------------- prep: p copy + o + pack4 + Ww1 transpose
__launch_bounds__(256)
__global__ void prep_k(const float* __restrict__ p, const int* __restrict__ o,
                       const float* __restrict__ Ww1,
                       float4* __restrict__ pp, u16* __restrict__ Ww1t,
                       float* __restrict__ out) {
  int b = blockIdx.x, t = threadIdx.x;
  int e = b*256 + t;
  if (e < 24576) out[e] = p[e];
  if (e == 0) out[24576 + 2097152] = (float)o[0];
  if (e < 8192) {
    float x = p[e*3+0], y = p[e*3+1], z = p[e*3+2];
    pp[e] = make_float4(x, y, z, (x*x + y*y) + z*z);
  }
  if (b >= 88) {                     // 8 blocks cover Ww1 (256x32 -> [32][256])
    int q = (b - 88)*1024 + t*4;
#pragma unroll
    for (int ii = 0; ii < 4; ++ii) {
      int e2 = q + ii;
      int k = e2 >> 5, n = e2 & 31;
      Ww1t[n*256 + k] = f2b(Ww1[e2]);
    }
  }
}

// ---------------------------------------------------------------- KNN
// 4 waves/block, one query/wave; branchless med3 sorted-insert on
// index-packed distances (low 13 bits = candidate index); 6-deep/lane.
__launch_bounds__(256)
__global__ void knn_k(const float4* __restrict__ pp, int* __restrict__ idxo) {
  int wave = threadIdx.x >> 6;
  int lane = threadIdx.x & 63;
  int q = blockIdx.x*4 + wave;
  float4 qv = pp[q];
  const float BIG = __uint_as_float(0x7F7FFFFFu);
  float d[6];
#pragma unroll
  for (int s = 0; s < 6; ++s) d[s] = BIG;
#pragma unroll 4
  for (int it = 0; it < 128; ++it) {
    int j = it*64 + lane;
    float4 c = pp[j];
    float dot = qv.x*c.x + (qv.y*c.y + qv.z*c.z);
    float d2 = __fmaf_rn(-2.0f, dot, qv.w + c.w);
    float pk = __uint_as_float((__float_as_uint(d2) & 0xFFFFE000u) | (unsigned)j);
#pragma unroll
    for (int s = 5; s >= 1; --s)
      d[s] = fminf(fmaxf(d[s-1], pk), d[s]);
    d[0] = fminf(d[0], pk);
  }
  for (int r = 0; r < 16; ++r) {
    float bd = d[0];
#pragma unroll
    for (int m = 1; m < 64; m <<= 1)
      bd = fminf(bd, __shfl_xor(bd, m));
    if (lane == 0) idxo[q*16 + r] = (int)(__float_as_uint(bd) & 0x1FFFu);
    if (d[0] == bd) {                       // unique -> exactly one lane shifts
#pragma unroll
      for (int s = 0; s < 5; ++s) d[s] = d[s+1];
      d[5] = BIG;
    }
  }
}

// ---------------------------------------------------------------- MFMA GEMM (f32 out, fused col-stats)
template<bool BNA, bool STATS>
__launch_bounds__(256)
__global__ void mfgemm_k(const float* __restrict__ A, const float* __restrict__ st,
                         const float* __restrict__ g, const float* __restrict__ bb,
                         float inv_cnt,
                         const float* __restrict__ W, float* __restrict__ out,
                         float* __restrict__ stout, int KA, int NOUT) {
  __shared__ short As[64][72];
  __shared__ short Bt[64][72];
  __shared__ float lscl[256], lsft[256];
  int t = threadIdx.x;
  int m0 = blockIdx.x * 64, n0 = blockIdx.y * 64;
  if (BNA) {
    for (int e = t; e < KA; e += 256) {
      float m = st[e] * inv_cnt;
      float var = st[KA + e] * inv_cnt - m*m;
      float sc = rsqrtf(var + 1e-5f) * g[e];
      lscl[e] = sc; lsft[e] = bb[e] - m*sc;
    }
    __syncthreads();
  }
  const f32x4 zero = {0.f, 0.f, 0.f, 0.f};
  f32x4 acc[2][2] = {{zero, zero}, {zero, zero}};
  int wv = t >> 6, l = t & 63;
  int wm = wv & 1, wn = wv >> 1;
  int lr = l & 15, lk = (l >> 4) * 8;
  int ra = t >> 4, qa = t & 15;
  int bn = t & 63, bkc = t >> 6;           // B-stage mapping
  for (int k0 = 0; k0 < KA; k0 += 64) {
    // stage A (f32 -> BN/ReLU -> bf16), coalesced float4 loads, 8B writes (bank-even-min)
#pragma unroll
    for (int rp = 0; rp < 4; ++rp) {
      int r = rp*16 + ra;
      float4 av = *(const float4*)(A + (size_t)(m0 + r)*KA + k0 + qa*4);
      float vv[4] = {av.x, av.y, av.z, av.w};
      short4 s;
#pragma unroll
      for (int jj = 0; jj < 4; ++jj) {
        float v = vv[jj];
        if (BNA) { int ch = k0 + qa*4 + jj; v = fmaxf(fmaf(v, lscl[ch], lsft[ch]), 0.f); }
        ((u16*)&s)[jj] = f2b(v);
      }
      *(short4*)&As[r][qa*4] = s;
    }
    // stage B transposed: coalesced column loads + two 16B writes (bank-minimal)
    {
      float v[16];
#pragma unroll
      for (int j2 = 0; j2 < 16; ++j2)
        v[j2] = W[(size_t)(k0 + bkc*16 + j2)*NOUT + n0 + bn];
      bf16x8 w0, w1v;
#pragma unroll
      for (int j2 = 0; j2 < 8; ++j2) {
        w0[j2]  = (short)f2b(v[j2]);
        w1v[j2] = (short)f2b(v[8 + j2]);
      }
      *(bf16x8*)&Bt[bn][bkc*16]     = w0;
      *(bf16x8*)&Bt[bn][bkc*16 + 8] = w1v;
    }
    __syncthreads();
#pragma unroll
    for (int fk = 0; fk < 2; ++fk) {
      bf16x8 a0 = *(const bf16x8*)&As[wm*32 +      lr][fk*32 + lk];
      bf16x8 a1 = *(const bf16x8*)&As[wm*32 + 16 + lr][fk*32 + lk];
      bf16x8 b0 = *(const bf16x8*)&Bt[wn*32 +      lr][fk*32 + lk];
      bf16x8 b1 = *(const bf16x8*)&Bt[wn*32 + 16 + lr][fk*32 + lk];
      acc[0][0] = __builtin_amdgcn_mfma_f32_16x16x32_bf16(a0, b0, acc[0][0], 0, 0, 0);
      acc[0][1] = __builtin_amdgcn_mfma_f32_16x16x32_bf16(a0, b1, acc[0][1], 0, 0, 0);
      acc[1][0] = __builtin_amdgcn_mfma_f32_16x16x32_bf16(a1, b0, acc[1][0], 0, 0, 0);
      acc[1][1] = __builtin_amdgcn_mfma_f32_16x16x32_bf16(a1, b1, acc[1][1], 0, 0, 0);
    }
    __syncthreads();
  }
  // D: col = lane&15, row = (lane>>4)*4 + reg  [verified m89]
#pragma unroll
  for (int fn = 0; fn < 2; ++fn) {
    int col = n0 + wn*32 + fn*16 + lr;
    float s1 = 0.f, s2 = 0.f;
#pragma unroll
    for (int fm = 0; fm < 2; ++fm) {
#pragma unroll
      for (int r = 0; r < 4; ++r) {
        int row = m0 + wm*32 + fm*16 + (l >> 4)*4 + r;
        float v = acc[fm][fn][r];
        out[(size_t)row*NOUT + col] = v;
        if (STATS) { s1 += v; s2 += v*v; }
      }
    }
    if (STATS) {
      s1 += __shfl_xor(s1, 16); s1 += __shfl_xor(s1, 32);
      s2 += __shfl_xor(s2, 16); s2 += __shfl_xor(s2, 32);
      if (l < 16) {
        atomicAdd(&stout[col], s1);
        atomicAdd(&stout[NOUT + col], s2);
      }
    }
  }
}

// ---------------------------------------------------------------- fused Q/K/V MFMA (bf16 out)
__launch_bounds__(256)
__global__ void qkv_k(const float* __restrict__ t1, const float* __restrict__ st,
                      const float* __restrict__ g1, const float* __restrict__ b1,
                      const float* __restrict__ Wq, const float* __restrict__ bq,
                      const float* __restrict__ Wk, const float* __restrict__ bk,
                      const float* __restrict__ Wv, const float* __restrict__ bv,
                      u16* __restrict__ xq, u16* __restrict__ xk, u16* __restrict__ xv) {
  __shared__ short As[64][72];
  __shared__ short Bt[3][64][72];
  __shared__ float lscl[256], lsft[256];
  int t = threadIdx.x;
  int m0 = blockIdx.x * 64, n0 = blockIdx.y * 64;
  {
    int e = t;
    float m = st[e] * INV_N;
    float var = st[256 + e] * INV_N - m*m;
    float sc = rsqrtf(var + 1e-5f) * g1[e];
    lscl[e] = sc; lsft[e] = b1[e] - m*sc;
  }
  __syncthreads();
  const f32x4 zero = {0.f, 0.f, 0.f, 0.f};
  f32x4 acc[3][2][2];
#pragma unroll
  for (int w = 0; w < 3; ++w)
#pragma unroll
    for (int i = 0; i < 2; ++i)
#pragma unroll
      for (int j = 0; j < 2; ++j) acc[w][i][j] = zero;
  int wv = t >> 6, l = t & 63;
  int wm = wv & 1, wn = wv >> 1;
  int lr = l & 15, lk = (l >> 4) * 8;
  int ra = t >> 4, qa = t & 15;
  int bn = t & 63, bkc = t >> 6;
  const float* Ws[3] = {Wq, Wk, Wv};
  for (int k0 = 0; k0 < 256; k0 += 64) {
#pragma unroll
    for (int rp = 0; rp < 4; ++rp) {
      int r = rp*16 + ra;
      float4 av = *(const float4*)(t1 + (size_t)(m0 + r)*256 + k0 + qa*4);
      float vv[4] = {av.x, av.y, av.z, av.w};
      short4 s;
#pragma unroll
      for (int jj = 0; jj < 4; ++jj) {
        int ch = k0 + qa*4 + jj;
        float v = fmaxf(fmaf(vv[jj], lscl[ch], lsft[ch]), 0.f);
        ((u16*)&s)[jj] = f2b(v);
      }
      *(short4*)&As[r][qa*4] = s;
    }
#pragma unroll
    for (int w = 0; w < 3; ++w) {
      float v[16];
#pragma unroll
      for (int j2 = 0; j2 < 16; ++j2)
        v[j2] = Ws[w][(size_t)(k0 + bkc*16 + j2)*256 + n0 + bn];
      bf16x8 w0, w1v;
#pragma unroll
      for (int j2 = 0; j2 < 8; ++j2) {
        w0[j2]  = (short)f2b(v[j2]);
        w1v[j2] = (short)f2b(v[8 + j2]);
      }
      *(bf16x8*)&Bt[w][bn][bkc*16]     = w0;
      *(bf16x8*)&Bt[w][bn][bkc*16 + 8] = w1v;
    }
    __syncthreads();
#pragma unroll
    for (int fk = 0; fk < 2; ++fk) {
      bf16x8 a0 = *(const bf16x8*)&As[wm*32 +      lr][fk*32 + lk];
      bf16x8 a1 = *(const bf16x8*)&As[wm*32 + 16 + lr][fk*32 + lk];
#pragma unroll
      for (int w = 0; w < 3; ++w) {
        bf16x8 b0 = *(const bf16x8*)&Bt[w][wn*32 +      lr][fk*32 + lk];
        bf16x8 b1 = *(const bf16x8*)&Bt[w][wn*32 + 16 + lr][fk*32 + lk];
        acc[w][0][0] = __builtin_amdgcn_mfma_f32_16x16x32_bf16(a0, b0, acc[w][0][0], 0, 0, 0);
        acc[w][0][1] = __builtin_amdgcn_mfma_f32_16x16x32_bf16(a0, b1, acc[w][0][1], 0, 0, 0);
        acc[w][1][0] = __builtin_amdgcn_mfma_f32_16x16x32_bf16(a1, b0, acc[w][1][0], 0, 0, 0);
        acc[w][1][1] = __builtin_amdgcn_mfma_f32_16x16x32_bf16(a1, b1, acc[w][1][1], 0, 0, 0);
      }
    }
    __syncthreads();
  }
  u16* outs[3] = {xq, xk, xv};
  const float* bs[3] = {bq, bk, bv};
#pragma unroll
  for (int w = 0; w < 3; ++w) {
#pragma unroll
    for (int fn = 0; fn < 2; ++fn) {
      int col = n0 + wn*32 + fn*16 + lr;
      float bvv = bs[w][col];
#pragma unroll
      for (int fm = 0; fm < 2; ++fm) {
#pragma unroll
        for (int r = 0; r < 4; ++r) {
          int row = m0 + wm*32 + fm*16 + (l >> 4)*4 + r;
          outs[w][(size_t)row*256 + col] = f2b(acc[w][fm][fn][r] + bvv);
        }
      }
    }
  }
}

// ---------------------------------------------------------------- stats (y only)
__launch_bounds__(256)
__global__ void stats256_k(const float* __restrict__ X, float* __restrict__ st) {
  int c = threadIdx.x;
  int r0 = blockIdx.x * 32;
  float s1 = 0.f, s2 = 0.f;
  for (int r = 0; r < 32; ++r) {
    float v = X[(size_t)(r0 + r)*256 + c];
    s1 += v; s2 += v*v;
  }
  atomicAdd(&st[c], s1);
  atomicAdd(&st[256 + c], s2);
}

// ---------------------------------------------------------------- p_r helpers
__device__ __forceinline__ void comp_pr1(const float* p, int i, int j,
                                         const float* Wp1, const float* bp1,
                                         float pr1[3]) {
  float rx = p[j*3+0] - p[i*3+0];
  float ry = p[j*3+1] - p[i*3+1];
  float rz = p[j*3+2] - p[i*3+2];
#pragma unroll
  for (int c = 0; c < 3; ++c)
    pr1[c] = rx*Wp1[c] + ry*Wp1[3+c] + rz*Wp1[6+c] + bp1[c];
}

__device__ __forceinline__ void comp_prv(const float* p, int i, int j,
                                         const float* Wp1, const float* bp1,
                                         const float* gp, const float* bpp,
                                         const float* sp, float o3[3]) {
  float pr1[3];
  comp_pr1(p, i, j, Wp1, bp1, pr1);
#pragma unroll
  for (int c = 0; c < 3; ++c)
    o3[c] = fmaxf(bn_ap(pr1[c], sp, 3, c, INV_NK, gp[c], bpp[c]), 0.0f);
}

__launch_bounds__(256)
__global__ void prstats_k(const float* __restrict__ p, const int* __restrict__ idx,
                          const float* Wp1, const float* bp1, float* __restrict__ sp) {
  float s[3] = {0,0,0}, s2[3] = {0,0,0};
  for (int it = 0; it < 4; ++it) {
    int e = blockIdx.x*1024 + it*256 + threadIdx.x;
    int i = e >> 4;
    int j = idx[e] & 8191;
    float pr1[3];
    comp_pr1(p, i, j, Wp1, bp1, pr1);
#pragma unroll
    for (int c = 0; c < 3; ++c) { s[c] += pr1[c]; s2[c] += pr1[c]*pr1[c]; }
  }
#pragma unroll
  for (int m = 1; m < 64; m <<= 1) {
#pragma unroll
    for (int c = 0; c < 3; ++c) {
      s[c]  += __shfl_xor(s[c],  m);
      s2[c] += __shfl_xor(s2[c], m);
    }
  }
  __shared__ float red[4][6];
  int wv = threadIdx.x >> 6, lane = threadIdx.x & 63;
  if (lane == 0) {
#pragma unroll
    for (int c = 0; c < 3; ++c) { red[wv][c] = s[c]; red[wv][3+c] = s2[c]; }
  }
  __syncthreads();
  if (threadIdx.x < 6) {
    float v = red[0][threadIdx.x] + red[1][threadIdx.x] +
              red[2][threadIdx.x] + red[3][threadIdx.x];
    atomicAdd(&sp[threadIdx.x], v);
  }
}

// ---------------------------------------------------------------- stats of w (no materialization)
__launch_bounds__(256)
__global__ void wstats_k(const u16* __restrict__ xk, const u16* __restrict__ xq,
                         const float* __restrict__ p, const int* __restrict__ idx,
                         const float* Wp1, const float* bp1, const float* gp, const float* bpp,
                         const float* sp, const float* __restrict__ Wp2, const float* bp2,
                         float* __restrict__ sw) {
  __shared__ float prv[32][16][4];
  __shared__ int   jidx[32][16];
  int base = blockIdx.x * 32;
  int t = threadIdx.x;
  for (int e = t; e < 512; e += 256) {
    int pt = e >> 4, k = e & 15;
    int j = idx[(base + pt)*16 + k] & 8191;
    jidx[pt][k] = j;
    float o3[3];
    comp_prv(p, base + pt, j, Wp1, bp1, gp, bpp, sp, o3);
    prv[pt][k][0] = o3[0]; prv[pt][k][1] = o3[1]; prv[pt][k][2] = o3[2];
  }
  __syncthreads();
  int c = t;
  float wp0 = Wp2[c], wp1v = Wp2[256+c], wp2v = Wp2[512+c];
  float bbv = bp2[c];
  float s1 = 0.f, s2 = 0.f;
  for (int pt = 0; pt < 32; ++pt) {
    int i = base + pt;
    float xqv = b2f(xq[(size_t)i*256 + c]);
#pragma unroll
    for (int k = 0; k < 16; ++k) {
      int j = jidx[pt][k];
      float pr = prv[pt][k][0]*wp0 + prv[pt][k][1]*wp1v + prv[pt][k][2]*wp2v + bbv;
      float wval = b2f(xk[(size_t)j*256 + c]) - xqv + pr;
      s1 += wval; s2 += wval*wval;
    }
  }
  atomicAdd(&sw[c], s1);
  atomicAdd(&sw[256 + c], s2);
}

// ---------------------------------------------------------------- w1gemm v2: full-K A-stage, B from global Ww1t
__launch_bounds__(256)
__global__ void w1gemm_k(const u16* __restrict__ xk, const u16* __restrict__ xq,
                         const float* __restrict__ p, const int* __restrict__ idx,
                         const float* Wp1, const float* bp1, const float* gp, const float* bpp,
                         const float* sp, const float* __restrict__ Wp2, const float* bp2,
                         const float* sw, const float* gw1, const float* bw1,
                         const u16* __restrict__ Ww1t, const float* bww1,
                         u16* __restrict__ w1, float* __restrict__ sw1out) {
  __shared__ short sA[64][264];
  __shared__ float prv[64][3];
  __shared__ int   jrow[64];
  __shared__ float cscl[256], csft[256], cw0[256], cw1[256], cw2[256], cb2[256];
  int t = threadIdx.x;
  int base4 = blockIdx.x * 4;
  { // phase 0: per-channel constants + prv/jrow
    float m = sw[t]*INV_NK;
    float var = sw[256+t]*INV_NK - m*m;
    float sc = rsqrtf(var + 1e-5f)*gw1[t];
    cscl[t] = sc; csft[t] = bw1[t] - m*sc;
    cw0[t] = Wp2[t]; cw1[t] = Wp2[256+t]; cw2[t] = Wp2[512+t]; cb2[t] = bp2[t];
  }
  if (t < 64) {
    int grow = blockIdx.x*64 + t;
    int j = idx[grow] & 8191;
    jrow[t] = j;
    float o3[3];
    comp_prv(p, grow >> 4, j, Wp1, bp1, gp, bpp, sp, o3);
    prv[t][0] = o3[0]; prv[t][1] = o3[1]; prv[t][2] = o3[2];
  }
  __syncthreads();
  // phase 1: stage all 64 rows x 256 ch of A; lane = row, wave = 64-ch chunk
  {
    int r = t & 63, c8 = t >> 6;
    int j = jrow[r];
    int i = base4 + (r >> 4);
    float p0 = prv[r][0], p1 = prv[r][1], p2 = prv[r][2];
    const u16* kp_ = xk + (size_t)j*256 + c8*64;
    const u16* qp_ = xq + (size_t)i*256 + c8*64;
#pragma unroll
    for (int ii = 0; ii < 8; ++ii) {
      bf16x8 kv = *(const bf16x8*)(kp_ + ii*8);
      bf16x8 qv = *(const bf16x8*)(qp_ + ii*8);
      bf16x8 ov;
#pragma unroll
      for (int jj = 0; jj < 8; ++jj) {
        int ch = c8*64 + ii*8 + jj;
        float v = b2f((u16)kv[jj]) - b2f((u16)qv[jj])
                + p0*cw0[ch] + p1*cw1[ch] + p2*cw2[ch] + cb2[ch];
        v = fmaxf(fmaf(v, cscl[ch], csft[ch]), 0.f);
        ov[jj] = (short)f2b(v);
      }
      *(bf16x8*)&sA[r][c8*64 + ii*8] = ov;
    }
  }
  __syncthreads();
  // phase 2: MFMA; B fragments straight from global Ww1t (L1-hot 16KB)
  const f32x4 zero = {0.f,0.f,0.f,0.f};
  f32x4 acc[2] = {zero, zero};
  int wv = t >> 6, l = t & 63;
  int lr = l & 15, hi = l >> 4;
#pragma unroll
  for (int k0 = 0; k0 < 256; k0 += 32) {
    bf16x8 a  = *(const bf16x8*)&sA[wv*16 + lr][k0 + hi*8];
    bf16x8 b0 = *(const bf16x8*)(Ww1t + (size_t)lr*256      + k0 + hi*8);
    bf16x8 b1 = *(const bf16x8*)(Ww1t + (size_t)(16+lr)*256 + k0 + hi*8);
    acc[0] = __builtin_amdgcn_mfma_f32_16x16x32_bf16(a, b0, acc[0], 0, 0, 0);
    acc[1] = __builtin_amdgcn_mfma_f32_16x16x32_bf16(a, b1, acc[1], 0, 0, 0);
  }
  __syncthreads();                        // all sA reads done before sred reuse
  float* sred = (float*)&sA[0][0];
#pragma unroll
  for (int fn = 0; fn < 2; ++fn) {
    int col = fn*16 + lr;
    float bv = bww1[col];
    float s1 = 0.f, s2 = 0.f;
#pragma unroll
    for (int r = 0; r < 4; ++r) {
      int grow = blockIdx.x*64 + wv*16 + hi*4 + r;
      float v = acc[fn][r] + bv;
      w1[(size_t)grow*32 + col] = f2b(v);
      s1 += v; s2 += v*v;
    }
    s1 += __shfl_xor(s1, 16); s1 += __shfl_xor(s1, 32);
    s2 += __shfl_xor(s2, 16); s2 += __shfl_xor(s2, 32);
    if (l < 16) { sred[(wv*2+fn)*16 + lr] = s1; sred[128 + (wv*2+fn)*16 + lr] = s2; }
  }
  __syncthreads();
  if (t < 32) {
    int fn = t >> 4, lrr = t & 15;
    float a = 0.f, b = 0.f;
#pragma unroll
    for (int w2 = 0; w2 < 4; ++w2) {
      a += sred[(w2*2+fn)*16 + lrr];
      b += sred[128 + (w2*2+fn)*16 + lrr];
    }
    atomicAdd(&sw1out[fn*16 + lrr], a);
    atomicAdd(&sw1out[32 + fn*16 + lrr], b);
  }
}

// ---------------------------------------------------------------- second linear_w + softmax + aggregate
__launch_bounds__(256)
__global__ void aggr_k(const u16* __restrict__ w1, const float* sw1,
                       const float* gw2, const float* bw2,
                       const float* __restrict__ Ww2, const float* bww2,
                       const u16* __restrict__ xv,
                       const float* __restrict__ p, const int* __restrict__ idx,
                       const float* Wp1, const float* bp1, const float* gp, const float* bpp,
                       const float* sp, const float* __restrict__ Wp2, const float* bp2,
                       float* __restrict__ y) {
  __shared__ float lw1[16][32];
  __shared__ float lW2[32][32];
  __shared__ float sw2[16][33];
  __shared__ float prv[16][4];
  __shared__ int   jidx[16];
  int i = blockIdx.x, t = threadIdx.x;
  for (int e = t; e < 1024; e += 256) lW2[e >> 5][e & 31] = Ww2[e];
  for (int e = t; e < 512; e += 256) {
    int c32 = e & 31;
    float v = b2f(w1[(size_t)i*512 + e]);
    v = fmaxf(bn_ap(v, sw1, 32, c32, INV_NK, gw2[c32], bw2[c32]), 0.0f);
    lw1[e >> 5][c32] = v;
  }
  if (t < 16) jidx[t] = idx[i*16 + t] & 8191;
  __syncthreads();
  if (t < 16) {
    float o3[3];
    comp_prv(p, i, jidx[t], Wp1, bp1, gp, bpp, sp, o3);
    prv[t][0] = o3[0]; prv[t][1] = o3[1]; prv[t][2] = o3[2];
  }
  for (int e = t; e < 512; e += 256) {
    int k = e >> 5, c32 = e & 31;
    float a = bww2[c32];
#pragma unroll
    for (int j = 0; j < 32; ++j) a += lw1[k][j] * lW2[j][c32];
    sw2[k][c32] = a;
  }
  __syncthreads();
  if (t < 32) {
    float mx = -3.0e38f;
#pragma unroll
    for (int k = 0; k < 16; ++k) mx = fmaxf(mx, sw2[k][t]);
    float s = 0.f;
#pragma unroll
    for (int k = 0; k < 16; ++k) { float e2 = expf(sw2[k][t] - mx); sw2[k][t] = e2; s += e2; }
    float r = 1.0f / s;
#pragma unroll
    for (int k = 0; k < 16; ++k) sw2[k][t] *= r;
  }
  __syncthreads();
  int c = t;
  float wp0 = Wp2[c], wp1v = Wp2[256+c], wp2v = Wp2[512+c];
  float bbv = bp2[c];
  int c32 = c & 31;
  float acc = 0.f;
#pragma unroll
  for (int k = 0; k < 16; ++k) {
    int j = jidx[k];
    float pr = prv[k][0]*wp0 + prv[k][1]*wp1v + prv[k][2]*wp2v + bbv;
    float xvv = b2f(xv[(size_t)j*256 + c]);
    acc += (xvv + pr) * sw2[k][c32];
  }
  y[(size_t)i*256 + c] = acc;
}

// ---------------------------------------------------------------- epilogue (x2 only)
__launch_bounds__(256)
__global__ void final_k(const float* __restrict__ t0, const float* s0,
                        const float* g0, const float* b0,
                        const float* __restrict__ t3, const float* s3,
                        const float* g3, const float* b3,
                        float* __restrict__ out) {
  int i = blockIdx.x, c = threadIdx.x;
  size_t off = (size_t)i*256 + c;
  float h0 = fmaxf(bn_ap(t0[off], s0, 256, c, INV_N, g0[c], b0[c]), 0.0f);
  float v3 = bn_ap(t3[off], s3, 256, c, INV_N, g3[c], b3[c]);
  out[24576 + off] = fmaxf(v3 + h0, 0.0f);
}

// ---------------------------------------------------------------- launch
extern "C" void kernel_launch(void* const* d_in, const int* in_sizes, int n_in,
                              void* d_out, int out_size, void* d_ws, size_t ws_size,
                              hipStream_t stream) {
  (void)in_sizes; (void)n_in; (void)out_size; (void)ws_size;
  const float* p    = (const float*)d_in[0];
  const float* x    = (const float*)d_in[1];
  const int*   o    = (const int*)  d_in[2];
  const float* W_pa = (const float*)d_in[3];
  const float* g_pa = (const float*)d_in[4];
  const float* b_pa = (const float*)d_in[5];
  const float* W1   = (const float*)d_in[6];
  const float* g1   = (const float*)d_in[7];
  const float* b1   = (const float*)d_in[8];
  const float* Wq   = (const float*)d_in[9];
  const float* bq   = (const float*)d_in[10];
  const float* Wk   = (const float*)d_in[11];
  const float* bk   = (const float*)d_in[12];
  const float* Wv   = (const float*)d_in[13];
  const float* bv   = (const float*)d_in[14];
  const float* Wp1  = (const float*)d_in[15];
  const float* bp1  = (const float*)d_in[16];
  const float* gp   = (const float*)d_in[17];
  const float* bpp  = (const float*)d_in[18];
  const float* Wp2  = (const float*)d_in[19];
  const float* bp2  = (const float*)d_in[20];
  const float* gw1  = (const float*)d_in[21];
  const float* bw1  = (const float*)d_in[22];
  const float* Ww1  = (const float*)d_in[23];
  const float* bww1 = (const float*)d_in[24];
  const float* gw2  = (const float*)d_in[25];
  const float* bw2  = (const float*)d_in[26];
  const float* Ww2  = (const float*)d_in[27];
  const float* bww2 = (const float*)d_in[28];
  const float* g2   = (const float*)d_in[29];
  const float* b2   = (const float*)d_in[30];
  const float* W3   = (const float*)d_in[31];
  const float* g3   = (const float*)d_in[32];
  const float* b3   = (const float*)d_in[33];

  // workspace layout (~38.3 MB)
  char* ws = (char*)d_ws;
  float* t0  = (float*)(ws + 0);          // [8192,256] f32 (live til final_k)
  float* t1  = (float*)(ws + 8388608);    // [8192,256] f32 (later: y)
  u16*   xq  = (u16*)  (ws + 16777216);   // [8192,256] bf16
  u16*   xk  = (u16*)  (ws + 20971520);   // [8192,256] bf16
  u16*   xv  = (u16*)  (ws + 25165824);   // [8192,256] bf16
  u16*   w1  = (u16*)  (ws + 29360128);   // [131072,32] bf16 (8 MB)
  int*   idx = (int*)  (ws + 37748736);   // [8192,16] i32
  float* st  = (float*)(ws + 38273024);   // stats block (16 KB)
  u16*   Ww1t= (u16*)  (ws + 38289408);   // [32][256] bf16 (16 KB)
  float* y   = t1;                        // aggr output (t1 dead after qkv)
  float* t3  = (float*)(ws + 16777216);   // aliases xq+xk (dead after w1gemm)
  float4* pp = (float4*)(ws + 29360128);  // aliases w1 (knn finishes first)
  // st offsets: s0=0, s1=512, sw=1024, sy=1536, s3=2048, sw1=2560, sp=2624

  hipMemsetAsync(st, 0, 16384, stream);

  prep_k<<<96, 256, 0, stream>>>(p, o, Ww1, pp, Ww1t, (float*)d_out);
  knn_k<<<2048, 256, 0, stream>>>(pp, idx);

  mfgemm_k<false, true><<<dim3(128, 4), 256, 0, stream>>>(
      x, nullptr, nullptr, nullptr, 0.f, W_pa, t0, st + 0, 64, 256);

  mfgemm_k<true, true><<<dim3(128, 4), 256, 0, stream>>>(
      t0, st + 0, g_pa, b_pa, INV_N, W1, t1, st + 512, 256, 256);

  qkv_k<<<dim3(128, 4), 256, 0, stream>>>(
      t1, st + 512, g1, b1, Wq, bq, Wk, bk, Wv, bv, xq, xk, xv);

  prstats_k<<<128, 256, 0, stream>>>(p, idx, Wp1, bp1, st + 2624);

  wstats_k<<<256, 256, 0, stream>>>(xk, xq, p, idx, Wp1, bp1, gp, bpp,
                                    st + 2624, Wp2, bp2, st + 1024);

  w1gemm_k<<<2048, 256, 0, stream>>>(xk, xq, p, idx, Wp1, bp1, gp, bpp,
                                     st + 2624, Wp2, bp2, st + 1024,
                                     gw1, bw1, Ww1t, bww1, w1, st + 2560);

  aggr_k<<<8192, 256, 0, stream>>>(w1, st + 2560, gw2, bw2, Ww2, bww2, xv,
                                   p, idx, Wp1, bp1, gp, bpp, st + 2624,
                                   Wp2, bp2, y);
  stats256_k<<<256, 256, 0, stream>>>(y, st + 1536);

  mfgemm_k<true, true><<<dim3(128, 4), 256, 0, stream>>>(
      y, st + 1536, g2, b2, INV_N, W3, t3, st + 2048, 256, 256);

  final_k<<<8192, 256, 0, stream>>>(t0, st + 0, g_pa, b_pa,
                                    t3, st + 2048, g3, b3, (float*)d_out);
}

// Round 9
// 260.524 us; speedup vs baseline: 3.6251x; 1.0256x over previous
//
#include <hip/hip_runtime.h>
#include <hip/hip_bf16.h>

// N=8192, K=16, CIN=64, C=256, S=8, C/S=32 ; float tensors are float32.
#define INV_N  (1.0f/8192.0f)
#define INV_NK (1.0f/131072.0f)

typedef __attribute__((ext_vector_type(8))) short bf16x8;
typedef __attribute__((ext_vector_type(4))) float f32x4;
typedef unsigned short u16;

__device__ __forceinline__ u16 f2b(float f) {   // f32 -> bf16 RNE
  unsigned u = __float_as_uint(f);
  return (u16)((u + 0x7FFFu + ((u >> 16) & 1u)) >> 16);
}
__device__ __forceinline__ float b2f(u16 u) {
  return __uint_as_float(((unsigned)u) << 16);
}

__device__ __forceinline__ float bn_ap(float v, const float* st, int C, int ch,
                                       float inv, float g, float b) {
  float m = st[ch] * inv;
  float var = st[C + ch] * inv - m * m;
  return (v - m) * rsqrtf(var + 1e-5f) * g + b;
}

// ---------------------------------------------------------------- prep: p copy + o + pack4 + Ww1 transpose
__launch_bounds__(256)
__global__ void prep_k(const float* __restrict__ p, const int* __restrict__ o,
                       const float* __restrict__ Ww1,
                       float4* __restrict__ pp, u16* __restrict__ Ww1t,
                       float* __restrict__ out) {
  int b = blockIdx.x, t = threadIdx.x;
  int e = b*256 + t;
  if (e < 24576) out[e] = p[e];
  if (e == 0) out[24576 + 2097152] = (float)o[0];
  if (e < 8192) {
    float x = p[e*3+0], y = p[e*3+1], z = p[e*3+2];
    pp[e] = make_float4(x, y, z, (x*x + y*y) + z*z);
  }
  if (b >= 88) {                     // 8 blocks cover Ww1 (256x32 -> [32][256])
    int q = (b - 88)*1024 + t*4;
#pragma unroll
    for (int ii = 0; ii < 4; ++ii) {
      int e2 = q + ii;
      int k = e2 >> 5, n = e2 & 31;
      Ww1t[n*256 + k] = f2b(Ww1[e2]);
    }
  }
}

// ---------------------------------------------------------------- KNN
// 4 waves/block, one query/wave; branchless med3 sorted-insert on
// index-packed distances (low 13 bits = candidate index); 5-deep/lane.
__launch_bounds__(256)
__global__ void knn_k(const float4* __restrict__ pp, int* __restrict__ idxo) {
  int wave = threadIdx.x >> 6;
  int lane = threadIdx.x & 63;
  int q = blockIdx.x*4 + wave;
  float4 qv = pp[q];
  const float BIG = __uint_as_float(0x7F7FFFFFu);
  float d[5];
#pragma unroll
  for (int s = 0; s < 5; ++s) d[s] = BIG;
#pragma unroll 4
  for (int it = 0; it < 128; ++it) {
    int j = it*64 + lane;
    float4 c = pp[j];
    float dot = qv.x*c.x + (qv.y*c.y + qv.z*c.z);
    float d2 = __fmaf_rn(-2.0f, dot, qv.w + c.w);
    float pk = __uint_as_float((__float_as_uint(d2) & 0xFFFFE000u) | (unsigned)j);
#pragma unroll
    for (int s = 4; s >= 1; --s)
      d[s] = fminf(fmaxf(d[s-1], pk), d[s]);
    d[0] = fminf(d[0], pk);
  }
  for (int r = 0; r < 16; ++r) {
    float bd = d[0];
#pragma unroll
    for (int m = 1; m < 64; m <<= 1)
      bd = fminf(bd, __shfl_xor(bd, m));
    if (lane == 0) idxo[q*16 + r] = (int)(__float_as_uint(bd) & 0x1FFFu);
    if (d[0] == bd) {                       // unique -> exactly one lane shifts
#pragma unroll
      for (int s = 0; s < 4; ++s) d[s] = d[s+1];
      d[4] = BIG;
    }
  }
}

// ---------------------------------------------------------------- MFMA GEMM (f32 out, fused col-stats)
template<bool BNA, bool STATS>
__launch_bounds__(256)
__global__ void mfgemm_k(const float* __restrict__ A, const float* __restrict__ st,
                         const float* __restrict__ g, const float* __restrict__ bb,
                         float inv_cnt,
                         const float* __restrict__ W, float* __restrict__ out,
                         float* __restrict__ stout, int KA, int NOUT) {
  __shared__ short As[64][72];
  __shared__ short Bt[64][72];
  __shared__ float lscl[256], lsft[256];
  int t = threadIdx.x;
  int m0 = blockIdx.x * 64, n0 = blockIdx.y * 64;
  if (BNA) {
    for (int e = t; e < KA; e += 256) {
      float m = st[e] * inv_cnt;
      float var = st[KA + e] * inv_cnt - m*m;
      float sc = rsqrtf(var + 1e-5f) * g[e];
      lscl[e] = sc; lsft[e] = bb[e] - m*sc;
    }
    __syncthreads();
  }
  const f32x4 zero = {0.f, 0.f, 0.f, 0.f};
  f32x4 acc[2][2] = {{zero, zero}, {zero, zero}};
  int wv = t >> 6, l = t & 63;
  int wm = wv & 1, wn = wv >> 1;
  int lr = l & 15, lk = (l >> 4) * 8;
  int ra = t >> 4, qa = t & 15;
  int bn = t & 63, bkc = t >> 6;           // B-stage mapping
  for (int k0 = 0; k0 < KA; k0 += 64) {
#pragma unroll
    for (int rp = 0; rp < 4; ++rp) {
      int r = rp*16 + ra;
      float4 av = *(const float4*)(A + (size_t)(m0 + r)*KA + k0 + qa*4);
      float vv[4] = {av.x, av.y, av.z, av.w};
      short4 s;
#pragma unroll
      for (int jj = 0; jj < 4; ++jj) {
        float v = vv[jj];
        if (BNA) { int ch = k0 + qa*4 + jj; v = fmaxf(fmaf(v, lscl[ch], lsft[ch]), 0.f); }
        ((u16*)&s)[jj] = f2b(v);
      }
      *(short4*)&As[r][qa*4] = s;
    }
    {
      float v[16];
#pragma unroll
      for (int j2 = 0; j2 < 16; ++j2)
        v[j2] = W[(size_t)(k0 + bkc*16 + j2)*NOUT + n0 + bn];
      bf16x8 w0, w1v;
#pragma unroll
      for (int j2 = 0; j2 < 8; ++j2) {
        w0[j2]  = (short)f2b(v[j2]);
        w1v[j2] = (short)f2b(v[8 + j2]);
      }
      *(bf16x8*)&Bt[bn][bkc*16]     = w0;
      *(bf16x8*)&Bt[bn][bkc*16 + 8] = w1v;
    }
    __syncthreads();
#pragma unroll
    for (int fk = 0; fk < 2; ++fk) {
      bf16x8 a0 = *(const bf16x8*)&As[wm*32 +      lr][fk*32 + lk];
      bf16x8 a1 = *(const bf16x8*)&As[wm*32 + 16 + lr][fk*32 + lk];
      bf16x8 b0 = *(const bf16x8*)&Bt[wn*32 +      lr][fk*32 + lk];
      bf16x8 b1 = *(const bf16x8*)&Bt[wn*32 + 16 + lr][fk*32 + lk];
      acc[0][0] = __builtin_amdgcn_mfma_f32_16x16x32_bf16(a0, b0, acc[0][0], 0, 0, 0);
      acc[0][1] = __builtin_amdgcn_mfma_f32_16x16x32_bf16(a0, b1, acc[0][1], 0, 0, 0);
      acc[1][0] = __builtin_amdgcn_mfma_f32_16x16x32_bf16(a1, b0, acc[1][0], 0, 0, 0);
      acc[1][1] = __builtin_amdgcn_mfma_f32_16x16x32_bf16(a1, b1, acc[1][1], 0, 0, 0);
    }
    __syncthreads();
  }
#pragma unroll
  for (int fn = 0; fn < 2; ++fn) {
    int col = n0 + wn*32 + fn*16 + lr;
    float s1 = 0.f, s2 = 0.f;
#pragma unroll
    for (int fm = 0; fm < 2; ++fm) {
#pragma unroll
      for (int r = 0; r < 4; ++r) {
        int row = m0 + wm*32 + fm*16 + (l >> 4)*4 + r;
        float v = acc[fm][fn][r];
        out[(size_t)row*NOUT + col] = v;
        if (STATS) { s1 += v; s2 += v*v; }
      }
    }
    if (STATS) {
      s1 += __shfl_xor(s1, 16); s1 += __shfl_xor(s1, 32);
      s2 += __shfl_xor(s2, 16); s2 += __shfl_xor(s2, 32);
      if (l < 16) {
        atomicAdd(&stout[col], s1);
        atomicAdd(&stout[NOUT + col], s2);
      }
    }
  }
}

// ---------------------------------------------------------------- fused Q/K/V MFMA (bf16 out)
__launch_bounds__(256)
__global__ void qkv_k(const float* __restrict__ t1, const float* __restrict__ st,
                      const float* __restrict__ g1, const float* __restrict__ b1,
                      const float* __restrict__ Wq, const float* __restrict__ bq,
                      const float* __restrict__ Wk, const float* __restrict__ bk,
                      const float* __restrict__ Wv, const float* __restrict__ bv,
                      u16* __restrict__ xq, u16* __restrict__ xk, u16* __restrict__ xv) {
  __shared__ short As[64][72];
  __shared__ short Bt[3][64][72];
  __shared__ float lscl[256], lsft[256];
  int t = threadIdx.x;
  int m0 = blockIdx.x * 64, n0 = blockIdx.y * 64;
  {
    int e = t;
    float m = st[e] * INV_N;
    float var = st[256 + e] * INV_N - m*m;
    float sc = rsqrtf(var + 1e-5f) * g1[e];
    lscl[e] = sc; lsft[e] = b1[e] - m*sc;
  }
  __syncthreads();
  const f32x4 zero = {0.f, 0.f, 0.f, 0.f};
  f32x4 acc[3][2][2];
#pragma unroll
  for (int w = 0; w < 3; ++w)
#pragma unroll
    for (int i = 0; i < 2; ++i)
#pragma unroll
      for (int j = 0; j < 2; ++j) acc[w][i][j] = zero;
  int wv = t >> 6, l = t & 63;
  int wm = wv & 1, wn = wv >> 1;
  int lr = l & 15, lk = (l >> 4) * 8;
  int ra = t >> 4, qa = t & 15;
  int bn = t & 63, bkc = t >> 6;
  const float* Ws[3] = {Wq, Wk, Wv};
  for (int k0 = 0; k0 < 256; k0 += 64) {
#pragma unroll
    for (int rp = 0; rp < 4; ++rp) {
      int r = rp*16 + ra;
      float4 av = *(const float4*)(t1 + (size_t)(m0 + r)*256 + k0 + qa*4);
      float vv[4] = {av.x, av.y, av.z, av.w};
      short4 s;
#pragma unroll
      for (int jj = 0; jj < 4; ++jj) {
        int ch = k0 + qa*4 + jj;
        float v = fmaxf(fmaf(vv[jj], lscl[ch], lsft[ch]), 0.f);
        ((u16*)&s)[jj] = f2b(v);
      }
      *(short4*)&As[r][qa*4] = s;
    }
#pragma unroll
    for (int w = 0; w < 3; ++w) {
      float v[16];
#pragma unroll
      for (int j2 = 0; j2 < 16; ++j2)
        v[j2] = Ws[w][(size_t)(k0 + bkc*16 + j2)*256 + n0 + bn];
      bf16x8 w0, w1v;
#pragma unroll
      for (int j2 = 0; j2 < 8; ++j2) {
        w0[j2]  = (short)f2b(v[j2]);
        w1v[j2] = (short)f2b(v[8 + j2]);
      }
      *(bf16x8*)&Bt[w][bn][bkc*16]     = w0;
      *(bf16x8*)&Bt[w][bn][bkc*16 + 8] = w1v;
    }
    __syncthreads();
#pragma unroll
    for (int fk = 0; fk < 2; ++fk) {
      bf16x8 a0 = *(const bf16x8*)&As[wm*32 +      lr][fk*32 + lk];
      bf16x8 a1 = *(const bf16x8*)&As[wm*32 + 16 + lr][fk*32 + lk];
#pragma unroll
      for (int w = 0; w < 3; ++w) {
        bf16x8 b0 = *(const bf16x8*)&Bt[w][wn*32 +      lr][fk*32 + lk];
        bf16x8 b1 = *(const bf16x8*)&Bt[w][wn*32 + 16 + lr][fk*32 + lk];
        acc[w][0][0] = __builtin_amdgcn_mfma_f32_16x16x32_bf16(a0, b0, acc[w][0][0], 0, 0, 0);
        acc[w][0][1] = __builtin_amdgcn_mfma_f32_16x16x32_bf16(a0, b1, acc[w][0][1], 0, 0, 0);
        acc[w][1][0] = __builtin_amdgcn_mfma_f32_16x16x32_bf16(a1, b0, acc[w][1][0], 0, 0, 0);
        acc[w][1][1] = __builtin_amdgcn_mfma_f32_16x16x32_bf16(a1, b1, acc[w][1][1], 0, 0, 0);
      }
    }
    __syncthreads();
  }
  u16* outs[3] = {xq, xk, xv};
  const float* bs[3] = {bq, bk, bv};
#pragma unroll
  for (int w = 0; w < 3; ++w) {
#pragma unroll
    for (int fn = 0; fn < 2; ++fn) {
      int col = n0 + wn*32 + fn*16 + lr;
      float bvv = bs[w][col];
#pragma unroll
      for (int fm = 0; fm < 2; ++fm) {
#pragma unroll
        for (int r = 0; r < 4; ++r) {
          int row = m0 + wm*32 + fm*16 + (l >> 4)*4 + r;
          outs[w][(size_t)row*256 + col] = f2b(acc[w][fm][fn][r] + bvv);
        }
      }
    }
  }
}

// ---------------------------------------------------------------- stats (y only)
__launch_bounds__(256)
__global__ void stats256_k(const float* __restrict__ X, float* __restrict__ st) {
  int c = threadIdx.x;
  int r0 = blockIdx.x * 32;
  float s1 = 0.f, s2 = 0.f;
  for (int r = 0; r < 32; ++r) {
    float v = X[(size_t)(r0 + r)*256 + c];
    s1 += v; s2 += v*v;
  }
  atomicAdd(&st[c], s1);
  atomicAdd(&st[256 + c], s2);
}

// ---------------------------------------------------------------- p_r helpers
__device__ __forceinline__ void comp_pr1(const float* p, int i, int j,
                                         const float* Wp1, const float* bp1,
                                         float pr1[3]) {
  float rx = p[j*3+0] - p[i*3+0];
  float ry = p[j*3+1] - p[i*3+1];
  float rz = p[j*3+2] - p[i*3+2];
#pragma unroll
  for (int c = 0; c < 3; ++c)
    pr1[c] = rx*Wp1[c] + ry*Wp1[3+c] + rz*Wp1[6+c] + bp1[c];
}

__device__ __forceinline__ void comp_prv(const float* p, int i, int j,
                                         const float* Wp1, const float* bp1,
                                         const float* gp, const float* bpp,
                                         const float* sp, float o3[3]) {
  float pr1[3];
  comp_pr1(p, i, j, Wp1, bp1, pr1);
#pragma unroll
  for (int c = 0; c < 3; ++c)
    o3[c] = fmaxf(bn_ap(pr1[c], sp, 3, c, INV_NK, gp[c], bpp[c]), 0.0f);
}

__launch_bounds__(256)
__global__ void prstats_k(const float* __restrict__ p, const int* __restrict__ idx,
                          const float* Wp1, const float* bp1, float* __restrict__ sp) {
  float s[3] = {0,0,0}, s2[3] = {0,0,0};
  for (int it = 0; it < 4; ++it) {
    int e = blockIdx.x*1024 + it*256 + threadIdx.x;
    int i = e >> 4;
    int j = idx[e] & 8191;
    float pr1[3];
    comp_pr1(p, i, j, Wp1, bp1, pr1);
#pragma unroll
    for (int c = 0; c < 3; ++c) { s[c] += pr1[c]; s2[c] += pr1[c]*pr1[c]; }
  }
#pragma unroll
  for (int m = 1; m < 64; m <<= 1) {
#pragma unroll
    for (int c = 0; c < 3; ++c) {
      s[c]  += __shfl_xor(s[c],  m);
      s2[c] += __shfl_xor(s2[c], m);
    }
  }
  __shared__ float red[4][6];
  int wv = threadIdx.x >> 6, lane = threadIdx.x & 63;
  if (lane == 0) {
#pragma unroll
    for (int c = 0; c < 3; ++c) { red[wv][c] = s[c]; red[wv][3+c] = s2[c]; }
  }
  __syncthreads();
  if (threadIdx.x < 6) {
    float v = red[0][threadIdx.x] + red[1][threadIdx.x] +
              red[2][threadIdx.x] + red[3][threadIdx.x];
    atomicAdd(&sp[threadIdx.x], v);
  }
}

// ---------------------------------------------------------------- stats of w (no materialization)
__launch_bounds__(256)
__global__ void wstats_k(const u16* __restrict__ xk, const u16* __restrict__ xq,
                         const float* __restrict__ p, const int* __restrict__ idx,
                         const float* Wp1, const float* bp1, const float* gp, const float* bpp,
                         const float* sp, const float* __restrict__ Wp2, const float* bp2,
                         float* __restrict__ sw) {
  __shared__ float prv[8][16][4];
  __shared__ int   jidx[8][16];
  int base = blockIdx.x * 8;
  int t = threadIdx.x;
  if (t < 128) {
    int pt = t >> 4, k = t & 15;
    int j = idx[(base + pt)*16 + k] & 8191;
    jidx[pt][k] = j;
    float o3[3];
    comp_prv(p, base + pt, j, Wp1, bp1, gp, bpp, sp, o3);
    prv[pt][k][0] = o3[0]; prv[pt][k][1] = o3[1]; prv[pt][k][2] = o3[2];
  }
  __syncthreads();
  int c = t;
  float wp0 = Wp2[c], wp1v = Wp2[256+c], wp2v = Wp2[512+c];
  float bbv = bp2[c];
  float s1 = 0.f, s2 = 0.f;
  for (int pt = 0; pt < 8; ++pt) {
    int i = base + pt;
    float xqv = b2f(xq[(size_t)i*256 + c]);
#pragma unroll
    for (int k = 0; k < 16; ++k) {
      int j = jidx[pt][k];
      float pr = prv[pt][k][0]*wp0 + prv[pt][k][1]*wp1v + prv[pt][k][2]*wp2v + bbv;
      float wval = b2f(xk[(size_t)j*256 + c]) - xqv + pr;
      s1 += wval; s2 += wval*wval;
    }
  }
  atomicAdd(&sw[c], s1);
  atomicAdd(&sw[256 + c], s2);
}

// ---------------------------------------------------------------- w1gemm v3: direct-gather A (no LDS-A), B from global Ww1t
__launch_bounds__(256)
__global__ void w1gemm_k(const u16* __restrict__ xk, const u16* __restrict__ xq,
                         const float* __restrict__ p, const int* __restrict__ idx,
                         const float* Wp1, const float* bp1, const float* gp, const float* bpp,
                         const float* sp, const float* __restrict__ Wp2, const float* bp2,
                         const float* sw, const float* gw1, const float* bw1,
                         const u16* __restrict__ Ww1t, const float* bww1,
                         u16* __restrict__ w1, float* __restrict__ sw1out) {
  __shared__ float cc[6][256];    // cscl,csft,wp2r0,wp2r1,wp2r2,bp2
  __shared__ float prv[64][3];
  __shared__ int   jrow[64];
  __shared__ float sred[256];
  int t = threadIdx.x;
  int base4 = blockIdx.x * 4;
  {
    float m = sw[t]*INV_NK;
    float var = sw[256+t]*INV_NK - m*m;
    float sc = rsqrtf(var + 1e-5f)*gw1[t];
    cc[0][t] = sc; cc[1][t] = bw1[t] - m*sc;
    cc[2][t] = Wp2[t]; cc[3][t] = Wp2[256+t]; cc[4][t] = Wp2[512+t]; cc[5][t] = bp2[t];
  }
  if (t < 64) {
    int grow = blockIdx.x*64 + t;
    int j = idx[grow] & 8191;
    jrow[t] = j;
    float o3[3];
    comp_prv(p, grow >> 4, j, Wp1, bp1, gp, bpp, sp, o3);
    prv[t][0] = o3[0]; prv[t][1] = o3[1]; prv[t][2] = o3[2];
  }
  __syncthreads();
  int wv = t >> 6, l = t & 63;
  int lr = l & 15, hi = l >> 4;
  int row = wv*16 + lr;                    // A-fragment row within block tile
  int j = jrow[row];
  int iq = base4 + wv;                     // rows wv*16..+15 all belong to query wv
  float p0 = prv[row][0], p1 = prv[row][1], p2 = prv[row][2];
  const u16* kp_ = xk + (size_t)j*256 + hi*8;
  const u16* qp_ = xq + (size_t)iq*256 + hi*8;
  const f32x4 zero = {0.f,0.f,0.f,0.f};
  f32x4 acc[2] = {zero, zero};
#pragma unroll
  for (int k0 = 0; k0 < 256; k0 += 32) {
    int kb = k0 + hi*8;
    bf16x8 kv = *(const bf16x8*)(kp_ + k0);
    bf16x8 qv = *(const bf16x8*)(qp_ + k0);
    bf16x8 a;
#pragma unroll
    for (int h = 0; h < 2; ++h) {
      f32x4 c0 = *(const f32x4*)&cc[0][kb + h*4];
      f32x4 c1 = *(const f32x4*)&cc[1][kb + h*4];
      f32x4 c2 = *(const f32x4*)&cc[2][kb + h*4];
      f32x4 c3 = *(const f32x4*)&cc[3][kb + h*4];
      f32x4 c4 = *(const f32x4*)&cc[4][kb + h*4];
      f32x4 c5 = *(const f32x4*)&cc[5][kb + h*4];
#pragma unroll
      for (int jj = 0; jj < 4; ++jj) {
        int e = h*4 + jj;
        float v = b2f((u16)kv[e]) - b2f((u16)qv[e])
                + p0*c2[jj] + p1*c3[jj] + p2*c4[jj] + c5[jj];
        v = fmaxf(fmaf(v, c0[jj], c1[jj]), 0.f);
        a[e] = (short)f2b(v);
      }
    }
    bf16x8 b0 = *(const bf16x8*)(Ww1t + (size_t)lr*256      + kb);
    bf16x8 b1 = *(const bf16x8*)(Ww1t + (size_t)(16+lr)*256 + kb);
    acc[0] = __builtin_amdgcn_mfma_f32_16x16x32_bf16(a, b0, acc[0], 0, 0, 0);
    acc[1] = __builtin_amdgcn_mfma_f32_16x16x32_bf16(a, b1, acc[1], 0, 0, 0);
  }
  // epilogue + fused w1-stats
#pragma unroll
  for (int fn = 0; fn < 2; ++fn) {
    int col = fn*16 + lr;
    float bv = bww1[col];
    float s1 = 0.f, s2 = 0.f;
#pragma unroll
    for (int r = 0; r < 4; ++r) {
      int grow = blockIdx.x*64 + wv*16 + hi*4 + r;
      float v = acc[fn][r] + bv;
      w1[(size_t)grow*32 + col] = f2b(v);
      s1 += v; s2 += v*v;
    }
    s1 += __shfl_xor(s1, 16); s1 += __shfl_xor(s1, 32);
    s2 += __shfl_xor(s2, 16); s2 += __shfl_xor(s2, 32);
    if (l < 16) { sred[(wv*2+fn)*16 + lr] = s1; sred[128 + (wv*2+fn)*16 + lr] = s2; }
  }
  __syncthreads();
  if (t < 32) {
    int fn = t >> 4, lrr = t & 15;
    float a = 0.f, b = 0.f;
#pragma unroll
    for (int w2 = 0; w2 < 4; ++w2) {
      a += sred[(w2*2+fn)*16 + lrr];
      b += sred[128 + (w2*2+fn)*16 + lrr];
    }
    atomicAdd(&sw1out[fn*16 + lrr], a);
    atomicAdd(&sw1out[32 + fn*16 + lrr], b);
  }
}

// ---------------------------------------------------------------- second linear_w + softmax + aggregate
__launch_bounds__(256)
__global__ void aggr_k(const u16* __restrict__ w1, const float* sw1,
                       const float* gw2, const float* bw2,
                       const float* __restrict__ Ww2, const float* bww2,
                       const u16* __restrict__ xv,
                       const float* __restrict__ p, const int* __restrict__ idx,
                       const float* Wp1, const float* bp1, const float* gp, const float* bpp,
                       const float* sp, const float* __restrict__ Wp2, const float* bp2,
                       float* __restrict__ y) {
  __shared__ float lw1[16][32];
  __shared__ float lW2[32][32];
  __shared__ float sw2[16][33];
  __shared__ float prv[16][4];
  __shared__ int   jidx[16];
  int i = blockIdx.x, t = threadIdx.x;
  for (int e = t; e < 1024; e += 256) lW2[e >> 5][e & 31] = Ww2[e];
  for (int e = t; e < 512; e += 256) {
    int c32 = e & 31;
    float v = b2f(w1[(size_t)i*512 + e]);
    v = fmaxf(bn_ap(v, sw1, 32, c32, INV_NK, gw2[c32], bw2[c32]), 0.0f);
    lw1[e >> 5][c32] = v;
  }
  if (t < 16) jidx[t] = idx[i*16 + t] & 8191;
  __syncthreads();
  if (t < 16) {
    float o3[3];
    comp_prv(p, i, jidx[t], Wp1, bp1, gp, bpp, sp, o3);
    prv[t][0] = o3[0]; prv[t][1] = o3[1]; prv[t][2] = o3[2];
  }
  for (int e = t; e < 512; e += 256) {
    int k = e >> 5, c32 = e & 31;
    float a = bww2[c32];
#pragma unroll
    for (int j = 0; j < 32; ++j) a += lw1[k][j] * lW2[j][c32];
    sw2[k][c32] = a;
  }
  __syncthreads();
  if (t < 32) {
    float mx = -3.0e38f;
#pragma unroll
    for (int k = 0; k < 16; ++k) mx = fmaxf(mx, sw2[k][t]);
    float s = 0.f;
#pragma unroll
    for (int k = 0; k < 16; ++k) { float e2 = expf(sw2[k][t] - mx); sw2[k][t] = e2; s += e2; }
    float r = 1.0f / s;
#pragma unroll
    for (int k = 0; k < 16; ++k) sw2[k][t] *= r;
  }
  __syncthreads();
  int c = t;
  float wp0 = Wp2[c], wp1v = Wp2[256+c], wp2v = Wp2[512+c];
  float bbv = bp2[c];
  int c32 = c & 31;
  float acc = 0.f;
#pragma unroll
  for (int k = 0; k < 16; ++k) {
    int j = jidx[k];
    float pr = prv[k][0]*wp0 + prv[k][1]*wp1v + prv[k][2]*wp2v + bbv;
    float xvv = b2f(xv[(size_t)j*256 + c]);
    acc += (xvv + pr) * sw2[k][c32];
  }
  y[(size_t)i*256 + c] = acc;
}

// ---------------------------------------------------------------- epilogue (x2 only)
__launch_bounds__(256)
__global__ void final_k(const float* __restrict__ t0, const float* s0,
                        const float* g0, const float* b0,
                        const float* __restrict__ t3, const float* s3,
                        const float* g3, const float* b3,
                        float* __restrict__ out) {
  int i = blockIdx.x, c = threadIdx.x;
  size_t off = (size_t)i*256 + c;
  float h0 = fmaxf(bn_ap(t0[off], s0, 256, c, INV_N, g0[c], b0[c]), 0.0f);
  float v3 = bn_ap(t3[off], s3, 256, c, INV_N, g3[c], b3[c]);
  out[24576 + off] = fmaxf(v3 + h0, 0.0f);
}

// ---------------------------------------------------------------- launch
extern "C" void kernel_launch(void* const* d_in, const int* in_sizes, int n_in,
                              void* d_out, int out_size, void* d_ws, size_t ws_size,
                              hipStream_t stream) {
  (void)in_sizes; (void)n_in; (void)out_size; (void)ws_size;
  const float* p    = (const float*)d_in[0];
  const float* x    = (const float*)d_in[1];
  const int*   o    = (const int*)  d_in[2];
  const float* W_pa = (const float*)d_in[3];
  const float* g_pa = (const float*)d_in[4];
  const float* b_pa = (const float*)d_in[5];
  const float* W1   = (const float*)d_in[6];
  const float* g1   = (const float*)d_in[7];
  const float* b1   = (const float*)d_in[8];
  const float* Wq   = (const float*)d_in[9];
  const float* bq   = (const float*)d_in[10];
  const float* Wk   = (const float*)d_in[11];
  const float* bk   = (const float*)d_in[12];
  const float* Wv   = (const float*)d_in[13];
  const float* bv   = (const float*)d_in[14];
  const float* Wp1  = (const float*)d_in[15];
  const float* bp1  = (const float*)d_in[16];
  const float* gp   = (const float*)d_in[17];
  const float* bpp  = (const float*)d_in[18];
  const float* Wp2  = (const float*)d_in[19];
  const float* bp2  = (const float*)d_in[20];
  const float* gw1  = (const float*)d_in[21];
  const float* bw1  = (const float*)d_in[22];
  const float* Ww1  = (const float*)d_in[23];
  const float* bww1 = (const float*)d_in[24];
  const float* gw2  = (const float*)d_in[25];
  const float* bw2  = (const float*)d_in[26];
  const float* Ww2  = (const float*)d_in[27];
  const float* bww2 = (const float*)d_in[28];
  const float* g2   = (const float*)d_in[29];
  const float* b2   = (const float*)d_in[30];
  const float* W3   = (const float*)d_in[31];
  const float* g3   = (const float*)d_in[32];
  const float* b3   = (const float*)d_in[33];

  // workspace layout (~38.3 MB)
  char* ws = (char*)d_ws;
  float* t0  = (float*)(ws + 0);          // [8192,256] f32 (live til final_k)
  float* t1  = (float*)(ws + 8388608);    // [8192,256] f32 (later: y)
  u16*   xq  = (u16*)  (ws + 16777216);   // [8192,256] bf16
  u16*   xk  = (u16*)  (ws + 20971520);   // [8192,256] bf16
  u16*   xv  = (u16*)  (ws + 25165824);   // [8192,256] bf16
  u16*   w1  = (u16*)  (ws + 29360128);   // [131072,32] bf16 (8 MB)
  int*   idx = (int*)  (ws + 37748736);   // [8192,16] i32
  float* st  = (float*)(ws + 38273024);   // stats block (16 KB)
  u16*   Ww1t= (u16*)  (ws + 38289408);   // [32][256] bf16 (16 KB)
  float* y   = t1;                        // aggr output (t1 dead after qkv)
  float* t3  = (float*)(ws + 16777216);   // aliases xq+xk (dead after w1gemm)
  float4* pp = (float4*)(ws + 29360128);  // aliases w1 (knn finishes first)
  // st offsets: s0=0, s1=512, sw=1024, sy=1536, s3=2048, sw1=2560, sp=2624

  hipMemsetAsync(st, 0, 16384, stream);

  prep_k<<<96, 256, 0, stream>>>(p, o, Ww1, pp, Ww1t, (float*)d_out);
  knn_k<<<2048, 256, 0, stream>>>(pp, idx);

  mfgemm_k<false, true><<<dim3(128, 4), 256, 0, stream>>>(
      x, nullptr, nullptr, nullptr, 0.f, W_pa, t0, st + 0, 64, 256);

  mfgemm_k<true, true><<<dim3(128, 4), 256, 0, stream>>>(
      t0, st + 0, g_pa, b_pa, INV_N, W1, t1, st + 512, 256, 256);

  qkv_k<<<dim3(128, 4), 256, 0, stream>>>(
      t1, st + 512, g1, b1, Wq, bq, Wk, bk, Wv, bv, xq, xk, xv);

  prstats_k<<<128, 256, 0, stream>>>(p, idx, Wp1, bp1, st + 2624);

  wstats_k<<<1024, 256, 0, stream>>>(xk, xq, p, idx, Wp1, bp1, gp, bpp,
                                     st + 2624, Wp2, bp2, st + 1024);

  w1gemm_k<<<2048, 256, 0, stream>>>(xk, xq, p, idx, Wp1, bp1, gp, bpp,
                                     st + 2624, Wp2, bp2, st + 1024,
                                     gw1, bw1, Ww1t, bww1, w1, st + 2560);

  aggr_k<<<8192, 256, 0, stream>>>(w1, st + 2560, gw2, bw2, Ww2, bww2, xv,
                                   p, idx, Wp1, bp1, gp, bpp, st + 2624,
                                   Wp2, bp2, y);
  stats256_k<<<256, 256, 0, stream>>>(y, st + 1536);

  mfgemm_k<true, true><<<dim3(128, 4), 256, 0, stream>>>(
      y, st + 1536, g2, b2, INV_N, W3, t3, st + 2048, 256, 256);

  final_k<<<8192, 256, 0, stream>>>(t0, st + 0, g_pa, b_pa,
                                    t3, st + 2048, g3, b3, (float*)d_out);
}